// Round 13
// baseline (2587.376 us; speedup 1.0000x reference)
//
#include <hip/hip_runtime.h>
#include <hip/hip_bf16.h>
#include <math.h>

#define N_NODES 50000
#define N_EDGES 200000
#define N_GRAPH 1024
#define HC      128
#define NFC     256
#define NLAYER  5
#define NFFC    512

typedef short bf16x8 __attribute__((ext_vector_type(8)));
typedef float f4v    __attribute__((ext_vector_type(4)));

// fast ssp: softplus(x)-ln2 via v_exp/v_log (~1e-7 abs err)
__device__ __forceinline__ float ssp_f(float x) {
  float e = __expf(-fabsf(x));
  return fmaxf(x, 0.0f) + __logf(1.0f + e) - 0.69314718055994530942f;
}
// fast tanh via v_exp + v_rcp (~1e-6 err); overflow-safe
__device__ __forceinline__ float tanh_f(float x) {
  float e = __expf(2.0f * fabsf(x));
  float t = 1.0f - 2.0f * __builtin_amdgcn_rcpf(e + 1.0f);
  return copysignf(t, x);
}
__device__ __forceinline__ unsigned short f2bf(float x) {
  union { float f; unsigned u; } v; v.f = x;
  unsigned r = v.u + 0x7fff + ((v.u >> 16) & 1);
  return (unsigned short)(r >> 16);
}
__device__ __forceinline__ float bf2f(unsigned short b) {
  union { unsigned u; float f; } v; v.u = (unsigned)b << 16; return v.f;
}

// ---------------------------------------------------------------------------
__global__ void zero_kernel(float4* __restrict__ p, int n4) {
  int i = blockIdx.x * blockDim.x + threadIdx.x;
  if (i < n4) p[i] = make_float4(0.f, 0.f, 0.f, 0.f);
}
__global__ void zeroi_kernel(int* __restrict__ p, int n) {
  int i = blockIdx.x * blockDim.x + threadIdx.x;
  if (i < n) p[i] = 0;
}

// ---- dst-sort infrastructure ----------------------------------------------
__global__ void hist_kernel(const int* __restrict__ ei, int* __restrict__ deg) {
  int e = blockIdx.x * blockDim.x + threadIdx.x;
  if (e < N_EDGES) atomicAdd(&deg[ei[N_EDGES + e]], 1);
}
__global__ __launch_bounds__(1024) void scan_kernel(
    const int* __restrict__ deg, int* __restrict__ cursor, int n) {
  __shared__ int buf[1024];
  __shared__ int carry;
  if (threadIdx.x == 0) carry = 0;
  __syncthreads();
  for (int base = 0; base < n; base += 1024) {
    int i = base + threadIdx.x;
    int v = (i < n) ? deg[i] : 0;
    buf[threadIdx.x] = v;
    __syncthreads();
    for (int s = 1; s < 1024; s <<= 1) {
      int t = (threadIdx.x >= s) ? buf[threadIdx.x - s] : 0;
      __syncthreads();
      buf[threadIdx.x] += t;
      __syncthreads();
    }
    int excl = carry + buf[threadIdx.x] - v;
    if (i < n) cursor[i] = excl;
    int tot = buf[1023];
    __syncthreads();
    if (threadIdx.x == 0) carry += tot;
    __syncthreads();
  }
}
__global__ void perm_kernel(const int* __restrict__ ei, int* __restrict__ cursor,
                            int* __restrict__ perm) {
  int e = blockIdx.x * blockDim.x + threadIdx.x;
  if (e < N_EDGES) {
    int d = ei[N_EDGES + e];
    int p = atomicAdd(&cursor[d], 1);
    perm[p] = e;
  }
}

// split fp32 weights -> bf16 hi + lo
__global__ void wsplit_kernel(const float* __restrict__ w,
                              unsigned short* __restrict__ hi,
                              unsigned short* __restrict__ lo, int n) {
  int i = blockIdx.x * blockDim.x + threadIdx.x;
  if (i < n) {
    float v = w[i];
    unsigned short hb = f2bf(v);
    hi[i] = hb;
    lo[i] = f2bf(v - bf2f(hb));
  }
}

__global__ void embed_kernel(const int* __restrict__ x, const float* __restrict__ pos,
                             const float* __restrict__ vert, const float* __restrict__ posw,
                             float* __restrict__ h) {
  int n = blockIdx.x;
  int c = threadIdx.x;            // 128 threads
  float v;
  if (c < 80) {
    v = vert[(size_t)x[n] * 80 + c];
  } else {
    int j = c - 80;
    v = pos[n*3+0]*posw[j*3+0] + pos[n*3+1]*posw[j*3+1] + pos[n*3+2]*posw[j*3+2];
  }
  h[(size_t)n*HC + c] = v;
}

__global__ void edgeproj_kernel(const float* __restrict__ eattr, const float* __restrict__ ew,
                                float* __restrict__ ea) {
  int idx = blockIdx.x * blockDim.x + threadIdx.x;
  if (idx >= N_EDGES * HC) return;
  int e = idx >> 7, c = idx & 127;
  const float* a = eattr + (size_t)e*4;
  const float* w = ew + (size_t)c*4;
  ea[idx] = a[0]*w[0] + a[1]*w[1] + a[2]*w[2] + a[3]*w[3];
}

// ---------------------------------------------------------------------------
// Edge-MLP, restructured (R13): 64-edge tile, 256 threads, ONE barrier.
// ea = tanh(cat(ea, h[src]+h[dst]) @ emw^T + emb) + ea, in place.
// Both A-halves staged once into stable LDS; B columns wave-distinct (32/wave).
__global__ __launch_bounds__(256, 2) void emlite_kernel(
    float* ea,
    const unsigned short* __restrict__ Bh, const unsigned short* __restrict__ Bl,
    const float* __restrict__ bias, const int* __restrict__ ei,
    const float* __restrict__ hfeat)
{
  __shared__ unsigned short ldsA[2][64][136];   // ea split     34816 B
  __shared__ unsigned short ldsH[2][64][136];   // hsum split   34816 B

  const int tid  = threadIdx.x;
  const int m0   = blockIdx.x * 64;             // N_EDGES % 64 == 0
  const int lane = tid & 63, wave = tid >> 6;
  const int quad = lane >> 4, l16 = lane & 15;
  const int r = tid >> 2, cb = (tid & 3) * 32;

  const int e = m0 + r;
  const int s = ei[e], d = ei[N_EDGES + e];

  // stage ea tile (64x128 split)
  {
    const float* ap = ea + (size_t)e * HC + cb;
    float v[32];
#pragma unroll
    for (int q = 0; q < 8; q++) *(float4*)&v[q*4] = *(const float4*)(ap + q*4);
    unsigned short th[32], tl[32];
#pragma unroll
    for (int j = 0; j < 32; j++) {
      unsigned short hb = f2bf(v[j]);
      th[j] = hb; tl[j] = f2bf(v[j] - bf2f(hb));
    }
#pragma unroll
    for (int q = 0; q < 4; q++) {
      *(bf16x8*)&ldsA[0][r][cb + q*8] = *(bf16x8*)&th[q*8];
      *(bf16x8*)&ldsA[1][r][cb + q*8] = *(bf16x8*)&tl[q*8];
    }
  }
  // stage hsum tile (64x128 split)
  {
    const float* p1 = hfeat + (size_t)s * HC + cb;
    const float* p2 = hfeat + (size_t)d * HC + cb;
    float v[32];
#pragma unroll
    for (int q = 0; q < 8; q++) {
      float4 xa = *(const float4*)(p1 + q*4);
      float4 xb = *(const float4*)(p2 + q*4);
      v[q*4+0] = xa.x + xb.x; v[q*4+1] = xa.y + xb.y;
      v[q*4+2] = xa.z + xb.z; v[q*4+3] = xa.w + xb.w;
    }
    unsigned short th[32], tl[32];
#pragma unroll
    for (int j = 0; j < 32; j++) {
      unsigned short hb = f2bf(v[j]);
      th[j] = hb; tl[j] = f2bf(v[j] - bf2f(hb));
    }
#pragma unroll
    for (int q = 0; q < 4; q++) {
      *(bf16x8*)&ldsH[0][r][cb + q*8] = *(bf16x8*)&th[q*8];
      *(bf16x8*)&ldsH[1][r][cb + q*8] = *(bf16x8*)&tl[q*8];
    }
  }

  const f4v zf = {0.f, 0.f, 0.f, 0.f};
  f4v acc[4][2];
#pragma unroll
  for (int mt = 0; mt < 4; mt++) { acc[mt][0] = zf; acc[mt][1] = zf; }

  __syncthreads();   // the only barrier

  // K loop, ea half (K 0..128) then hsum half (K 128..256); both LDS stable.
#pragma unroll
  for (int nt = 0; nt < 2; nt++) {
    const size_t brow = (size_t)(wave*32 + nt*16 + l16);
#pragma unroll
    for (int kk = 0; kk < 128; kk += 32) {
      bf16x8 bh = *(const bf16x8*)&Bh[brow * 2*HC + kk + quad*8];
      bf16x8 bl = *(const bf16x8*)&Bl[brow * 2*HC + kk + quad*8];
#pragma unroll
      for (int mt = 0; mt < 4; mt++) {
        bf16x8 ah = *(const bf16x8*)&ldsA[0][mt*16 + l16][kk + quad*8];
        bf16x8 al = *(const bf16x8*)&ldsA[1][mt*16 + l16][kk + quad*8];
        acc[mt][nt] = __builtin_amdgcn_mfma_f32_16x16x32_bf16(ah, bh, acc[mt][nt], 0, 0, 0);
        acc[mt][nt] = __builtin_amdgcn_mfma_f32_16x16x32_bf16(ah, bl, acc[mt][nt], 0, 0, 0);
        acc[mt][nt] = __builtin_amdgcn_mfma_f32_16x16x32_bf16(al, bh, acc[mt][nt], 0, 0, 0);
      }
    }
#pragma unroll
    for (int kk = 0; kk < 128; kk += 32) {
      bf16x8 bh = *(const bf16x8*)&Bh[brow * 2*HC + HC + kk + quad*8];
      bf16x8 bl = *(const bf16x8*)&Bl[brow * 2*HC + HC + kk + quad*8];
#pragma unroll
      for (int mt = 0; mt < 4; mt++) {
        bf16x8 ah = *(const bf16x8*)&ldsH[0][mt*16 + l16][kk + quad*8];
        bf16x8 al = *(const bf16x8*)&ldsH[1][mt*16 + l16][kk + quad*8];
        acc[mt][nt] = __builtin_amdgcn_mfma_f32_16x16x32_bf16(ah, bh, acc[mt][nt], 0, 0, 0);
        acc[mt][nt] = __builtin_amdgcn_mfma_f32_16x16x32_bf16(ah, bl, acc[mt][nt], 0, 0, 0);
        acc[mt][nt] = __builtin_amdgcn_mfma_f32_16x16x32_bf16(al, bh, acc[mt][nt], 0, 0, 0);
      }
    }
  }

  // epilogue: each (row,col) owned by exactly one lane -> in-place safe.
#pragma unroll
  for (int nt = 0; nt < 2; nt++) {
    const int col = wave*32 + nt*16 + l16;
    const float bz = bias[col];
#pragma unroll
    for (int mt = 0; mt < 4; mt++) {
      const int rowb = mt*16 + quad*4;
#pragma unroll
      for (int rr = 0; rr < 4; rr++) {
        const size_t idx = (size_t)(m0 + rowb + rr) * HC + col;
        ea[idx] = tanh_f(acc[mt][nt][rr] + bz) + ea[idx];   // residual L2-hot
      }
    }
  }
}

// ---------------------------------------------------------------------------
// Fused node update: h = relu(ssp(agg @ l2^T + b2) @ l3^T + b3) + h.
__global__ __launch_bounds__(256, 2) void nodeup_kernel(
    const float* __restrict__ agg,
    const unsigned short* __restrict__ L2h, const unsigned short* __restrict__ L2l,
    const float* __restrict__ b2,
    const unsigned short* __restrict__ L3h, const unsigned short* __restrict__ L3l,
    const float* __restrict__ b3,
    float* h)
{
  __shared__ unsigned short lds[2 * 128 * 136];
  const int AH = 0, AL = 5120;            // A chunk staging (pitch 40)
  const int TH = 0, TL = 17408;           // t2 full tile (pitch 136)

  const int tid  = threadIdx.x;
  const int m0   = blockIdx.x * 128;
  const int lane = tid & 63, wave = tid >> 6;
  const int quad = lane >> 4, l16 = lane & 15;
  const int wm = (wave >> 1) * 64, wn = (wave & 1) * 64;
  const int r  = tid >> 1;
  const int c0 = (tid & 1) * 16;

  const f4v zf = {0.f, 0.f, 0.f, 0.f};
  f4v acc[4][4];
#pragma unroll
  for (int i = 0; i < 4; i++)
#pragma unroll
    for (int j = 0; j < 4; j++) acc[i][j] = zf;

  const bool mok = (m0 + r) < N_NODES;
  const size_t arow = (size_t)(m0 + r);

  for (int kk = 0; kk < NFC; kk += 32) {
    float av[16];
    if (mok) {
      const float* ap = agg + arow * NFC + kk + c0;
#pragma unroll
      for (int q = 0; q < 4; q++) *(float4*)&av[q*4] = *(const float4*)(ap + q*4);
    } else {
#pragma unroll
      for (int j = 0; j < 16; j++) av[j] = 0.f;
    }
    bf16x8 bh[4], bl[4];
#pragma unroll
    for (int nt = 0; nt < 4; nt++) {
      const size_t brow = (size_t)(wn + nt*16 + l16);
      bh[nt] = *(const bf16x8*)&L2h[brow * NFC + kk + quad*8];
      bl[nt] = *(const bf16x8*)&L2l[brow * NFC + kk + quad*8];
    }
    __syncthreads();
    unsigned short th[16], tl[16];
#pragma unroll
    for (int j = 0; j < 16; j++) {
      unsigned short hb = f2bf(av[j]);
      th[j] = hb; tl[j] = f2bf(av[j] - bf2f(hb));
    }
    *(bf16x8*)&lds[AH + r*40 + c0]     = *(bf16x8*)&th[0];
    *(bf16x8*)&lds[AH + r*40 + c0 + 8] = *(bf16x8*)&th[8];
    *(bf16x8*)&lds[AL + r*40 + c0]     = *(bf16x8*)&tl[0];
    *(bf16x8*)&lds[AL + r*40 + c0 + 8] = *(bf16x8*)&tl[8];
    __syncthreads();
    bf16x8 ah[4], al[4];
#pragma unroll
    for (int t = 0; t < 4; t++) {
      const int ra = (wm + t*16 + l16) * 40 + quad * 8;
      ah[t] = *(const bf16x8*)&lds[AH + ra];
      al[t] = *(const bf16x8*)&lds[AL + ra];
    }
#pragma unroll
    for (int mt = 0; mt < 4; mt++)
#pragma unroll
      for (int nt = 0; nt < 4; nt++) {
        acc[mt][nt] = __builtin_amdgcn_mfma_f32_16x16x32_bf16(ah[mt], bh[nt], acc[mt][nt], 0, 0, 0);
        acc[mt][nt] = __builtin_amdgcn_mfma_f32_16x16x32_bf16(ah[mt], bl[nt], acc[mt][nt], 0, 0, 0);
        acc[mt][nt] = __builtin_amdgcn_mfma_f32_16x16x32_bf16(al[mt], bh[nt], acc[mt][nt], 0, 0, 0);
      }
  }
  __syncthreads();

#pragma unroll
  for (int nt = 0; nt < 4; nt++) {
    const int col = wn + nt*16 + l16;
    const float bz = b2[col];
#pragma unroll
    for (int mt = 0; mt < 4; mt++) {
      const int rowb = wm + mt*16 + quad*4;
#pragma unroll
      for (int rr = 0; rr < 4; rr++) {
        float v = ssp_f(acc[mt][nt][rr] + bz);
        unsigned short hb = f2bf(v);
        lds[TH + (rowb+rr)*136 + col] = hb;
        lds[TL + (rowb+rr)*136 + col] = f2bf(v - bf2f(hb));
      }
    }
  }
  __syncthreads();

  f4v acc2[4][4];
#pragma unroll
  for (int i = 0; i < 4; i++)
#pragma unroll
    for (int j = 0; j < 4; j++) acc2[i][j] = zf;

  for (int kk = 0; kk < HC; kk += 32) {
    bf16x8 bh[4], bl[4];
#pragma unroll
    for (int nt = 0; nt < 4; nt++) {
      const size_t brow = (size_t)(wn + nt*16 + l16);
      bh[nt] = *(const bf16x8*)&L3h[brow * HC + kk + quad*8];
      bl[nt] = *(const bf16x8*)&L3l[brow * HC + kk + quad*8];
    }
    bf16x8 ah[4], al[4];
#pragma unroll
    for (int t = 0; t < 4; t++) {
      const int ra = (wm + t*16 + l16) * 136 + kk + quad * 8;
      ah[t] = *(const bf16x8*)&lds[TH + ra];
      al[t] = *(const bf16x8*)&lds[TL + ra];
    }
#pragma unroll
    for (int mt = 0; mt < 4; mt++)
#pragma unroll
      for (int nt = 0; nt < 4; nt++) {
        acc2[mt][nt] = __builtin_amdgcn_mfma_f32_16x16x32_bf16(ah[mt], bh[nt], acc2[mt][nt], 0, 0, 0);
        acc2[mt][nt] = __builtin_amdgcn_mfma_f32_16x16x32_bf16(ah[mt], bl[nt], acc2[mt][nt], 0, 0, 0);
        acc2[mt][nt] = __builtin_amdgcn_mfma_f32_16x16x32_bf16(al[mt], bh[nt], acc2[mt][nt], 0, 0, 0);
      }
  }

#pragma unroll
  for (int nt = 0; nt < 4; nt++) {
    const int ncol = wn + nt*16 + l16;
    const float bz = b3[ncol];
#pragma unroll
    for (int mt = 0; mt < 4; mt++) {
      const int mb = wm + mt*16 + quad*4;
#pragma unroll
      for (int rr = 0; rr < 4; rr++) {
        const int m = m0 + mb + rr;
        if (m < N_NODES) {
          const size_t idx = (size_t)m * HC + ncol;
          h[idx] = fmaxf(acc2[mt][nt][rr] + bz, 0.f) + h[idx];
        }
      }
    }
  }
}

// ---------------------------------------------------------------------------
// Fused lin1 + filter MLP + in-register run-reduced scatter (R11 structure).
__device__ __forceinline__ int sigma_row(int r) {
  return ((r >> 2) & 3) * 16 + (r >> 4) * 4 + (r & 3);
}
__global__ __launch_bounds__(256, 3) void ffs_kernel(
    const float* __restrict__ ea,
    const unsigned short* __restrict__ l1h, const unsigned short* __restrict__ l1l,
    const unsigned short* __restrict__ fw1h, const unsigned short* __restrict__ fw1l,
    const float* __restrict__ fb1,
    const unsigned short* __restrict__ fw2h, const unsigned short* __restrict__ fw2l,
    const float* __restrict__ fb2, const int* __restrict__ ei,
    const int* __restrict__ perm,
    const float* __restrict__ hfeat, float* agg)
{
  __shared__ unsigned short ldsA[2][64][136];
  __shared__ unsigned short ldsT[2][64][72];
  __shared__ int sS[64], sD[64];

  const int tid  = threadIdx.x;
  const int m0   = blockIdx.x * 64;
  const int lane = tid & 63, wave = tid >> 6;
  const int quad = lane >> 4, l16 = lane & 15;

  {
    const int r = tid >> 2, cb = (tid & 3) * 32;
    const int pe = perm[m0 + sigma_row(r)];
    const float* ap = ea + (size_t)pe * HC + cb;
    unsigned short th[32], tl[32];
#pragma unroll
    for (int q = 0; q < 8; q++) {
      float4 v = *(const float4*)(ap + q*4);
      float vv[4] = {v.x, v.y, v.z, v.w};
#pragma unroll
      for (int e = 0; e < 4; e++) {
        unsigned short hb = f2bf(vv[e]);
        th[q*4+e] = hb; tl[q*4+e] = f2bf(vv[e] - bf2f(hb));
      }
    }
#pragma unroll
    for (int q = 0; q < 4; q++) {
      *(bf16x8*)&ldsA[0][r][cb + q*8] = *(bf16x8*)&th[q*8];
      *(bf16x8*)&ldsA[1][r][cb + q*8] = *(bf16x8*)&tl[q*8];
    }
  }
  if (tid < 64) {
    int pe = perm[m0 + sigma_row(tid)];
    sS[tid] = ei[pe];
    sD[tid] = ei[N_EDGES + pe];
  }

  const f4v zf = {0.f, 0.f, 0.f, 0.f};
  __syncthreads();

  f4v hacc[4][4];
#pragma unroll
  for (int mt = 0; mt < 4; mt++)
#pragma unroll
    for (int nt = 0; nt < 4; nt++) hacc[mt][nt] = zf;

  unsigned short* ldsF = &ldsT[0][0][0];
  for (int kk = 0; kk < 128; kk += 32) {
    {
      const int r = tid >> 2, c8 = (tid & 3) * 8;
      const float* hp_ = hfeat + (size_t)sS[r] * HC + kk + c8;
      float4 v0 = *(const float4*)hp_;
      float4 v1 = *(const float4*)(hp_ + 4);
      float vv[8] = {v0.x, v0.y, v0.z, v0.w, v1.x, v1.y, v1.z, v1.w};
      unsigned short th[8], tl[8];
#pragma unroll
      for (int e = 0; e < 8; e++) {
        unsigned short hb = f2bf(vv[e]);
        th[e] = hb; tl[e] = f2bf(vv[e] - bf2f(hb));
      }
      *(bf16x8*)&ldsF[r*40 + c8]        = *(bf16x8*)&th[0];
      *(bf16x8*)&ldsF[2560 + r*40 + c8] = *(bf16x8*)&tl[0];
    }
    __syncthreads();
#pragma unroll
    for (int nt = 0; nt < 4; nt++) {
      const size_t brow = (size_t)(wave*64 + nt*16 + l16);
      bf16x8 bh = *(const bf16x8*)&l1h[brow * HC + kk + quad*8];
      bf16x8 bl = *(const bf16x8*)&l1l[brow * HC + kk + quad*8];
#pragma unroll
      for (int mt = 0; mt < 4; mt++) {
        bf16x8 ah = *(const bf16x8*)&ldsF[(mt*16 + l16)*40 + quad*8];
        bf16x8 al = *(const bf16x8*)&ldsF[2560 + (mt*16 + l16)*40 + quad*8];
        hacc[mt][nt] = __builtin_amdgcn_mfma_f32_16x16x32_bf16(ah, bh, hacc[mt][nt], 0, 0, 0);
        hacc[mt][nt] = __builtin_amdgcn_mfma_f32_16x16x32_bf16(ah, bl, hacc[mt][nt], 0, 0, 0);
        hacc[mt][nt] = __builtin_amdgcn_mfma_f32_16x16x32_bf16(al, bh, hacc[mt][nt], 0, 0, 0);
      }
    }
    __syncthreads();
  }

  f4v wacc[4][4];
#pragma unroll
  for (int mt = 0; mt < 4; mt++)
#pragma unroll
    for (int nt = 0; nt < 4; nt++) wacc[mt][nt] = zf;

  for (int p = 0; p < 4; p++) {
    f4v tacc[4];
#pragma unroll
    for (int mt = 0; mt < 4; mt++) tacc[mt] = zf;
    const size_t b1row = (size_t)(p*64 + wave*16 + l16);
#pragma unroll
    for (int kk = 0; kk < 128; kk += 32) {
      bf16x8 bh = *(const bf16x8*)&fw1h[b1row * HC + kk + quad*8];
      bf16x8 bl = *(const bf16x8*)&fw1l[b1row * HC + kk + quad*8];
#pragma unroll
      for (int mt = 0; mt < 4; mt++) {
        bf16x8 ah = *(const bf16x8*)&ldsA[0][mt*16 + l16][kk + quad*8];
        bf16x8 al = *(const bf16x8*)&ldsA[1][mt*16 + l16][kk + quad*8];
        tacc[mt] = __builtin_amdgcn_mfma_f32_16x16x32_bf16(ah, bh, tacc[mt], 0, 0, 0);
        tacc[mt] = __builtin_amdgcn_mfma_f32_16x16x32_bf16(ah, bl, tacc[mt], 0, 0, 0);
        tacc[mt] = __builtin_amdgcn_mfma_f32_16x16x32_bf16(al, bh, tacc[mt], 0, 0, 0);
      }
    }
    {
      const int col = wave*16 + l16;
      const float bz = fb1[p*64 + col];
#pragma unroll
      for (int mt = 0; mt < 4; mt++) {
        const int rowb = mt*16 + quad*4;
#pragma unroll
        for (int rr = 0; rr < 4; rr++) {
          float v = ssp_f(tacc[mt][rr] + bz);
          unsigned short hb = f2bf(v);
          ldsT[0][rowb+rr][col] = hb;
          ldsT[1][rowb+rr][col] = f2bf(v - bf2f(hb));
        }
      }
    }
    __syncthreads();

#pragma unroll
    for (int kc = 0; kc < 2; kc++) {
      bf16x8 a_h[4], a_l[4];
#pragma unroll
      for (int mt = 0; mt < 4; mt++) {
        a_h[mt] = *(const bf16x8*)&ldsT[0][mt*16 + l16][kc*32 + quad*8];
        a_l[mt] = *(const bf16x8*)&ldsT[1][mt*16 + l16][kc*32 + quad*8];
      }
#pragma unroll
      for (int nt = 0; nt < 4; nt++) {
        const size_t brow = (size_t)(wave*64 + nt*16 + l16);
        bf16x8 bh = *(const bf16x8*)&fw2h[brow * NFC + p*64 + kc*32 + quad*8];
        bf16x8 bl = *(const bf16x8*)&fw2l[brow * NFC + p*64 + kc*32 + quad*8];
#pragma unroll
        for (int mt = 0; mt < 4; mt++) {
          wacc[mt][nt] = __builtin_amdgcn_mfma_f32_16x16x32_bf16(a_h[mt], bh, wacc[mt][nt], 0, 0, 0);
          wacc[mt][nt] = __builtin_amdgcn_mfma_f32_16x16x32_bf16(a_h[mt], bl, wacc[mt][nt], 0, 0, 0);
          wacc[mt][nt] = __builtin_amdgcn_mfma_f32_16x16x32_bf16(a_l[mt], bh, wacc[mt][nt], 0, 0, 0);
        }
      }
    }
    __syncthreads();
  }

#pragma unroll
  for (int nt = 0; nt < 4; nt++) {
    const int col = wave*64 + nt*16 + l16;
    const float bz = fb2[col];
    float accum = 0.f;
    int prev = -1;
#pragma unroll
    for (int mt = 0; mt < 4; mt++) {
#pragma unroll
      for (int rr = 0; rr < 4; rr++) {
        const int prow = mt*16 + quad*4 + rr;
        const int d = sD[prow];
        const float v = (wacc[mt][nt][rr] + bz) * hacc[mt][nt][rr];
        if (d != prev) {
          if (prev >= 0) atomicAdd(&agg[(size_t)prev * NFC + col], accum);
          accum = v; prev = d;
        } else {
          accum += v;
        }
      }
    }
    atomicAdd(&agg[(size_t)prev * NFC + col], accum);
  }
}

// ---------------------------------------------------------------------------
__global__ void pool_kernel(const int* __restrict__ batch, const float* __restrict__ h,
                            float* __restrict__ ssum, float* __restrict__ cnt) {
  int idx = blockIdx.x * blockDim.x + threadIdx.x;
  if (idx >= N_NODES * HC) return;
  int n = idx >> 7, c = idx & 127;
  int b = batch[n];
  atomicAdd(&ssum[(size_t)b*HC + c], h[idx]);
  if (c == 0) atomicAdd(&cnt[b], 1.0f);
}

__global__ __launch_bounds__(256) void head_kernel(
    const float* __restrict__ ssum, const float* __restrict__ cnt,
    const float* __restrict__ w1, const float* __restrict__ b1,
    const float* __restrict__ w2, const float* __restrict__ b2,
    float* __restrict__ y) {
  int g = blockIdx.x;
  __shared__ float gs[HC];
  __shared__ float red[256];
  int tid = threadIdx.x;
  float inv = 1.0f / fmaxf(cnt[g], 1.0f);
  if (tid < HC) gs[tid] = ssum[(size_t)g*HC + tid] * inv;
  __syncthreads();
  float partial = 0.0f;
  for (int f = tid; f < NFFC; f += 256) {
    float acc = b1[f];
    const float* wr = w1 + (size_t)f*HC;
#pragma unroll 8
    for (int k = 0; k < HC; k++) acc = fmaf(gs[k], wr[k], acc);
    float t = 0.5f * acc * (1.0f + erff(acc * 0.70710678118654752440f));
    partial = fmaf(t, w2[f], partial);
  }
  red[tid] = partial;
  __syncthreads();
  for (int s = 128; s > 0; s >>= 1) {
    if (tid < s) red[tid] += red[tid + s];
    __syncthreads();
  }
  if (tid == 0) y[g] = red[0] + b2[0];
}

// ---------------------------------------------------------------------------
extern "C" void kernel_launch(void* const* d_in, const int* in_sizes, int n_in,
                              void* d_out, int out_size, void* d_ws, size_t ws_size,
                              hipStream_t stream) {
  const int*   x     = (const int*)  d_in[0];
  const int*   ei    = (const int*)  d_in[1];
  const float* eattr = (const float*)d_in[2];
  const int*   batch = (const int*)  d_in[3];
  const float* pos   = (const float*)d_in[4];
  const float* vert  = (const float*)d_in[5];
  const float* posw  = (const float*)d_in[6];
  const float* edgew = (const float*)d_in[7];
  const float* fw1   = (const float*)d_in[8];
  const float* fb1   = (const float*)d_in[9];
  const float* fw2   = (const float*)d_in[10];
  const float* fb2   = (const float*)d_in[11];
  const float* l1w   = (const float*)d_in[12];
  const float* l2w   = (const float*)d_in[13];
  const float* l2b   = (const float*)d_in[14];
  const float* l3w   = (const float*)d_in[15];
  const float* l3b   = (const float*)d_in[16];
  const float* emw   = (const float*)d_in[17];
  const float* emb   = (const float*)d_in[18];
  const float* hw1   = (const float*)d_in[19];
  const float* hb1   = (const float*)d_in[20];
  const float* hw2   = (const float*)d_in[21];
  const float* hb2   = (const float*)d_in[22];
  float* out = (float*)d_out;

  char* ws = (char*)d_ws;
  size_t off = 0;
  auto alloc = [&](size_t bytes) { char* p = ws + off; off += (bytes + 511) & ~(size_t)511; return p; };
  float* ea   = (float*)alloc((size_t)N_EDGES*HC*4);
  float* h    = (float*)alloc((size_t)N_NODES*HC*4);
  float* agg  = (float*)alloc((size_t)N_NODES*NFC*4);
  float* ssum = (float*)alloc((size_t)N_GRAPH*HC*4);
  float* cnt  = (float*)alloc((size_t)N_GRAPH*4);
  int* deg    = (int*)alloc((size_t)(N_NODES+1)*4);
  int* cursor = (int*)alloc((size_t)(N_NODES+1)*4);
  int* perm   = (int*)alloc((size_t)N_EDGES*4);
  const int n_fw1 = NLAYER*NFC*HC, n_fw2 = NLAYER*NFC*NFC, n_l1 = NLAYER*NFC*HC;
  const int n_l2 = NLAYER*HC*NFC, n_l3 = NLAYER*HC*HC, n_em = NLAYER*HC*2*HC;
  unsigned short* fw1h = (unsigned short*)alloc((size_t)n_fw1*2);
  unsigned short* fw1l = (unsigned short*)alloc((size_t)n_fw1*2);
  unsigned short* fw2h = (unsigned short*)alloc((size_t)n_fw2*2);
  unsigned short* fw2l = (unsigned short*)alloc((size_t)n_fw2*2);
  unsigned short* l1h  = (unsigned short*)alloc((size_t)n_l1*2);
  unsigned short* l1l  = (unsigned short*)alloc((size_t)n_l1*2);
  unsigned short* l2h  = (unsigned short*)alloc((size_t)n_l2*2);
  unsigned short* l2l  = (unsigned short*)alloc((size_t)n_l2*2);
  unsigned short* l3h  = (unsigned short*)alloc((size_t)n_l3*2);
  unsigned short* l3l  = (unsigned short*)alloc((size_t)n_l3*2);
  unsigned short* emh  = (unsigned short*)alloc((size_t)n_em*2);
  unsigned short* eml  = (unsigned short*)alloc((size_t)n_em*2);

  zeroi_kernel<<<(N_NODES+1+255)/256, 256, 0, stream>>>(deg, N_NODES+1);
  hist_kernel<<<(N_EDGES+255)/256, 256, 0, stream>>>(ei, deg);
  scan_kernel<<<1, 1024, 0, stream>>>(deg, cursor, N_NODES+1);
  perm_kernel<<<(N_EDGES+255)/256, 256, 0, stream>>>(ei, cursor, perm);

  wsplit_kernel<<<(n_fw1+255)/256, 256, 0, stream>>>(fw1, fw1h, fw1l, n_fw1);
  wsplit_kernel<<<(n_fw2+255)/256, 256, 0, stream>>>(fw2, fw2h, fw2l, n_fw2);
  wsplit_kernel<<<(n_l1 +255)/256, 256, 0, stream>>>(l1w, l1h, l1l, n_l1);
  wsplit_kernel<<<(n_l2 +255)/256, 256, 0, stream>>>(l2w, l2h, l2l, n_l2);
  wsplit_kernel<<<(n_l3 +255)/256, 256, 0, stream>>>(l3w, l3h, l3l, n_l3);
  wsplit_kernel<<<(n_em +255)/256, 256, 0, stream>>>(emw, emh, eml, n_em);

  const int GN   = (N_NODES + 127) / 128;   // 391
  const int GE64 = N_EDGES / 64;            // 3125 (exact)

  embed_kernel<<<N_NODES, 128, 0, stream>>>(x, pos, vert, posw, h);
  edgeproj_kernel<<<(N_EDGES*HC + 255)/256, 256, 0, stream>>>(eattr, edgew, ea);

  for (int i = 0; i < NLAYER; ++i) {
    zero_kernel<<<((N_NODES*NFC/4) + 255)/256, 256, 0, stream>>>(
        (float4*)agg, N_NODES*NFC/4);
    ffs_kernel<<<GE64, 256, 0, stream>>>(
        ea, l1h + (size_t)i*NFC*HC, l1l + (size_t)i*NFC*HC,
        fw1h + (size_t)i*NFC*HC, fw1l + (size_t)i*NFC*HC, fb1 + (size_t)i*NFC,
        fw2h + (size_t)i*NFC*NFC, fw2l + (size_t)i*NFC*NFC, fb2 + (size_t)i*NFC,
        ei, perm, h, agg);
    nodeup_kernel<<<GN, 256, 0, stream>>>(
        agg, l2h + (size_t)i*HC*NFC, l2l + (size_t)i*HC*NFC, l2b + (size_t)i*HC,
        l3h + (size_t)i*HC*HC, l3l + (size_t)i*HC*HC, l3b + (size_t)i*HC, h);
    // edge-MLP update is DEAD at the last layer (ea never read again)
    if (i < NLAYER - 1) {
      emlite_kernel<<<GE64, 256, 0, stream>>>(
          ea, emh + (size_t)i*HC*2*HC, eml + (size_t)i*HC*2*HC, emb + (size_t)i*HC,
          ei, h);
    }
  }

  zero_kernel<<<((N_GRAPH*HC/4) + 255)/256, 256, 0, stream>>>((float4*)ssum, N_GRAPH*HC/4);
  zero_kernel<<<((N_GRAPH/4) + 255)/256, 256, 0, stream>>>((float4*)cnt, N_GRAPH/4);
  pool_kernel<<<(N_NODES*HC + 255)/256, 256, 0, stream>>>(batch, h, ssum, cnt);
  head_kernel<<<N_GRAPH, 256, 0, stream>>>(ssum, cnt, hw1, hb1, hw2, hb2, out);
}

// Round 14
// 2567.783 us; speedup vs baseline: 1.0076x; 1.0076x over previous
//
#include <hip/hip_runtime.h>
#include <hip/hip_bf16.h>
#include <math.h>

#define N_NODES 50000
#define N_EDGES 200000
#define N_GRAPH 1024
#define HC      128
#define NFC     256
#define NLAYER  5
#define NFFC    512

typedef short bf16x8 __attribute__((ext_vector_type(8)));
typedef float f4v    __attribute__((ext_vector_type(4)));

// fast ssp: softplus(x)-ln2 via v_exp/v_log (~1e-7 abs err)
__device__ __forceinline__ float ssp_f(float x) {
  float e = __expf(-fabsf(x));
  return fmaxf(x, 0.0f) + __logf(1.0f + e) - 0.69314718055994530942f;
}
// fast tanh via v_exp + v_rcp (~1e-6 err); overflow-safe
__device__ __forceinline__ float tanh_f(float x) {
  float e = __expf(2.0f * fabsf(x));
  float t = 1.0f - 2.0f * __builtin_amdgcn_rcpf(e + 1.0f);
  return copysignf(t, x);
}
__device__ __forceinline__ unsigned short f2bf(float x) {
  union { float f; unsigned u; } v; v.f = x;
  unsigned r = v.u + 0x7fff + ((v.u >> 16) & 1);
  return (unsigned short)(r >> 16);
}
__device__ __forceinline__ float bf2f(unsigned short b) {
  union { unsigned u; float f; } v; v.u = (unsigned)b << 16; return v.f;
}

// ---------------------------------------------------------------------------
__global__ void zero_kernel(float4* __restrict__ p, int n4) {
  int i = blockIdx.x * blockDim.x + threadIdx.x;
  if (i < n4) p[i] = make_float4(0.f, 0.f, 0.f, 0.f);
}
__global__ void zeroi_kernel(int* __restrict__ p, int n) {
  int i = blockIdx.x * blockDim.x + threadIdx.x;
  if (i < n) p[i] = 0;
}

// ---- dst-sort infrastructure ----------------------------------------------
__global__ void hist_kernel(const int* __restrict__ ei, int* __restrict__ deg) {
  int e = blockIdx.x * blockDim.x + threadIdx.x;
  if (e < N_EDGES) atomicAdd(&deg[ei[N_EDGES + e]], 1);
}
__global__ __launch_bounds__(1024) void scan_kernel(
    const int* __restrict__ deg, int* __restrict__ cursor, int n) {
  __shared__ int buf[1024];
  __shared__ int carry;
  if (threadIdx.x == 0) carry = 0;
  __syncthreads();
  for (int base = 0; base < n; base += 1024) {
    int i = base + threadIdx.x;
    int v = (i < n) ? deg[i] : 0;
    buf[threadIdx.x] = v;
    __syncthreads();
    for (int s = 1; s < 1024; s <<= 1) {
      int t = (threadIdx.x >= s) ? buf[threadIdx.x - s] : 0;
      __syncthreads();
      buf[threadIdx.x] += t;
      __syncthreads();
    }
    int excl = carry + buf[threadIdx.x] - v;
    if (i < n) cursor[i] = excl;
    int tot = buf[1023];
    __syncthreads();
    if (threadIdx.x == 0) carry += tot;
    __syncthreads();
  }
}
__global__ void perm_kernel(const int* __restrict__ ei, int* __restrict__ cursor,
                            int* __restrict__ perm) {
  int e = blockIdx.x * blockDim.x + threadIdx.x;
  if (e < N_EDGES) {
    int d = ei[N_EDGES + e];
    int p = atomicAdd(&cursor[d], 1);
    perm[p] = e;
  }
}

// split fp32 weights -> bf16 hi + lo
__global__ void wsplit_kernel(const float* __restrict__ w,
                              unsigned short* __restrict__ hi,
                              unsigned short* __restrict__ lo, int n) {
  int i = blockIdx.x * blockDim.x + threadIdx.x;
  if (i < n) {
    float v = w[i];
    unsigned short hb = f2bf(v);
    hi[i] = hb;
    lo[i] = f2bf(v - bf2f(hb));
  }
}

__global__ void embed_kernel(const int* __restrict__ x, const float* __restrict__ pos,
                             const float* __restrict__ vert, const float* __restrict__ posw,
                             float* __restrict__ h) {
  int n = blockIdx.x;
  int c = threadIdx.x;            // 128 threads
  float v;
  if (c < 80) {
    v = vert[(size_t)x[n] * 80 + c];
  } else {
    int j = c - 80;
    v = pos[n*3+0]*posw[j*3+0] + pos[n*3+1]*posw[j*3+1] + pos[n*3+2]*posw[j*3+2];
  }
  h[(size_t)n*HC + c] = v;
}

__global__ void edgeproj_kernel(const float* __restrict__ eattr, const float* __restrict__ ew,
                                float* __restrict__ ea) {
  int idx = blockIdx.x * blockDim.x + threadIdx.x;
  if (idx >= N_EDGES * HC) return;
  int e = idx >> 7, c = idx & 127;
  const float* a = eattr + (size_t)e*4;
  const float* w = ew + (size_t)c*4;
  ea[idx] = a[0]*w[0] + a[1]*w[1] + a[2]*w[2] + a[3]*w[3];
}

// ---------------------------------------------------------------------------
// Edge-MLP: 64-edge tile, 256 threads, ONE barrier.
// ea = tanh(cat(ea, h[src]+h[dst]) @ emw^T + emb) + ea, in place.
__global__ __launch_bounds__(256, 2) void emlite_kernel(
    float* ea,
    const unsigned short* __restrict__ Bh, const unsigned short* __restrict__ Bl,
    const float* __restrict__ bias, const int* __restrict__ ei,
    const float* __restrict__ hfeat)
{
  __shared__ unsigned short ldsA[2][64][136];   // ea split
  __shared__ unsigned short ldsH[2][64][136];   // hsum split

  const int tid  = threadIdx.x;
  const int m0   = blockIdx.x * 64;             // N_EDGES % 64 == 0
  const int lane = tid & 63, wave = tid >> 6;
  const int quad = lane >> 4, l16 = lane & 15;
  const int r = tid >> 2, cb = (tid & 3) * 32;

  const int e = m0 + r;
  const int s = ei[e], d = ei[N_EDGES + e];

  {
    const float* ap = ea + (size_t)e * HC + cb;
    float v[32];
#pragma unroll
    for (int q = 0; q < 8; q++) *(float4*)&v[q*4] = *(const float4*)(ap + q*4);
    unsigned short th[32], tl[32];
#pragma unroll
    for (int j = 0; j < 32; j++) {
      unsigned short hb = f2bf(v[j]);
      th[j] = hb; tl[j] = f2bf(v[j] - bf2f(hb));
    }
#pragma unroll
    for (int q = 0; q < 4; q++) {
      *(bf16x8*)&ldsA[0][r][cb + q*8] = *(bf16x8*)&th[q*8];
      *(bf16x8*)&ldsA[1][r][cb + q*8] = *(bf16x8*)&tl[q*8];
    }
  }
  {
    const float* p1 = hfeat + (size_t)s * HC + cb;
    const float* p2 = hfeat + (size_t)d * HC + cb;
    float v[32];
#pragma unroll
    for (int q = 0; q < 8; q++) {
      float4 xa = *(const float4*)(p1 + q*4);
      float4 xb = *(const float4*)(p2 + q*4);
      v[q*4+0] = xa.x + xb.x; v[q*4+1] = xa.y + xb.y;
      v[q*4+2] = xa.z + xb.z; v[q*4+3] = xa.w + xb.w;
    }
    unsigned short th[32], tl[32];
#pragma unroll
    for (int j = 0; j < 32; j++) {
      unsigned short hb = f2bf(v[j]);
      th[j] = hb; tl[j] = f2bf(v[j] - bf2f(hb));
    }
#pragma unroll
    for (int q = 0; q < 4; q++) {
      *(bf16x8*)&ldsH[0][r][cb + q*8] = *(bf16x8*)&th[q*8];
      *(bf16x8*)&ldsH[1][r][cb + q*8] = *(bf16x8*)&tl[q*8];
    }
  }

  const f4v zf = {0.f, 0.f, 0.f, 0.f};
  f4v acc[4][2];
#pragma unroll
  for (int mt = 0; mt < 4; mt++) { acc[mt][0] = zf; acc[mt][1] = zf; }

  __syncthreads();   // the only barrier

#pragma unroll
  for (int nt = 0; nt < 2; nt++) {
    const size_t brow = (size_t)(wave*32 + nt*16 + l16);
#pragma unroll
    for (int kk = 0; kk < 128; kk += 32) {
      bf16x8 bh = *(const bf16x8*)&Bh[brow * 2*HC + kk + quad*8];
      bf16x8 bl = *(const bf16x8*)&Bl[brow * 2*HC + kk + quad*8];
#pragma unroll
      for (int mt = 0; mt < 4; mt++) {
        bf16x8 ah = *(const bf16x8*)&ldsA[0][mt*16 + l16][kk + quad*8];
        bf16x8 al = *(const bf16x8*)&ldsA[1][mt*16 + l16][kk + quad*8];
        acc[mt][nt] = __builtin_amdgcn_mfma_f32_16x16x32_bf16(ah, bh, acc[mt][nt], 0, 0, 0);
        acc[mt][nt] = __builtin_amdgcn_mfma_f32_16x16x32_bf16(ah, bl, acc[mt][nt], 0, 0, 0);
        acc[mt][nt] = __builtin_amdgcn_mfma_f32_16x16x32_bf16(al, bh, acc[mt][nt], 0, 0, 0);
      }
    }
#pragma unroll
    for (int kk = 0; kk < 128; kk += 32) {
      bf16x8 bh = *(const bf16x8*)&Bh[brow * 2*HC + HC + kk + quad*8];
      bf16x8 bl = *(const bf16x8*)&Bl[brow * 2*HC + HC + kk + quad*8];
#pragma unroll
      for (int mt = 0; mt < 4; mt++) {
        bf16x8 ah = *(const bf16x8*)&ldsH[0][mt*16 + l16][kk + quad*8];
        bf16x8 al = *(const bf16x8*)&ldsH[1][mt*16 + l16][kk + quad*8];
        acc[mt][nt] = __builtin_amdgcn_mfma_f32_16x16x32_bf16(ah, bh, acc[mt][nt], 0, 0, 0);
        acc[mt][nt] = __builtin_amdgcn_mfma_f32_16x16x32_bf16(ah, bl, acc[mt][nt], 0, 0, 0);
        acc[mt][nt] = __builtin_amdgcn_mfma_f32_16x16x32_bf16(al, bh, acc[mt][nt], 0, 0, 0);
      }
    }
  }

#pragma unroll
  for (int nt = 0; nt < 2; nt++) {
    const int col = wave*32 + nt*16 + l16;
    const float bz = bias[col];
#pragma unroll
    for (int mt = 0; mt < 4; mt++) {
      const int rowb = mt*16 + quad*4;
#pragma unroll
      for (int rr = 0; rr < 4; rr++) {
        const size_t idx = (size_t)(m0 + rowb + rr) * HC + col;
        ea[idx] = tanh_f(acc[mt][nt][rr] + bz) + ea[idx];
      }
    }
  }
}

// ---------------------------------------------------------------------------
// Fused node update: h = relu(ssp(agg @ l2^T + b2) @ l3^T + b3) + h.
// R14: 2-stage software pipeline on the agg chunk load.
__global__ __launch_bounds__(256, 2) void nodeup_kernel(
    const float* __restrict__ agg,
    const unsigned short* __restrict__ L2h, const unsigned short* __restrict__ L2l,
    const float* __restrict__ b2,
    const unsigned short* __restrict__ L3h, const unsigned short* __restrict__ L3l,
    const float* __restrict__ b3,
    float* h)
{
  __shared__ unsigned short lds[2 * 128 * 136];
  const int AH = 0, AL = 5120;            // A chunk staging (pitch 40)
  const int TH = 0, TL = 17408;           // t2 full tile (pitch 136)

  const int tid  = threadIdx.x;
  const int m0   = blockIdx.x * 128;
  const int lane = tid & 63, wave = tid >> 6;
  const int quad = lane >> 4, l16 = lane & 15;
  const int wm = (wave >> 1) * 64, wn = (wave & 1) * 64;
  const int r  = tid >> 1;
  const int c0 = (tid & 1) * 16;

  const f4v zf = {0.f, 0.f, 0.f, 0.f};
  f4v acc[4][4];
#pragma unroll
  for (int i = 0; i < 4; i++)
#pragma unroll
    for (int j = 0; j < 4; j++) acc[i][j] = zf;

  const bool mok = (m0 + r) < N_NODES;
  const size_t arow = (size_t)(m0 + r);

  float av[16];
  if (mok) {
    const float* ap = agg + arow * NFC + c0;
#pragma unroll
    for (int q = 0; q < 4; q++) *(float4*)&av[q*4] = *(const float4*)(ap + q*4);
  } else {
#pragma unroll
    for (int j = 0; j < 16; j++) av[j] = 0.f;
  }

  for (int kk = 0; kk < NFC; kk += 32) {
    float avn[16];
    if (kk + 32 < NFC) {                       // prefetch next chunk
      if (mok) {
        const float* ap = agg + arow * NFC + kk + 32 + c0;
#pragma unroll
        for (int q = 0; q < 4; q++) *(float4*)&avn[q*4] = *(const float4*)(ap + q*4);
      } else {
#pragma unroll
        for (int j = 0; j < 16; j++) avn[j] = 0.f;
      }
    }
    bf16x8 bh[4], bl[4];
#pragma unroll
    for (int nt = 0; nt < 4; nt++) {
      const size_t brow = (size_t)(wn + nt*16 + l16);
      bh[nt] = *(const bf16x8*)&L2h[brow * NFC + kk + quad*8];
      bl[nt] = *(const bf16x8*)&L2l[brow * NFC + kk + quad*8];
    }
    __syncthreads();
    unsigned short th[16], tl[16];
#pragma unroll
    for (int j = 0; j < 16; j++) {
      unsigned short hb = f2bf(av[j]);
      th[j] = hb; tl[j] = f2bf(av[j] - bf2f(hb));
    }
    *(bf16x8*)&lds[AH + r*40 + c0]     = *(bf16x8*)&th[0];
    *(bf16x8*)&lds[AH + r*40 + c0 + 8] = *(bf16x8*)&th[8];
    *(bf16x8*)&lds[AL + r*40 + c0]     = *(bf16x8*)&tl[0];
    *(bf16x8*)&lds[AL + r*40 + c0 + 8] = *(bf16x8*)&tl[8];
    __syncthreads();
    bf16x8 ah[4], al[4];
#pragma unroll
    for (int t = 0; t < 4; t++) {
      const int ra = (wm + t*16 + l16) * 40 + quad * 8;
      ah[t] = *(const bf16x8*)&lds[AH + ra];
      al[t] = *(const bf16x8*)&lds[AL + ra];
    }
#pragma unroll
    for (int mt = 0; mt < 4; mt++)
#pragma unroll
      for (int nt = 0; nt < 4; nt++) {
        acc[mt][nt] = __builtin_amdgcn_mfma_f32_16x16x32_bf16(ah[mt], bh[nt], acc[mt][nt], 0, 0, 0);
        acc[mt][nt] = __builtin_amdgcn_mfma_f32_16x16x32_bf16(ah[mt], bl[nt], acc[mt][nt], 0, 0, 0);
        acc[mt][nt] = __builtin_amdgcn_mfma_f32_16x16x32_bf16(al[mt], bh[nt], acc[mt][nt], 0, 0, 0);
      }
    if (kk + 32 < NFC) {
#pragma unroll
      for (int j = 0; j < 16; j++) av[j] = avn[j];
    }
  }
  __syncthreads();

#pragma unroll
  for (int nt = 0; nt < 4; nt++) {
    const int col = wn + nt*16 + l16;
    const float bz = b2[col];
#pragma unroll
    for (int mt = 0; mt < 4; mt++) {
      const int rowb = wm + mt*16 + quad*4;
#pragma unroll
      for (int rr = 0; rr < 4; rr++) {
        float v = ssp_f(acc[mt][nt][rr] + bz);
        unsigned short hb = f2bf(v);
        lds[TH + (rowb+rr)*136 + col] = hb;
        lds[TL + (rowb+rr)*136 + col] = f2bf(v - bf2f(hb));
      }
    }
  }
  __syncthreads();

  f4v acc2[4][4];
#pragma unroll
  for (int i = 0; i < 4; i++)
#pragma unroll
    for (int j = 0; j < 4; j++) acc2[i][j] = zf;

  for (int kk = 0; kk < HC; kk += 32) {
    bf16x8 bh[4], bl[4];
#pragma unroll
    for (int nt = 0; nt < 4; nt++) {
      const size_t brow = (size_t)(wn + nt*16 + l16);
      bh[nt] = *(const bf16x8*)&L3h[brow * HC + kk + quad*8];
      bl[nt] = *(const bf16x8*)&L3l[brow * HC + kk + quad*8];
    }
    bf16x8 ah[4], al[4];
#pragma unroll
    for (int t = 0; t < 4; t++) {
      const int ra = (wm + t*16 + l16) * 136 + kk + quad * 8;
      ah[t] = *(const bf16x8*)&lds[TH + ra];
      al[t] = *(const bf16x8*)&lds[TL + ra];
    }
#pragma unroll
    for (int mt = 0; mt < 4; mt++)
#pragma unroll
      for (int nt = 0; nt < 4; nt++) {
        acc2[mt][nt] = __builtin_amdgcn_mfma_f32_16x16x32_bf16(ah[mt], bh[nt], acc2[mt][nt], 0, 0, 0);
        acc2[mt][nt] = __builtin_amdgcn_mfma_f32_16x16x32_bf16(ah[mt], bl[nt], acc2[mt][nt], 0, 0, 0);
        acc2[mt][nt] = __builtin_amdgcn_mfma_f32_16x16x32_bf16(al[mt], bh[nt], acc2[mt][nt], 0, 0, 0);
      }
  }

#pragma unroll
  for (int nt = 0; nt < 4; nt++) {
    const int ncol = wn + nt*16 + l16;
    const float bz = b3[ncol];
#pragma unroll
    for (int mt = 0; mt < 4; mt++) {
      const int mb = wm + mt*16 + quad*4;
#pragma unroll
      for (int rr = 0; rr < 4; rr++) {
        const int m = m0 + mb + rr;
        if (m < N_NODES) {
          const size_t idx = (size_t)m * HC + ncol;
          h[idx] = fmaxf(acc2[mt][nt][rr] + bz, 0.f) + h[idx];
        }
      }
    }
  }
}

// ---------------------------------------------------------------------------
// Fused lin1 + filter MLP + in-register run-reduced scatter (R11 structure).
// R14: all 4 h-gather chunks prefetched into regs right after sS is visible.
__device__ __forceinline__ int sigma_row(int r) {
  return ((r >> 2) & 3) * 16 + (r >> 4) * 4 + (r & 3);
}
__global__ __launch_bounds__(256, 3) void ffs_kernel(
    const float* __restrict__ ea,
    const unsigned short* __restrict__ l1h, const unsigned short* __restrict__ l1l,
    const unsigned short* __restrict__ fw1h, const unsigned short* __restrict__ fw1l,
    const float* __restrict__ fb1,
    const unsigned short* __restrict__ fw2h, const unsigned short* __restrict__ fw2l,
    const float* __restrict__ fb2, const int* __restrict__ ei,
    const int* __restrict__ perm,
    const float* __restrict__ hfeat, float* agg)
{
  __shared__ unsigned short ldsA[2][64][136];
  __shared__ unsigned short ldsT[2][64][72];
  __shared__ int sS[64], sD[64];

  const int tid  = threadIdx.x;
  const int m0   = blockIdx.x * 64;
  const int lane = tid & 63, wave = tid >> 6;
  const int quad = lane >> 4, l16 = lane & 15;

  {
    const int r = tid >> 2, cb = (tid & 3) * 32;
    const int pe = perm[m0 + sigma_row(r)];
    const float* ap = ea + (size_t)pe * HC + cb;
    unsigned short th[32], tl[32];
#pragma unroll
    for (int q = 0; q < 8; q++) {
      float4 v = *(const float4*)(ap + q*4);
      float vv[4] = {v.x, v.y, v.z, v.w};
#pragma unroll
      for (int e = 0; e < 4; e++) {
        unsigned short hb = f2bf(vv[e]);
        th[q*4+e] = hb; tl[q*4+e] = f2bf(vv[e] - bf2f(hb));
      }
    }
#pragma unroll
    for (int q = 0; q < 4; q++) {
      *(bf16x8*)&ldsA[0][r][cb + q*8] = *(bf16x8*)&th[q*8];
      *(bf16x8*)&ldsA[1][r][cb + q*8] = *(bf16x8*)&tl[q*8];
    }
  }
  if (tid < 64) {
    int pe = perm[m0 + sigma_row(tid)];
    sS[tid] = ei[pe];
    sD[tid] = ei[N_EDGES + pe];
  }

  const f4v zf = {0.f, 0.f, 0.f, 0.f};
  __syncthreads();   // sS visible; ldsA(ea) staged

  // ---- prefetch ALL 4 h-gather chunks (overlapping latencies) ----
  float hv[4][8];
  {
    const int r = tid >> 2, c8 = (tid & 3) * 8;
    const float* hp_ = hfeat + (size_t)sS[r] * HC + c8;
#pragma unroll
    for (int p = 0; p < 4; p++) {
      *(float4*)&hv[p][0] = *(const float4*)(hp_ + p*32);
      *(float4*)&hv[p][4] = *(const float4*)(hp_ + p*32 + 4);
    }
  }

  f4v hacc[4][4];
#pragma unroll
  for (int mt = 0; mt < 4; mt++)
#pragma unroll
    for (int nt = 0; nt < 4; nt++) hacc[mt][nt] = zf;

  unsigned short* ldsF = &ldsT[0][0][0];
  for (int p = 0; p < 4; p++) {
    const int kk = p * 32;
    {
      const int r = tid >> 2, c8 = (tid & 3) * 8;
      unsigned short th[8], tl[8];
#pragma unroll
      for (int e = 0; e < 8; e++) {
        unsigned short hb = f2bf(hv[p][e]);
        th[e] = hb; tl[e] = f2bf(hv[p][e] - bf2f(hb));
      }
      *(bf16x8*)&ldsF[r*40 + c8]        = *(bf16x8*)&th[0];
      *(bf16x8*)&ldsF[2560 + r*40 + c8] = *(bf16x8*)&tl[0];
    }
    __syncthreads();
#pragma unroll
    for (int nt = 0; nt < 4; nt++) {
      const size_t brow = (size_t)(wave*64 + nt*16 + l16);
      bf16x8 bh = *(const bf16x8*)&l1h[brow * HC + kk + quad*8];
      bf16x8 bl = *(const bf16x8*)&l1l[brow * HC + kk + quad*8];
#pragma unroll
      for (int mt = 0; mt < 4; mt++) {
        bf16x8 ah = *(const bf16x8*)&ldsF[(mt*16 + l16)*40 + quad*8];
        bf16x8 al = *(const bf16x8*)&ldsF[2560 + (mt*16 + l16)*40 + quad*8];
        hacc[mt][nt] = __builtin_amdgcn_mfma_f32_16x16x32_bf16(ah, bh, hacc[mt][nt], 0, 0, 0);
        hacc[mt][nt] = __builtin_amdgcn_mfma_f32_16x16x32_bf16(ah, bl, hacc[mt][nt], 0, 0, 0);
        hacc[mt][nt] = __builtin_amdgcn_mfma_f32_16x16x32_bf16(al, bh, hacc[mt][nt], 0, 0, 0);
      }
    }
    __syncthreads();
  }

  f4v wacc[4][4];
#pragma unroll
  for (int mt = 0; mt < 4; mt++)
#pragma unroll
    for (int nt = 0; nt < 4; nt++) wacc[mt][nt] = zf;

  for (int p = 0; p < 4; p++) {
    f4v tacc[4];
#pragma unroll
    for (int mt = 0; mt < 4; mt++) tacc[mt] = zf;
    const size_t b1row = (size_t)(p*64 + wave*16 + l16);
#pragma unroll
    for (int kk = 0; kk < 128; kk += 32) {
      bf16x8 bh = *(const bf16x8*)&fw1h[b1row * HC + kk + quad*8];
      bf16x8 bl = *(const bf16x8*)&fw1l[b1row * HC + kk + quad*8];
#pragma unroll
      for (int mt = 0; mt < 4; mt++) {
        bf16x8 ah = *(const bf16x8*)&ldsA[0][mt*16 + l16][kk + quad*8];
        bf16x8 al = *(const bf16x8*)&ldsA[1][mt*16 + l16][kk + quad*8];
        tacc[mt] = __builtin_amdgcn_mfma_f32_16x16x32_bf16(ah, bh, tacc[mt], 0, 0, 0);
        tacc[mt] = __builtin_amdgcn_mfma_f32_16x16x32_bf16(ah, bl, tacc[mt], 0, 0, 0);
        tacc[mt] = __builtin_amdgcn_mfma_f32_16x16x32_bf16(al, bh, tacc[mt], 0, 0, 0);
      }
    }
    {
      const int col = wave*16 + l16;
      const float bz = fb1[p*64 + col];
#pragma unroll
      for (int mt = 0; mt < 4; mt++) {
        const int rowb = mt*16 + quad*4;
#pragma unroll
        for (int rr = 0; rr < 4; rr++) {
          float v = ssp_f(tacc[mt][rr] + bz);
          unsigned short hb = f2bf(v);
          ldsT[0][rowb+rr][col] = hb;
          ldsT[1][rowb+rr][col] = f2bf(v - bf2f(hb));
        }
      }
    }
    __syncthreads();

#pragma unroll
    for (int kc = 0; kc < 2; kc++) {
      bf16x8 a_h[4], a_l[4];
#pragma unroll
      for (int mt = 0; mt < 4; mt++) {
        a_h[mt] = *(const bf16x8*)&ldsT[0][mt*16 + l16][kc*32 + quad*8];
        a_l[mt] = *(const bf16x8*)&ldsT[1][mt*16 + l16][kc*32 + quad*8];
      }
#pragma unroll
      for (int nt = 0; nt < 4; nt++) {
        const size_t brow = (size_t)(wave*64 + nt*16 + l16);
        bf16x8 bh = *(const bf16x8*)&fw2h[brow * NFC + p*64 + kc*32 + quad*8];
        bf16x8 bl = *(const bf16x8*)&fw2l[brow * NFC + p*64 + kc*32 + quad*8];
#pragma unroll
        for (int mt = 0; mt < 4; mt++) {
          wacc[mt][nt] = __builtin_amdgcn_mfma_f32_16x16x32_bf16(a_h[mt], bh, wacc[mt][nt], 0, 0, 0);
          wacc[mt][nt] = __builtin_amdgcn_mfma_f32_16x16x32_bf16(a_h[mt], bl, wacc[mt][nt], 0, 0, 0);
          wacc[mt][nt] = __builtin_amdgcn_mfma_f32_16x16x32_bf16(a_l[mt], bh, wacc[mt][nt], 0, 0, 0);
        }
      }
    }
    __syncthreads();
  }

#pragma unroll
  for (int nt = 0; nt < 4; nt++) {
    const int col = wave*64 + nt*16 + l16;
    const float bz = fb2[col];
    float accum = 0.f;
    int prev = -1;
#pragma unroll
    for (int mt = 0; mt < 4; mt++) {
#pragma unroll
      for (int rr = 0; rr < 4; rr++) {
        const int prow = mt*16 + quad*4 + rr;
        const int d = sD[prow];
        const float v = (wacc[mt][nt][rr] + bz) * hacc[mt][nt][rr];
        if (d != prev) {
          if (prev >= 0) atomicAdd(&agg[(size_t)prev * NFC + col], accum);
          accum = v; prev = d;
        } else {
          accum += v;
        }
      }
    }
    atomicAdd(&agg[(size_t)prev * NFC + col], accum);
  }
}

// ---------------------------------------------------------------------------
__global__ void pool_kernel(const int* __restrict__ batch, const float* __restrict__ h,
                            float* __restrict__ ssum, float* __restrict__ cnt) {
  int idx = blockIdx.x * blockDim.x + threadIdx.x;
  if (idx >= N_NODES * HC) return;
  int n = idx >> 7, c = idx & 127;
  int b = batch[n];
  atomicAdd(&ssum[(size_t)b*HC + c], h[idx]);
  if (c == 0) atomicAdd(&cnt[b], 1.0f);
}

__global__ __launch_bounds__(256) void head_kernel(
    const float* __restrict__ ssum, const float* __restrict__ cnt,
    const float* __restrict__ w1, const float* __restrict__ b1,
    const float* __restrict__ w2, const float* __restrict__ b2,
    float* __restrict__ y) {
  int g = blockIdx.x;
  __shared__ float gs[HC];
  __shared__ float red[256];
  int tid = threadIdx.x;
  float inv = 1.0f / fmaxf(cnt[g], 1.0f);
  if (tid < HC) gs[tid] = ssum[(size_t)g*HC + tid] * inv;
  __syncthreads();
  float partial = 0.0f;
  for (int f = tid; f < NFFC; f += 256) {
    float acc = b1[f];
    const float* wr = w1 + (size_t)f*HC;
#pragma unroll 8
    for (int k = 0; k < HC; k++) acc = fmaf(gs[k], wr[k], acc);
    float t = 0.5f * acc * (1.0f + erff(acc * 0.70710678118654752440f));
    partial = fmaf(t, w2[f], partial);
  }
  red[tid] = partial;
  __syncthreads();
  for (int s = 128; s > 0; s >>= 1) {
    if (tid < s) red[tid] += red[tid + s];
    __syncthreads();
  }
  if (tid == 0) y[g] = red[0] + b2[0];
}

// ---------------------------------------------------------------------------
extern "C" void kernel_launch(void* const* d_in, const int* in_sizes, int n_in,
                              void* d_out, int out_size, void* d_ws, size_t ws_size,
                              hipStream_t stream) {
  const int*   x     = (const int*)  d_in[0];
  const int*   ei    = (const int*)  d_in[1];
  const float* eattr = (const float*)d_in[2];
  const int*   batch = (const int*)  d_in[3];
  const float* pos   = (const float*)d_in[4];
  const float* vert  = (const float*)d_in[5];
  const float* posw  = (const float*)d_in[6];
  const float* edgew = (const float*)d_in[7];
  const float* fw1   = (const float*)d_in[8];
  const float* fb1   = (const float*)d_in[9];
  const float* fw2   = (const float*)d_in[10];
  const float* fb2   = (const float*)d_in[11];
  const float* l1w   = (const float*)d_in[12];
  const float* l2w   = (const float*)d_in[13];
  const float* l2b   = (const float*)d_in[14];
  const float* l3w   = (const float*)d_in[15];
  const float* l3b   = (const float*)d_in[16];
  const float* emw   = (const float*)d_in[17];
  const float* emb   = (const float*)d_in[18];
  const float* hw1   = (const float*)d_in[19];
  const float* hb1   = (const float*)d_in[20];
  const float* hw2   = (const float*)d_in[21];
  const float* hb2   = (const float*)d_in[22];
  float* out = (float*)d_out;

  char* ws = (char*)d_ws;
  size_t off = 0;
  auto alloc = [&](size_t bytes) { char* p = ws + off; off += (bytes + 511) & ~(size_t)511; return p; };
  float* ea   = (float*)alloc((size_t)N_EDGES*HC*4);
  float* h    = (float*)alloc((size_t)N_NODES*HC*4);
  float* agg  = (float*)alloc((size_t)N_NODES*NFC*4);
  float* ssum = (float*)alloc((size_t)N_GRAPH*HC*4);
  float* cnt  = (float*)alloc((size_t)N_GRAPH*4);
  int* deg    = (int*)alloc((size_t)(N_NODES+1)*4);
  int* cursor = (int*)alloc((size_t)(N_NODES+1)*4);
  int* perm   = (int*)alloc((size_t)N_EDGES*4);
  const int n_fw1 = NLAYER*NFC*HC, n_fw2 = NLAYER*NFC*NFC, n_l1 = NLAYER*NFC*HC;
  const int n_l2 = NLAYER*HC*NFC, n_l3 = NLAYER*HC*HC, n_em = NLAYER*HC*2*HC;
  unsigned short* fw1h = (unsigned short*)alloc((size_t)n_fw1*2);
  unsigned short* fw1l = (unsigned short*)alloc((size_t)n_fw1*2);
  unsigned short* fw2h = (unsigned short*)alloc((size_t)n_fw2*2);
  unsigned short* fw2l = (unsigned short*)alloc((size_t)n_fw2*2);
  unsigned short* l1h  = (unsigned short*)alloc((size_t)n_l1*2);
  unsigned short* l1l  = (unsigned short*)alloc((size_t)n_l1*2);
  unsigned short* l2h  = (unsigned short*)alloc((size_t)n_l2*2);
  unsigned short* l2l  = (unsigned short*)alloc((size_t)n_l2*2);
  unsigned short* l3h  = (unsigned short*)alloc((size_t)n_l3*2);
  unsigned short* l3l  = (unsigned short*)alloc((size_t)n_l3*2);
  unsigned short* emh  = (unsigned short*)alloc((size_t)n_em*2);
  unsigned short* eml  = (unsigned short*)alloc((size_t)n_em*2);

  zeroi_kernel<<<(N_NODES+1+255)/256, 256, 0, stream>>>(deg, N_NODES+1);
  hist_kernel<<<(N_EDGES+255)/256, 256, 0, stream>>>(ei, deg);
  scan_kernel<<<1, 1024, 0, stream>>>(deg, cursor, N_NODES+1);
  perm_kernel<<<(N_EDGES+255)/256, 256, 0, stream>>>(ei, cursor, perm);

  wsplit_kernel<<<(n_fw1+255)/256, 256, 0, stream>>>(fw1, fw1h, fw1l, n_fw1);
  wsplit_kernel<<<(n_fw2+255)/256, 256, 0, stream>>>(fw2, fw2h, fw2l, n_fw2);
  wsplit_kernel<<<(n_l1 +255)/256, 256, 0, stream>>>(l1w, l1h, l1l, n_l1);
  wsplit_kernel<<<(n_l2 +255)/256, 256, 0, stream>>>(l2w, l2h, l2l, n_l2);
  wsplit_kernel<<<(n_l3 +255)/256, 256, 0, stream>>>(l3w, l3h, l3l, n_l3);
  wsplit_kernel<<<(n_em +255)/256, 256, 0, stream>>>(emw, emh, eml, n_em);

  const int GN   = (N_NODES + 127) / 128;   // 391
  const int GE64 = N_EDGES / 64;            // 3125 (exact)

  embed_kernel<<<N_NODES, 128, 0, stream>>>(x, pos, vert, posw, h);
  edgeproj_kernel<<<(N_EDGES*HC + 255)/256, 256, 0, stream>>>(eattr, edgew, ea);

  for (int i = 0; i < NLAYER; ++i) {
    zero_kernel<<<((N_NODES*NFC/4) + 255)/256, 256, 0, stream>>>(
        (float4*)agg, N_NODES*NFC/4);
    ffs_kernel<<<GE64, 256, 0, stream>>>(
        ea, l1h + (size_t)i*NFC*HC, l1l + (size_t)i*NFC*HC,
        fw1h + (size_t)i*NFC*HC, fw1l + (size_t)i*NFC*HC, fb1 + (size_t)i*NFC,
        fw2h + (size_t)i*NFC*NFC, fw2l + (size_t)i*NFC*NFC, fb2 + (size_t)i*NFC,
        ei, perm, h, agg);
    nodeup_kernel<<<GN, 256, 0, stream>>>(
        agg, l2h + (size_t)i*HC*NFC, l2l + (size_t)i*HC*NFC, l2b + (size_t)i*HC,
        l3h + (size_t)i*HC*HC, l3l + (size_t)i*HC*HC, l3b + (size_t)i*HC, h);
    if (i < NLAYER - 1) {
      emlite_kernel<<<GE64, 256, 0, stream>>>(
          ea, emh + (size_t)i*HC*2*HC, eml + (size_t)i*HC*2*HC, emb + (size_t)i*HC,
          ei, h);
    }
  }

  zero_kernel<<<((N_GRAPH*HC/4) + 255)/256, 256, 0, stream>>>((float4*)ssum, N_GRAPH*HC/4);
  zero_kernel<<<((N_GRAPH/4) + 255)/256, 256, 0, stream>>>((float4*)cnt, N_GRAPH/4);
  pool_kernel<<<(N_NODES*HC + 255)/256, 256, 0, stream>>>(batch, h, ssum, cnt);
  head_kernel<<<N_GRAPH, 256, 0, stream>>>(ssum, cnt, hw1, hb1, hw2, hb2, out);
}

// Round 15
// 2542.620 us; speedup vs baseline: 1.0176x; 1.0099x over previous
//
#include <hip/hip_runtime.h>
#include <hip/hip_bf16.h>
#include <math.h>

#define N_NODES 50000
#define N_EDGES 200000
#define N_GRAPH 1024
#define HC      128
#define NFC     256
#define NLAYER  5
#define NFFC    512

typedef short bf16x8 __attribute__((ext_vector_type(8)));
typedef float f4v    __attribute__((ext_vector_type(4)));

// fast ssp: softplus(x)-ln2 via v_exp/v_log (~1e-7 abs err)
__device__ __forceinline__ float ssp_f(float x) {
  float e = __expf(-fabsf(x));
  return fmaxf(x, 0.0f) + __logf(1.0f + e) - 0.69314718055994530942f;
}
// fast tanh via v_exp + v_rcp (~1e-6 err); overflow-safe
__device__ __forceinline__ float tanh_f(float x) {
  float e = __expf(2.0f * fabsf(x));
  float t = 1.0f - 2.0f * __builtin_amdgcn_rcpf(e + 1.0f);
  return copysignf(t, x);
}
__device__ __forceinline__ unsigned short f2bf(float x) {
  union { float f; unsigned u; } v; v.f = x;
  unsigned r = v.u + 0x7fff + ((v.u >> 16) & 1);
  return (unsigned short)(r >> 16);
}
__device__ __forceinline__ float bf2f(unsigned short b) {
  union { unsigned u; float f; } v; v.u = (unsigned)b << 16; return v.f;
}

// ---------------------------------------------------------------------------
__global__ void zero_kernel(float4* __restrict__ p, int n4) {
  int i = blockIdx.x * blockDim.x + threadIdx.x;
  if (i < n4) p[i] = make_float4(0.f, 0.f, 0.f, 0.f);
}
__global__ void zeroi_kernel(int* __restrict__ p, int n) {
  int i = blockIdx.x * blockDim.x + threadIdx.x;
  if (i < n) p[i] = 0;
}

// ---- dst-sort infrastructure ----------------------------------------------
__global__ void hist_kernel(const int* __restrict__ ei, int* __restrict__ deg) {
  int e = blockIdx.x * blockDim.x + threadIdx.x;
  if (e < N_EDGES) atomicAdd(&deg[ei[N_EDGES + e]], 1);
}
__global__ __launch_bounds__(1024) void scan_kernel(
    const int* __restrict__ deg, int* __restrict__ cursor, int n) {
  __shared__ int buf[1024];
  __shared__ int carry;
  if (threadIdx.x == 0) carry = 0;
  __syncthreads();
  for (int base = 0; base < n; base += 1024) {
    int i = base + threadIdx.x;
    int v = (i < n) ? deg[i] : 0;
    buf[threadIdx.x] = v;
    __syncthreads();
    for (int s = 1; s < 1024; s <<= 1) {
      int t = (threadIdx.x >= s) ? buf[threadIdx.x - s] : 0;
      __syncthreads();
      buf[threadIdx.x] += t;
      __syncthreads();
    }
    int excl = carry + buf[threadIdx.x] - v;
    if (i < n) cursor[i] = excl;
    int tot = buf[1023];
    __syncthreads();
    if (threadIdx.x == 0) carry += tot;
    __syncthreads();
  }
}
__global__ void perm_kernel(const int* __restrict__ ei, int* __restrict__ cursor,
                            int* __restrict__ perm) {
  int e = blockIdx.x * blockDim.x + threadIdx.x;
  if (e < N_EDGES) {
    int d = ei[N_EDGES + e];
    int p = atomicAdd(&cursor[d], 1);
    perm[p] = e;
  }
}

// split fp32 weights -> bf16 hi + lo
__global__ void wsplit_kernel(const float* __restrict__ w,
                              unsigned short* __restrict__ hi,
                              unsigned short* __restrict__ lo, int n) {
  int i = blockIdx.x * blockDim.x + threadIdx.x;
  if (i < n) {
    float v = w[i];
    unsigned short hb = f2bf(v);
    hi[i] = hb;
    lo[i] = f2bf(v - bf2f(hb));
  }
}

__global__ void embed_kernel(const int* __restrict__ x, const float* __restrict__ pos,
                             const float* __restrict__ vert, const float* __restrict__ posw,
                             float* __restrict__ h) {
  int n = blockIdx.x;
  int c = threadIdx.x;            // 128 threads
  float v;
  if (c < 80) {
    v = vert[(size_t)x[n] * 80 + c];
  } else {
    int j = c - 80;
    v = pos[n*3+0]*posw[j*3+0] + pos[n*3+1]*posw[j*3+1] + pos[n*3+2]*posw[j*3+2];
  }
  h[(size_t)n*HC + c] = v;
}

__global__ void edgeproj_kernel(const float* __restrict__ eattr, const float* __restrict__ ew,
                                float* __restrict__ ea) {
  int idx = blockIdx.x * blockDim.x + threadIdx.x;
  if (idx >= N_EDGES * HC) return;
  int e = idx >> 7, c = idx & 127;
  const float* a = eattr + (size_t)e*4;
  const float* w = ew + (size_t)c*4;
  ea[idx] = a[0]*w[0] + a[1]*w[1] + a[2]*w[2] + a[3]*w[3];
}

// ---------------------------------------------------------------------------
// Edge-MLP: 64-edge tile, 256 threads, ONE barrier.
// ea = tanh(cat(ea, h[src]+h[dst]) @ emw^T + emb) + ea, in place.
__global__ __launch_bounds__(256, 2) void emlite_kernel(
    float* ea,
    const unsigned short* __restrict__ Bh, const unsigned short* __restrict__ Bl,
    const float* __restrict__ bias, const int* __restrict__ ei,
    const float* __restrict__ hfeat)
{
  __shared__ unsigned short ldsA[2][64][136];   // ea split
  __shared__ unsigned short ldsH[2][64][136];   // hsum split

  const int tid  = threadIdx.x;
  const int m0   = blockIdx.x * 64;             // N_EDGES % 64 == 0
  const int lane = tid & 63, wave = tid >> 6;
  const int quad = lane >> 4, l16 = lane & 15;
  const int r = tid >> 2, cb = (tid & 3) * 32;

  const int e = m0 + r;
  const int s = ei[e], d = ei[N_EDGES + e];

  {
    const float* ap = ea + (size_t)e * HC + cb;
    float v[32];
#pragma unroll
    for (int q = 0; q < 8; q++) *(float4*)&v[q*4] = *(const float4*)(ap + q*4);
    unsigned short th[32], tl[32];
#pragma unroll
    for (int j = 0; j < 32; j++) {
      unsigned short hb = f2bf(v[j]);
      th[j] = hb; tl[j] = f2bf(v[j] - bf2f(hb));
    }
#pragma unroll
    for (int q = 0; q < 4; q++) {
      *(bf16x8*)&ldsA[0][r][cb + q*8] = *(bf16x8*)&th[q*8];
      *(bf16x8*)&ldsA[1][r][cb + q*8] = *(bf16x8*)&tl[q*8];
    }
  }
  {
    const float* p1 = hfeat + (size_t)s * HC + cb;
    const float* p2 = hfeat + (size_t)d * HC + cb;
    float v[32];
#pragma unroll
    for (int q = 0; q < 8; q++) {
      float4 xa = *(const float4*)(p1 + q*4);
      float4 xb = *(const float4*)(p2 + q*4);
      v[q*4+0] = xa.x + xb.x; v[q*4+1] = xa.y + xb.y;
      v[q*4+2] = xa.z + xb.z; v[q*4+3] = xa.w + xb.w;
    }
    unsigned short th[32], tl[32];
#pragma unroll
    for (int j = 0; j < 32; j++) {
      unsigned short hb = f2bf(v[j]);
      th[j] = hb; tl[j] = f2bf(v[j] - bf2f(hb));
    }
#pragma unroll
    for (int q = 0; q < 4; q++) {
      *(bf16x8*)&ldsH[0][r][cb + q*8] = *(bf16x8*)&th[q*8];
      *(bf16x8*)&ldsH[1][r][cb + q*8] = *(bf16x8*)&tl[q*8];
    }
  }

  const f4v zf = {0.f, 0.f, 0.f, 0.f};
  f4v acc[4][2];
#pragma unroll
  for (int mt = 0; mt < 4; mt++) { acc[mt][0] = zf; acc[mt][1] = zf; }

  __syncthreads();   // the only barrier

#pragma unroll
  for (int nt = 0; nt < 2; nt++) {
    const size_t brow = (size_t)(wave*32 + nt*16 + l16);
#pragma unroll
    for (int kk = 0; kk < 128; kk += 32) {
      bf16x8 bh = *(const bf16x8*)&Bh[brow * 2*HC + kk + quad*8];
      bf16x8 bl = *(const bf16x8*)&Bl[brow * 2*HC + kk + quad*8];
#pragma unroll
      for (int mt = 0; mt < 4; mt++) {
        bf16x8 ah = *(const bf16x8*)&ldsA[0][mt*16 + l16][kk + quad*8];
        bf16x8 al = *(const bf16x8*)&ldsA[1][mt*16 + l16][kk + quad*8];
        acc[mt][nt] = __builtin_amdgcn_mfma_f32_16x16x32_bf16(ah, bh, acc[mt][nt], 0, 0, 0);
        acc[mt][nt] = __builtin_amdgcn_mfma_f32_16x16x32_bf16(ah, bl, acc[mt][nt], 0, 0, 0);
        acc[mt][nt] = __builtin_amdgcn_mfma_f32_16x16x32_bf16(al, bh, acc[mt][nt], 0, 0, 0);
      }
    }
#pragma unroll
    for (int kk = 0; kk < 128; kk += 32) {
      bf16x8 bh = *(const bf16x8*)&Bh[brow * 2*HC + HC + kk + quad*8];
      bf16x8 bl = *(const bf16x8*)&Bl[brow * 2*HC + HC + kk + quad*8];
#pragma unroll
      for (int mt = 0; mt < 4; mt++) {
        bf16x8 ah = *(const bf16x8*)&ldsH[0][mt*16 + l16][kk + quad*8];
        bf16x8 al = *(const bf16x8*)&ldsH[1][mt*16 + l16][kk + quad*8];
        acc[mt][nt] = __builtin_amdgcn_mfma_f32_16x16x32_bf16(ah, bh, acc[mt][nt], 0, 0, 0);
        acc[mt][nt] = __builtin_amdgcn_mfma_f32_16x16x32_bf16(ah, bl, acc[mt][nt], 0, 0, 0);
        acc[mt][nt] = __builtin_amdgcn_mfma_f32_16x16x32_bf16(al, bh, acc[mt][nt], 0, 0, 0);
      }
    }
  }

#pragma unroll
  for (int nt = 0; nt < 2; nt++) {
    const int col = wave*32 + nt*16 + l16;
    const float bz = bias[col];
#pragma unroll
    for (int mt = 0; mt < 4; mt++) {
      const int rowb = mt*16 + quad*4;
#pragma unroll
      for (int rr = 0; rr < 4; rr++) {
        const size_t idx = (size_t)(m0 + rowb + rr) * HC + col;
        ea[idx] = tanh_f(acc[mt][nt][rr] + bz) + ea[idx];
      }
    }
  }
}

// ---------------------------------------------------------------------------
// Fused node update: h = relu(ssp(agg @ l2^T + b2) @ l3^T + b3) + h.
// R15: zeroes its own agg rows after the GEMM1 reads complete (replaces the
// per-layer zero_kernel; next layer's ffs accumulates into clean agg).
__global__ __launch_bounds__(256, 2) void nodeup_kernel(
    float* __restrict__ agg,
    const unsigned short* __restrict__ L2h, const unsigned short* __restrict__ L2l,
    const float* __restrict__ b2,
    const unsigned short* __restrict__ L3h, const unsigned short* __restrict__ L3l,
    const float* __restrict__ b3,
    float* h)
{
  __shared__ unsigned short lds[2 * 128 * 136];
  const int AH = 0, AL = 5120;            // A chunk staging (pitch 40)
  const int TH = 0, TL = 17408;           // t2 full tile (pitch 136)

  const int tid  = threadIdx.x;
  const int m0   = blockIdx.x * 128;
  const int lane = tid & 63, wave = tid >> 6;
  const int quad = lane >> 4, l16 = lane & 15;
  const int wm = (wave >> 1) * 64, wn = (wave & 1) * 64;
  const int r  = tid >> 1;
  const int c0 = (tid & 1) * 16;

  const f4v zf = {0.f, 0.f, 0.f, 0.f};
  f4v acc[4][4];
#pragma unroll
  for (int i = 0; i < 4; i++)
#pragma unroll
    for (int j = 0; j < 4; j++) acc[i][j] = zf;

  const bool mok = (m0 + r) < N_NODES;
  const size_t arow = (size_t)(m0 + r);

  float av[16];
  if (mok) {
    const float* ap = agg + arow * NFC + c0;
#pragma unroll
    for (int q = 0; q < 4; q++) *(float4*)&av[q*4] = *(const float4*)(ap + q*4);
  } else {
#pragma unroll
    for (int j = 0; j < 16; j++) av[j] = 0.f;
  }

  for (int kk = 0; kk < NFC; kk += 32) {
    float avn[16];
    if (kk + 32 < NFC) {
      if (mok) {
        const float* ap = agg + arow * NFC + kk + 32 + c0;
#pragma unroll
        for (int q = 0; q < 4; q++) *(float4*)&avn[q*4] = *(const float4*)(ap + q*4);
      } else {
#pragma unroll
        for (int j = 0; j < 16; j++) avn[j] = 0.f;
      }
    }
    bf16x8 bh[4], bl[4];
#pragma unroll
    for (int nt = 0; nt < 4; nt++) {
      const size_t brow = (size_t)(wn + nt*16 + l16);
      bh[nt] = *(const bf16x8*)&L2h[brow * NFC + kk + quad*8];
      bl[nt] = *(const bf16x8*)&L2l[brow * NFC + kk + quad*8];
    }
    __syncthreads();
    unsigned short th[16], tl[16];
#pragma unroll
    for (int j = 0; j < 16; j++) {
      unsigned short hb = f2bf(av[j]);
      th[j] = hb; tl[j] = f2bf(av[j] - bf2f(hb));
    }
    *(bf16x8*)&lds[AH + r*40 + c0]     = *(bf16x8*)&th[0];
    *(bf16x8*)&lds[AH + r*40 + c0 + 8] = *(bf16x8*)&th[8];
    *(bf16x8*)&lds[AL + r*40 + c0]     = *(bf16x8*)&tl[0];
    *(bf16x8*)&lds[AL + r*40 + c0 + 8] = *(bf16x8*)&tl[8];
    __syncthreads();
    bf16x8 ah[4], al[4];
#pragma unroll
    for (int t = 0; t < 4; t++) {
      const int ra = (wm + t*16 + l16) * 40 + quad * 8;
      ah[t] = *(const bf16x8*)&lds[AH + ra];
      al[t] = *(const bf16x8*)&lds[AL + ra];
    }
#pragma unroll
    for (int mt = 0; mt < 4; mt++)
#pragma unroll
      for (int nt = 0; nt < 4; nt++) {
        acc[mt][nt] = __builtin_amdgcn_mfma_f32_16x16x32_bf16(ah[mt], bh[nt], acc[mt][nt], 0, 0, 0);
        acc[mt][nt] = __builtin_amdgcn_mfma_f32_16x16x32_bf16(ah[mt], bl[nt], acc[mt][nt], 0, 0, 0);
        acc[mt][nt] = __builtin_amdgcn_mfma_f32_16x16x32_bf16(al[mt], bh[nt], acc[mt][nt], 0, 0, 0);
      }
    if (kk + 32 < NFC) {
#pragma unroll
      for (int j = 0; j < 16; j++) av[j] = avn[j];
    }
  }
  __syncthreads();   // ALL threads' agg reads complete here

  // ---- zero this block's agg rows for the next layer's scatter ----
  if (mok) {
    float4* zp = (float4*)(agg + arow * NFC + (tid & 1) * 128);
    const float4 z4 = make_float4(0.f, 0.f, 0.f, 0.f);
#pragma unroll
    for (int q = 0; q < 32; q++) zp[q] = z4;
  }

#pragma unroll
  for (int nt = 0; nt < 4; nt++) {
    const int col = wn + nt*16 + l16;
    const float bz = b2[col];
#pragma unroll
    for (int mt = 0; mt < 4; mt++) {
      const int rowb = wm + mt*16 + quad*4;
#pragma unroll
      for (int rr = 0; rr < 4; rr++) {
        float v = ssp_f(acc[mt][nt][rr] + bz);
        unsigned short hb = f2bf(v);
        lds[TH + (rowb+rr)*136 + col] = hb;
        lds[TL + (rowb+rr)*136 + col] = f2bf(v - bf2f(hb));
      }
    }
  }
  __syncthreads();

  f4v acc2[4][4];
#pragma unroll
  for (int i = 0; i < 4; i++)
#pragma unroll
    for (int j = 0; j < 4; j++) acc2[i][j] = zf;

  for (int kk = 0; kk < HC; kk += 32) {
    bf16x8 bh[4], bl[4];
#pragma unroll
    for (int nt = 0; nt < 4; nt++) {
      const size_t brow = (size_t)(wn + nt*16 + l16);
      bh[nt] = *(const bf16x8*)&L3h[brow * HC + kk + quad*8];
      bl[nt] = *(const bf16x8*)&L3l[brow * HC + kk + quad*8];
    }
    bf16x8 ah[4], al[4];
#pragma unroll
    for (int t = 0; t < 4; t++) {
      const int ra = (wm + t*16 + l16) * 136 + kk + quad * 8;
      ah[t] = *(const bf16x8*)&lds[TH + ra];
      al[t] = *(const bf16x8*)&lds[TL + ra];
    }
#pragma unroll
    for (int mt = 0; mt < 4; mt++)
#pragma unroll
      for (int nt = 0; nt < 4; nt++) {
        acc2[mt][nt] = __builtin_amdgcn_mfma_f32_16x16x32_bf16(ah[mt], bh[nt], acc2[mt][nt], 0, 0, 0);
        acc2[mt][nt] = __builtin_amdgcn_mfma_f32_16x16x32_bf16(ah[mt], bl[nt], acc2[mt][nt], 0, 0, 0);
        acc2[mt][nt] = __builtin_amdgcn_mfma_f32_16x16x32_bf16(al[mt], bh[nt], acc2[mt][nt], 0, 0, 0);
      }
  }

#pragma unroll
  for (int nt = 0; nt < 4; nt++) {
    const int ncol = wn + nt*16 + l16;
    const float bz = b3[ncol];
#pragma unroll
    for (int mt = 0; mt < 4; mt++) {
      const int mb = wm + mt*16 + quad*4;
#pragma unroll
      for (int rr = 0; rr < 4; rr++) {
        const int m = m0 + mb + rr;
        if (m < N_NODES) {
          const size_t idx = (size_t)m * HC + ncol;
          h[idx] = fmaxf(acc2[mt][nt][rr] + bz, 0.f) + h[idx];
        }
      }
    }
  }
}

// ---------------------------------------------------------------------------
// Fused lin1 + filter MLP + in-register run-reduced scatter (R11/R14 structure).
__device__ __forceinline__ int sigma_row(int r) {
  return ((r >> 2) & 3) * 16 + (r >> 4) * 4 + (r & 3);
}
__global__ __launch_bounds__(256, 3) void ffs_kernel(
    const float* __restrict__ ea,
    const unsigned short* __restrict__ l1h, const unsigned short* __restrict__ l1l,
    const unsigned short* __restrict__ fw1h, const unsigned short* __restrict__ fw1l,
    const float* __restrict__ fb1,
    const unsigned short* __restrict__ fw2h, const unsigned short* __restrict__ fw2l,
    const float* __restrict__ fb2, const int* __restrict__ ei,
    const int* __restrict__ perm,
    const float* __restrict__ hfeat, float* agg)
{
  __shared__ unsigned short ldsA[2][64][136];
  __shared__ unsigned short ldsT[2][64][72];
  __shared__ int sS[64], sD[64];

  const int tid  = threadIdx.x;
  const int m0   = blockIdx.x * 64;
  const int lane = tid & 63, wave = tid >> 6;
  const int quad = lane >> 4, l16 = lane & 15;

  {
    const int r = tid >> 2, cb = (tid & 3) * 32;
    const int pe = perm[m0 + sigma_row(r)];
    const float* ap = ea + (size_t)pe * HC + cb;
    unsigned short th[32], tl[32];
#pragma unroll
    for (int q = 0; q < 8; q++) {
      float4 v = *(const float4*)(ap + q*4);
      float vv[4] = {v.x, v.y, v.z, v.w};
#pragma unroll
      for (int e = 0; e < 4; e++) {
        unsigned short hb = f2bf(vv[e]);
        th[q*4+e] = hb; tl[q*4+e] = f2bf(vv[e] - bf2f(hb));
      }
    }
#pragma unroll
    for (int q = 0; q < 4; q++) {
      *(bf16x8*)&ldsA[0][r][cb + q*8] = *(bf16x8*)&th[q*8];
      *(bf16x8*)&ldsA[1][r][cb + q*8] = *(bf16x8*)&tl[q*8];
    }
  }
  if (tid < 64) {
    int pe = perm[m0 + sigma_row(tid)];
    sS[tid] = ei[pe];
    sD[tid] = ei[N_EDGES + pe];
  }

  const f4v zf = {0.f, 0.f, 0.f, 0.f};
  __syncthreads();

  f4v hacc[4][4];
#pragma unroll
  for (int mt = 0; mt < 4; mt++)
#pragma unroll
    for (int nt = 0; nt < 4; nt++) hacc[mt][nt] = zf;

  unsigned short* ldsF = &ldsT[0][0][0];
  for (int kk = 0; kk < 128; kk += 32) {
    {
      const int r = tid >> 2, c8 = (tid & 3) * 8;
      const float* hp_ = hfeat + (size_t)sS[r] * HC + kk + c8;
      float4 v0 = *(const float4*)hp_;
      float4 v1 = *(const float4*)(hp_ + 4);
      float vv[8] = {v0.x, v0.y, v0.z, v0.w, v1.x, v1.y, v1.z, v1.w};
      unsigned short th[8], tl[8];
#pragma unroll
      for (int e = 0; e < 8; e++) {
        unsigned short hb = f2bf(vv[e]);
        th[e] = hb; tl[e] = f2bf(vv[e] - bf2f(hb));
      }
      *(bf16x8*)&ldsF[r*40 + c8]        = *(bf16x8*)&th[0];
      *(bf16x8*)&ldsF[2560 + r*40 + c8] = *(bf16x8*)&tl[0];
    }
    __syncthreads();
#pragma unroll
    for (int nt = 0; nt < 4; nt++) {
      const size_t brow = (size_t)(wave*64 + nt*16 + l16);
      bf16x8 bh = *(const bf16x8*)&l1h[brow * HC + kk + quad*8];
      bf16x8 bl = *(const bf16x8*)&l1l[brow * HC + kk + quad*8];
#pragma unroll
      for (int mt = 0; mt < 4; mt++) {
        bf16x8 ah = *(const bf16x8*)&ldsF[(mt*16 + l16)*40 + quad*8];
        bf16x8 al = *(const bf16x8*)&ldsF[2560 + (mt*16 + l16)*40 + quad*8];
        hacc[mt][nt] = __builtin_amdgcn_mfma_f32_16x16x32_bf16(ah, bh, hacc[mt][nt], 0, 0, 0);
        hacc[mt][nt] = __builtin_amdgcn_mfma_f32_16x16x32_bf16(ah, bl, hacc[mt][nt], 0, 0, 0);
        hacc[mt][nt] = __builtin_amdgcn_mfma_f32_16x16x32_bf16(al, bh, hacc[mt][nt], 0, 0, 0);
      }
    }
    __syncthreads();
  }

  f4v wacc[4][4];
#pragma unroll
  for (int mt = 0; mt < 4; mt++)
#pragma unroll
    for (int nt = 0; nt < 4; nt++) wacc[mt][nt] = zf;

  for (int p = 0; p < 4; p++) {
    f4v tacc[4];
#pragma unroll
    for (int mt = 0; mt < 4; mt++) tacc[mt] = zf;
    const size_t b1row = (size_t)(p*64 + wave*16 + l16);
#pragma unroll
    for (int kk = 0; kk < 128; kk += 32) {
      bf16x8 bh = *(const bf16x8*)&fw1h[b1row * HC + kk + quad*8];
      bf16x8 bl = *(const bf16x8*)&fw1l[b1row * HC + kk + quad*8];
#pragma unroll
      for (int mt = 0; mt < 4; mt++) {
        bf16x8 ah = *(const bf16x8*)&ldsA[0][mt*16 + l16][kk + quad*8];
        bf16x8 al = *(const bf16x8*)&ldsA[1][mt*16 + l16][kk + quad*8];
        tacc[mt] = __builtin_amdgcn_mfma_f32_16x16x32_bf16(ah, bh, tacc[mt], 0, 0, 0);
        tacc[mt] = __builtin_amdgcn_mfma_f32_16x16x32_bf16(ah, bl, tacc[mt], 0, 0, 0);
        tacc[mt] = __builtin_amdgcn_mfma_f32_16x16x32_bf16(al, bh, tacc[mt], 0, 0, 0);
      }
    }
    {
      const int col = wave*16 + l16;
      const float bz = fb1[p*64 + col];
#pragma unroll
      for (int mt = 0; mt < 4; mt++) {
        const int rowb = mt*16 + quad*4;
#pragma unroll
        for (int rr = 0; rr < 4; rr++) {
          float v = ssp_f(tacc[mt][rr] + bz);
          unsigned short hb = f2bf(v);
          ldsT[0][rowb+rr][col] = hb;
          ldsT[1][rowb+rr][col] = f2bf(v - bf2f(hb));
        }
      }
    }
    __syncthreads();

#pragma unroll
    for (int kc = 0; kc < 2; kc++) {
      bf16x8 a_h[4], a_l[4];
#pragma unroll
      for (int mt = 0; mt < 4; mt++) {
        a_h[mt] = *(const bf16x8*)&ldsT[0][mt*16 + l16][kc*32 + quad*8];
        a_l[mt] = *(const bf16x8*)&ldsT[1][mt*16 + l16][kc*32 + quad*8];
      }
#pragma unroll
      for (int nt = 0; nt < 4; nt++) {
        const size_t brow = (size_t)(wave*64 + nt*16 + l16);
        bf16x8 bh = *(const bf16x8*)&fw2h[brow * NFC + p*64 + kc*32 + quad*8];
        bf16x8 bl = *(const bf16x8*)&fw2l[brow * NFC + p*64 + kc*32 + quad*8];
#pragma unroll
        for (int mt = 0; mt < 4; mt++) {
          wacc[mt][nt] = __builtin_amdgcn_mfma_f32_16x16x32_bf16(a_h[mt], bh, wacc[mt][nt], 0, 0, 0);
          wacc[mt][nt] = __builtin_amdgcn_mfma_f32_16x16x32_bf16(a_h[mt], bl, wacc[mt][nt], 0, 0, 0);
          wacc[mt][nt] = __builtin_amdgcn_mfma_f32_16x16x32_bf16(a_l[mt], bh, wacc[mt][nt], 0, 0, 0);
        }
      }
    }
    __syncthreads();
  }

#pragma unroll
  for (int nt = 0; nt < 4; nt++) {
    const int col = wave*64 + nt*16 + l16;
    const float bz = fb2[col];
    float accum = 0.f;
    int prev = -1;
#pragma unroll
    for (int mt = 0; mt < 4; mt++) {
#pragma unroll
      for (int rr = 0; rr < 4; rr++) {
        const int prow = mt*16 + quad*4 + rr;
        const int d = sD[prow];
        const float v = (wacc[mt][nt][rr] + bz) * hacc[mt][nt][rr];
        if (d != prev) {
          if (prev >= 0) atomicAdd(&agg[(size_t)prev * NFC + col], accum);
          accum = v; prev = d;
        } else {
          accum += v;
        }
      }
    }
    atomicAdd(&agg[(size_t)prev * NFC + col], accum);
  }
}

// ---------------------------------------------------------------------------
// Fused pool + head. batch is SORTED: block g binary-searches its node range,
// computes the mean row, then the head MLP + reduction. 1024 blocks.
__global__ __launch_bounds__(256) void poolhead_kernel(
    const int* __restrict__ batch, const float* __restrict__ h,
    const float* __restrict__ w1, const float* __restrict__ b1,
    const float* __restrict__ w2, const float* __restrict__ b2,
    float* __restrict__ y)
{
  __shared__ float gs[HC];
  __shared__ float red[256];
  const int g = blockIdx.x;
  const int tid = threadIdx.x;

  // lower_bound(batch, g) and lower_bound(batch, g+1), redundantly per thread
  int lo = 0, hi = N_NODES;
  while (lo < hi) { int m = (lo + hi) >> 1; if (batch[m] < g) lo = m + 1; else hi = m; }
  int lo2 = lo, hi2 = N_NODES;
  while (lo2 < hi2) { int m = (lo2 + hi2) >> 1; if (batch[m] < g + 1) lo2 = m + 1; else hi2 = m; }
  const int cnt = lo2 - lo;

  if (tid < HC) {
    float s = 0.f;
    for (int i = lo; i < lo2; i++) s += h[(size_t)i * HC + tid];   // coalesced across threads
    gs[tid] = s / (float)max(cnt, 1);
  }
  __syncthreads();

  float partial = 0.f;
  for (int f = tid; f < NFFC; f += 256) {
    float acc = b1[f];
    const float* wr = w1 + (size_t)f * HC;
#pragma unroll 8
    for (int k = 0; k < HC; k++) acc = fmaf(gs[k], wr[k], acc);
    float t = 0.5f * acc * (1.0f + erff(acc * 0.70710678118654752440f));  // exact GELU
    partial = fmaf(t, w2[f], partial);
  }
  red[tid] = partial;
  __syncthreads();
  for (int s = 128; s > 0; s >>= 1) {
    if (tid < s) red[tid] += red[tid + s];
    __syncthreads();
  }
  if (tid == 0) y[g] = red[0] + b2[0];
}

// ---------------------------------------------------------------------------
extern "C" void kernel_launch(void* const* d_in, const int* in_sizes, int n_in,
                              void* d_out, int out_size, void* d_ws, size_t ws_size,
                              hipStream_t stream) {
  const int*   x     = (const int*)  d_in[0];
  const int*   ei    = (const int*)  d_in[1];
  const float* eattr = (const float*)d_in[2];
  const int*   batch = (const int*)  d_in[3];
  const float* pos   = (const float*)d_in[4];
  const float* vert  = (const float*)d_in[5];
  const float* posw  = (const float*)d_in[6];
  const float* edgew = (const float*)d_in[7];
  const float* fw1   = (const float*)d_in[8];
  const float* fb1   = (const float*)d_in[9];
  const float* fw2   = (const float*)d_in[10];
  const float* fb2   = (const float*)d_in[11];
  const float* l1w   = (const float*)d_in[12];
  const float* l2w   = (const float*)d_in[13];
  const float* l2b   = (const float*)d_in[14];
  const float* l3w   = (const float*)d_in[15];
  const float* l3b   = (const float*)d_in[16];
  const float* emw   = (const float*)d_in[17];
  const float* emb   = (const float*)d_in[18];
  const float* hw1   = (const float*)d_in[19];
  const float* hb1   = (const float*)d_in[20];
  const float* hw2   = (const float*)d_in[21];
  const float* hb2   = (const float*)d_in[22];
  float* out = (float*)d_out;

  char* ws = (char*)d_ws;
  size_t off = 0;
  auto alloc = [&](size_t bytes) { char* p = ws + off; off += (bytes + 511) & ~(size_t)511; return p; };
  float* ea   = (float*)alloc((size_t)N_EDGES*HC*4);
  float* h    = (float*)alloc((size_t)N_NODES*HC*4);
  float* agg  = (float*)alloc((size_t)N_NODES*NFC*4);
  int* deg    = (int*)alloc((size_t)(N_NODES+1)*4);
  int* cursor = (int*)alloc((size_t)(N_NODES+1)*4);
  int* perm   = (int*)alloc((size_t)N_EDGES*4);
  const int n_fw1 = NLAYER*NFC*HC, n_fw2 = NLAYER*NFC*NFC, n_l1 = NLAYER*NFC*HC;
  const int n_l2 = NLAYER*HC*NFC, n_l3 = NLAYER*HC*HC, n_em = NLAYER*HC*2*HC;
  unsigned short* fw1h = (unsigned short*)alloc((size_t)n_fw1*2);
  unsigned short* fw1l = (unsigned short*)alloc((size_t)n_fw1*2);
  unsigned short* fw2h = (unsigned short*)alloc((size_t)n_fw2*2);
  unsigned short* fw2l = (unsigned short*)alloc((size_t)n_fw2*2);
  unsigned short* l1h  = (unsigned short*)alloc((size_t)n_l1*2);
  unsigned short* l1l  = (unsigned short*)alloc((size_t)n_l1*2);
  unsigned short* l2h  = (unsigned short*)alloc((size_t)n_l2*2);
  unsigned short* l2l  = (unsigned short*)alloc((size_t)n_l2*2);
  unsigned short* l3h  = (unsigned short*)alloc((size_t)n_l3*2);
  unsigned short* l3l  = (unsigned short*)alloc((size_t)n_l3*2);
  unsigned short* emh  = (unsigned short*)alloc((size_t)n_em*2);
  unsigned short* eml  = (unsigned short*)alloc((size_t)n_em*2);

  zeroi_kernel<<<(N_NODES+1+255)/256, 256, 0, stream>>>(deg, N_NODES+1);
  hist_kernel<<<(N_EDGES+255)/256, 256, 0, stream>>>(ei, deg);
  scan_kernel<<<1, 1024, 0, stream>>>(deg, cursor, N_NODES+1);
  perm_kernel<<<(N_EDGES+255)/256, 256, 0, stream>>>(ei, cursor, perm);

  wsplit_kernel<<<(n_fw1+255)/256, 256, 0, stream>>>(fw1, fw1h, fw1l, n_fw1);
  wsplit_kernel<<<(n_fw2+255)/256, 256, 0, stream>>>(fw2, fw2h, fw2l, n_fw2);
  wsplit_kernel<<<(n_l1 +255)/256, 256, 0, stream>>>(l1w, l1h, l1l, n_l1);
  wsplit_kernel<<<(n_l2 +255)/256, 256, 0, stream>>>(l2w, l2h, l2l, n_l2);
  wsplit_kernel<<<(n_l3 +255)/256, 256, 0, stream>>>(l3w, l3h, l3l, n_l3);
  wsplit_kernel<<<(n_em +255)/256, 256, 0, stream>>>(emw, emh, eml, n_em);

  const int GN   = (N_NODES + 127) / 128;   // 391
  const int GE64 = N_EDGES / 64;            // 3125 (exact)

  embed_kernel<<<N_NODES, 128, 0, stream>>>(x, pos, vert, posw, h);
  edgeproj_kernel<<<(N_EDGES*HC + 255)/256, 256, 0, stream>>>(eattr, edgew, ea);
  // agg zeroed once; later layers re-zeroed inside nodeup_kernel
  zero_kernel<<<((N_NODES*NFC/4) + 255)/256, 256, 0, stream>>>(
      (float4*)agg, N_NODES*NFC/4);

  for (int i = 0; i < NLAYER; ++i) {
    ffs_kernel<<<GE64, 256, 0, stream>>>(
        ea, l1h + (size_t)i*NFC*HC, l1l + (size_t)i*NFC*HC,
        fw1h + (size_t)i*NFC*HC, fw1l + (size_t)i*NFC*HC, fb1 + (size_t)i*NFC,
        fw2h + (size_t)i*NFC*NFC, fw2l + (size_t)i*NFC*NFC, fb2 + (size_t)i*NFC,
        ei, perm, h, agg);
    nodeup_kernel<<<GN, 256, 0, stream>>>(
        agg, l2h + (size_t)i*HC*NFC, l2l + (size_t)i*HC*NFC, l2b + (size_t)i*HC,
        l3h + (size_t)i*HC*HC, l3l + (size_t)i*HC*HC, l3b + (size_t)i*HC, h);
    if (i < NLAYER - 1) {
      emlite_kernel<<<GE64, 256, 0, stream>>>(
          ea, emh + (size_t)i*HC*2*HC, eml + (size_t)i*HC*2*HC, emb + (size_t)i*HC,
          ei, h);
    }
  }

  poolhead_kernel<<<N_GRAPH, 256, 0, stream>>>(batch, h, hw1, hb1, hw2, hb2, out);
}

// Round 16
// 2459.171 us; speedup vs baseline: 1.0521x; 1.0339x over previous
//
#include <hip/hip_runtime.h>
#include <hip/hip_bf16.h>
#include <math.h>

#define N_NODES 50000
#define N_EDGES 200000
#define N_GRAPH 1024
#define HC      128
#define NFC     256
#define NLAYER  5
#define NFFC    512

typedef short bf16x8 __attribute__((ext_vector_type(8)));
typedef float f4v    __attribute__((ext_vector_type(4)));

__device__ __forceinline__ float ssp_f(float x) {
  float e = __expf(-fabsf(x));
  return fmaxf(x, 0.0f) + __logf(1.0f + e) - 0.69314718055994530942f;
}
__device__ __forceinline__ float tanh_f(float x) {
  float e = __expf(2.0f * fabsf(x));
  float t = 1.0f - 2.0f * __builtin_amdgcn_rcpf(e + 1.0f);
  return copysignf(t, x);
}
__device__ __forceinline__ unsigned short f2bf(float x) {
  union { float f; unsigned u; } v; v.f = x;
  unsigned r = v.u + 0x7fff + ((v.u >> 16) & 1);
  return (unsigned short)(r >> 16);
}
__device__ __forceinline__ float bf2f(unsigned short b) {
  union { unsigned u; float f; } v; v.u = (unsigned)b << 16; return v.f;
}

// ---------------------------------------------------------------------------
__global__ void zero_kernel(float4* __restrict__ p, int n4) {
  int i = blockIdx.x * blockDim.x + threadIdx.x;
  if (i < n4) p[i] = make_float4(0.f, 0.f, 0.f, 0.f);
}
__global__ void zeroi_kernel(int* __restrict__ p, int n) {
  int i = blockIdx.x * blockDim.x + threadIdx.x;
  if (i < n) p[i] = 0;
}

// ---- dst-sort infrastructure ----------------------------------------------
__global__ void hist_kernel(const int* __restrict__ ei, int* __restrict__ deg) {
  int e = blockIdx.x * blockDim.x + threadIdx.x;
  if (e < N_EDGES) atomicAdd(&deg[ei[N_EDGES + e]], 1);
}
// hierarchical exclusive scan: pass1 per-256-block, pass2 block sums, pass3 add
__global__ void scan1_kernel(const int* __restrict__ deg, int* __restrict__ excl,
                             int* __restrict__ bsum, int n) {
  __shared__ int buf[256];
  const int tid = threadIdx.x;
  const int i = blockIdx.x * 256 + tid;
  int v = (i < n) ? deg[i] : 0;
  buf[tid] = v;
  __syncthreads();
  for (int s = 1; s < 256; s <<= 1) {
    int t = (tid >= s) ? buf[tid - s] : 0;
    __syncthreads();
    buf[tid] += t;
    __syncthreads();
  }
  if (i < n) excl[i] = buf[tid] - v;
  if (tid == 255) bsum[blockIdx.x] = buf[255];
}
__global__ void scan2_kernel(int* __restrict__ bsum, int nb) {
  __shared__ int buf[256];
  const int tid = threadIdx.x;
  int v = (tid < nb) ? bsum[tid] : 0;
  buf[tid] = v;
  __syncthreads();
  for (int s = 1; s < 256; s <<= 1) {
    int t = (tid >= s) ? buf[tid - s] : 0;
    __syncthreads();
    buf[tid] += t;
    __syncthreads();
  }
  if (tid < nb) bsum[tid] = buf[tid] - v;
}
__global__ void scan3_kernel(int* __restrict__ excl, const int* __restrict__ bsum, int n) {
  int i = blockIdx.x * 256 + threadIdx.x;
  if (i < n) excl[i] += bsum[blockIdx.x];
}
__global__ void perm_kernel(const int* __restrict__ ei, int* __restrict__ cursor,
                            int* __restrict__ perm) {
  int e = blockIdx.x * blockDim.x + threadIdx.x;
  if (e < N_EDGES) {
    int d = ei[N_EDGES + e];
    int p = atomicAdd(&cursor[d], 1);
    perm[p] = e;
  }
}

// split fp32 weights -> bf16 hi + lo
__global__ void wsplit_kernel(const float* __restrict__ w,
                              unsigned short* __restrict__ hi,
                              unsigned short* __restrict__ lo, int n) {
  int i = blockIdx.x * blockDim.x + threadIdx.x;
  if (i < n) {
    float v = w[i];
    unsigned short hb = f2bf(v);
    hi[i] = hb;
    lo[i] = f2bf(v - bf2f(hb));
  }
}

__global__ void embed_kernel(const int* __restrict__ x, const float* __restrict__ pos,
                             const float* __restrict__ vert, const float* __restrict__ posw,
                             float* __restrict__ h) {
  int n = blockIdx.x;
  int c = threadIdx.x;            // 128 threads
  float v;
  if (c < 80) {
    v = vert[(size_t)x[n] * 80 + c];
  } else {
    int j = c - 80;
    v = pos[n*3+0]*posw[j*3+0] + pos[n*3+1]*posw[j*3+1] + pos[n*3+2]*posw[j*3+2];
  }
  h[(size_t)n*HC + c] = v;
}

__global__ void edgeproj_kernel(const float* __restrict__ eattr, const float* __restrict__ ew,
                                float* __restrict__ ea) {
  int idx = blockIdx.x * blockDim.x + threadIdx.x;
  if (idx >= N_EDGES * HC) return;
  int e = idx >> 7, c = idx & 127;
  const float* a = eattr + (size_t)e*4;
  const float* w = ew + (size_t)c*4;
  ea[idx] = a[0]*w[0] + a[1]*w[1] + a[2]*w[2] + a[3]*w[3];
}

// ---------------------------------------------------------------------------
// Edge-MLP: 64-edge tile, 256 threads, ONE barrier.
// R16: ea + h loads all issued before any conversion (latency overlap).
__global__ __launch_bounds__(256, 2) void emlite_kernel(
    float* ea,
    const unsigned short* __restrict__ Bh, const unsigned short* __restrict__ Bl,
    const float* __restrict__ bias, const int* __restrict__ ei,
    const float* __restrict__ hfeat)
{
  __shared__ unsigned short ldsA[2][64][136];   // ea split
  __shared__ unsigned short ldsH[2][64][136];   // hsum split

  const int tid  = threadIdx.x;
  const int m0   = blockIdx.x * 64;             // N_EDGES % 64 == 0
  const int lane = tid & 63, wave = tid >> 6;
  const int quad = lane >> 4, l16 = lane & 15;
  const int r = tid >> 2, cb = (tid & 3) * 32;

  const int e = m0 + r;
  const int s = ei[e], d = ei[N_EDGES + e];

  // ---- issue ALL loads first ----
  float va[32], v1[32], v2[32];
  {
    const float* ap = ea + (size_t)e * HC + cb;
    const float* p1 = hfeat + (size_t)s * HC + cb;
    const float* p2 = hfeat + (size_t)d * HC + cb;
#pragma unroll
    for (int q = 0; q < 8; q++) *(float4*)&va[q*4] = *(const float4*)(ap + q*4);
#pragma unroll
    for (int q = 0; q < 8; q++) *(float4*)&v1[q*4] = *(const float4*)(p1 + q*4);
#pragma unroll
    for (int q = 0; q < 8; q++) *(float4*)&v2[q*4] = *(const float4*)(p2 + q*4);
  }
  // ---- convert + stage ----
  {
    unsigned short th[32], tl[32];
#pragma unroll
    for (int j = 0; j < 32; j++) {
      unsigned short hb = f2bf(va[j]);
      th[j] = hb; tl[j] = f2bf(va[j] - bf2f(hb));
    }
#pragma unroll
    for (int q = 0; q < 4; q++) {
      *(bf16x8*)&ldsA[0][r][cb + q*8] = *(bf16x8*)&th[q*8];
      *(bf16x8*)&ldsA[1][r][cb + q*8] = *(bf16x8*)&tl[q*8];
    }
#pragma unroll
    for (int j = 0; j < 32; j++) {
      float v = v1[j] + v2[j];
      unsigned short hb = f2bf(v);
      th[j] = hb; tl[j] = f2bf(v - bf2f(hb));
    }
#pragma unroll
    for (int q = 0; q < 4; q++) {
      *(bf16x8*)&ldsH[0][r][cb + q*8] = *(bf16x8*)&th[q*8];
      *(bf16x8*)&ldsH[1][r][cb + q*8] = *(bf16x8*)&tl[q*8];
    }
  }

  const f4v zf = {0.f, 0.f, 0.f, 0.f};
  f4v acc[4][2];
#pragma unroll
  for (int mt = 0; mt < 4; mt++) { acc[mt][0] = zf; acc[mt][1] = zf; }

  __syncthreads();   // the only barrier

#pragma unroll
  for (int nt = 0; nt < 2; nt++) {
    const size_t brow = (size_t)(wave*32 + nt*16 + l16);
#pragma unroll
    for (int kk = 0; kk < 128; kk += 32) {
      bf16x8 bh = *(const bf16x8*)&Bh[brow * 2*HC + kk + quad*8];
      bf16x8 bl = *(const bf16x8*)&Bl[brow * 2*HC + kk + quad*8];
#pragma unroll
      for (int mt = 0; mt < 4; mt++) {
        bf16x8 ah = *(const bf16x8*)&ldsA[0][mt*16 + l16][kk + quad*8];
        bf16x8 al = *(const bf16x8*)&ldsA[1][mt*16 + l16][kk + quad*8];
        acc[mt][nt] = __builtin_amdgcn_mfma_f32_16x16x32_bf16(ah, bh, acc[mt][nt], 0, 0, 0);
        acc[mt][nt] = __builtin_amdgcn_mfma_f32_16x16x32_bf16(ah, bl, acc[mt][nt], 0, 0, 0);
        acc[mt][nt] = __builtin_amdgcn_mfma_f32_16x16x32_bf16(al, bh, acc[mt][nt], 0, 0, 0);
      }
    }
#pragma unroll
    for (int kk = 0; kk < 128; kk += 32) {
      bf16x8 bh = *(const bf16x8*)&Bh[brow * 2*HC + HC + kk + quad*8];
      bf16x8 bl = *(const bf16x8*)&Bl[brow * 2*HC + HC + kk + quad*8];
#pragma unroll
      for (int mt = 0; mt < 4; mt++) {
        bf16x8 ah = *(const bf16x8*)&ldsH[0][mt*16 + l16][kk + quad*8];
        bf16x8 al = *(const bf16x8*)&ldsH[1][mt*16 + l16][kk + quad*8];
        acc[mt][nt] = __builtin_amdgcn_mfma_f32_16x16x32_bf16(ah, bh, acc[mt][nt], 0, 0, 0);
        acc[mt][nt] = __builtin_amdgcn_mfma_f32_16x16x32_bf16(ah, bl, acc[mt][nt], 0, 0, 0);
        acc[mt][nt] = __builtin_amdgcn_mfma_f32_16x16x32_bf16(al, bh, acc[mt][nt], 0, 0, 0);
      }
    }
  }

#pragma unroll
  for (int nt = 0; nt < 2; nt++) {
    const int col = wave*32 + nt*16 + l16;
    const float bz = bias[col];
#pragma unroll
    for (int mt = 0; mt < 4; mt++) {
      const int rowb = mt*16 + quad*4;
#pragma unroll
      for (int rr = 0; rr < 4; rr++) {
        const size_t idx = (size_t)(m0 + rowb + rr) * HC + col;
        ea[idx] = tanh_f(acc[mt][nt][rr] + bz) + ea[idx];
      }
    }
  }
}

// ---------------------------------------------------------------------------
// Fused node update: h = relu(ssp(agg @ l2^T + b2) @ l3^T + b3) + h.
// Zeroes its own agg rows after GEMM1 reads complete.
__global__ __launch_bounds__(256, 2) void nodeup_kernel(
    float* __restrict__ agg,
    const unsigned short* __restrict__ L2h, const unsigned short* __restrict__ L2l,
    const float* __restrict__ b2,
    const unsigned short* __restrict__ L3h, const unsigned short* __restrict__ L3l,
    const float* __restrict__ b3,
    float* h)
{
  __shared__ unsigned short lds[2 * 128 * 136];
  const int AH = 0, AL = 5120;            // A chunk staging (pitch 40)
  const int TH = 0, TL = 17408;           // t2 full tile (pitch 136)

  const int tid  = threadIdx.x;
  const int m0   = blockIdx.x * 128;
  const int lane = tid & 63, wave = tid >> 6;
  const int quad = lane >> 4, l16 = lane & 15;
  const int wm = (wave >> 1) * 64, wn = (wave & 1) * 64;
  const int r  = tid >> 1;
  const int c0 = (tid & 1) * 16;

  const f4v zf = {0.f, 0.f, 0.f, 0.f};
  f4v acc[4][4];
#pragma unroll
  for (int i = 0; i < 4; i++)
#pragma unroll
    for (int j = 0; j < 4; j++) acc[i][j] = zf;

  const bool mok = (m0 + r) < N_NODES;
  const size_t arow = (size_t)(m0 + r);

  float av[16];
  if (mok) {
    const float* ap = agg + arow * NFC + c0;
#pragma unroll
    for (int q = 0; q < 4; q++) *(float4*)&av[q*4] = *(const float4*)(ap + q*4);
  } else {
#pragma unroll
    for (int j = 0; j < 16; j++) av[j] = 0.f;
  }

  for (int kk = 0; kk < NFC; kk += 32) {
    float avn[16];
    if (kk + 32 < NFC) {
      if (mok) {
        const float* ap = agg + arow * NFC + kk + 32 + c0;
#pragma unroll
        for (int q = 0; q < 4; q++) *(float4*)&avn[q*4] = *(const float4*)(ap + q*4);
      } else {
#pragma unroll
        for (int j = 0; j < 16; j++) avn[j] = 0.f;
      }
    }
    bf16x8 bh[4], bl[4];
#pragma unroll
    for (int nt = 0; nt < 4; nt++) {
      const size_t brow = (size_t)(wn + nt*16 + l16);
      bh[nt] = *(const bf16x8*)&L2h[brow * NFC + kk + quad*8];
      bl[nt] = *(const bf16x8*)&L2l[brow * NFC + kk + quad*8];
    }
    __syncthreads();
    unsigned short th[16], tl[16];
#pragma unroll
    for (int j = 0; j < 16; j++) {
      unsigned short hb = f2bf(av[j]);
      th[j] = hb; tl[j] = f2bf(av[j] - bf2f(hb));
    }
    *(bf16x8*)&lds[AH + r*40 + c0]     = *(bf16x8*)&th[0];
    *(bf16x8*)&lds[AH + r*40 + c0 + 8] = *(bf16x8*)&th[8];
    *(bf16x8*)&lds[AL + r*40 + c0]     = *(bf16x8*)&tl[0];
    *(bf16x8*)&lds[AL + r*40 + c0 + 8] = *(bf16x8*)&tl[8];
    __syncthreads();
    bf16x8 ah[4], al[4];
#pragma unroll
    for (int t = 0; t < 4; t++) {
      const int ra = (wm + t*16 + l16) * 40 + quad * 8;
      ah[t] = *(const bf16x8*)&lds[AH + ra];
      al[t] = *(const bf16x8*)&lds[AL + ra];
    }
#pragma unroll
    for (int mt = 0; mt < 4; mt++)
#pragma unroll
      for (int nt = 0; nt < 4; nt++) {
        acc[mt][nt] = __builtin_amdgcn_mfma_f32_16x16x32_bf16(ah[mt], bh[nt], acc[mt][nt], 0, 0, 0);
        acc[mt][nt] = __builtin_amdgcn_mfma_f32_16x16x32_bf16(ah[mt], bl[nt], acc[mt][nt], 0, 0, 0);
        acc[mt][nt] = __builtin_amdgcn_mfma_f32_16x16x32_bf16(al[mt], bh[nt], acc[mt][nt], 0, 0, 0);
      }
    if (kk + 32 < NFC) {
#pragma unroll
      for (int j = 0; j < 16; j++) av[j] = avn[j];
    }
  }
  __syncthreads();   // ALL threads' agg reads complete

  if (mok) {
    float4* zp = (float4*)(agg + arow * NFC + (tid & 1) * 128);
    const float4 z4 = make_float4(0.f, 0.f, 0.f, 0.f);
#pragma unroll
    for (int q = 0; q < 32; q++) zp[q] = z4;
  }

#pragma unroll
  for (int nt = 0; nt < 4; nt++) {
    const int col = wn + nt*16 + l16;
    const float bz = b2[col];
#pragma unroll
    for (int mt = 0; mt < 4; mt++) {
      const int rowb = wm + mt*16 + quad*4;
#pragma unroll
      for (int rr = 0; rr < 4; rr++) {
        float v = ssp_f(acc[mt][nt][rr] + bz);
        unsigned short hb = f2bf(v);
        lds[TH + (rowb+rr)*136 + col] = hb;
        lds[TL + (rowb+rr)*136 + col] = f2bf(v - bf2f(hb));
      }
    }
  }
  __syncthreads();

  f4v acc2[4][4];
#pragma unroll
  for (int i = 0; i < 4; i++)
#pragma unroll
    for (int j = 0; j < 4; j++) acc2[i][j] = zf;

  for (int kk = 0; kk < HC; kk += 32) {
    bf16x8 bh[4], bl[4];
#pragma unroll
    for (int nt = 0; nt < 4; nt++) {
      const size_t brow = (size_t)(wn + nt*16 + l16);
      bh[nt] = *(const bf16x8*)&L3h[brow * HC + kk + quad*8];
      bl[nt] = *(const bf16x8*)&L3l[brow * HC + kk + quad*8];
    }
    bf16x8 ah[4], al[4];
#pragma unroll
    for (int t = 0; t < 4; t++) {
      const int ra = (wm + t*16 + l16) * 136 + kk + quad * 8;
      ah[t] = *(const bf16x8*)&lds[TH + ra];
      al[t] = *(const bf16x8*)&lds[TL + ra];
    }
#pragma unroll
    for (int mt = 0; mt < 4; mt++)
#pragma unroll
      for (int nt = 0; nt < 4; nt++) {
        acc2[mt][nt] = __builtin_amdgcn_mfma_f32_16x16x32_bf16(ah[mt], bh[nt], acc2[mt][nt], 0, 0, 0);
        acc2[mt][nt] = __builtin_amdgcn_mfma_f32_16x16x32_bf16(ah[mt], bl[nt], acc2[mt][nt], 0, 0, 0);
        acc2[mt][nt] = __builtin_amdgcn_mfma_f32_16x16x32_bf16(al[mt], bh[nt], acc2[mt][nt], 0, 0, 0);
      }
  }

#pragma unroll
  for (int nt = 0; nt < 4; nt++) {
    const int ncol = wn + nt*16 + l16;
    const float bz = b3[ncol];
#pragma unroll
    for (int mt = 0; mt < 4; mt++) {
      const int mb = wm + mt*16 + quad*4;
#pragma unroll
      for (int rr = 0; rr < 4; rr++) {
        const int m = m0 + mb + rr;
        if (m < N_NODES) {
          const size_t idx = (size_t)m * HC + ncol;
          h[idx] = fmaxf(acc2[mt][nt][rr] + bz, 0.f) + h[idx];
        }
      }
    }
  }
}

// ---------------------------------------------------------------------------
// Fused lin1 + filter MLP + in-register run-reduced scatter (R11 structure).
__device__ __forceinline__ int sigma_row(int r) {
  return ((r >> 2) & 3) * 16 + (r >> 4) * 4 + (r & 3);
}
__global__ __launch_bounds__(256, 3) void ffs_kernel(
    const float* __restrict__ ea,
    const unsigned short* __restrict__ l1h, const unsigned short* __restrict__ l1l,
    const unsigned short* __restrict__ fw1h, const unsigned short* __restrict__ fw1l,
    const float* __restrict__ fb1,
    const unsigned short* __restrict__ fw2h, const unsigned short* __restrict__ fw2l,
    const float* __restrict__ fb2, const int* __restrict__ ei,
    const int* __restrict__ perm,
    const float* __restrict__ hfeat, float* agg)
{
  __shared__ unsigned short ldsA[2][64][136];
  __shared__ unsigned short ldsT[2][64][72];
  __shared__ int sS[64], sD[64];

  const int tid  = threadIdx.x;
  const int m0   = blockIdx.x * 64;
  const int lane = tid & 63, wave = tid >> 6;
  const int quad = lane >> 4, l16 = lane & 15;

  {
    const int r = tid >> 2, cb = (tid & 3) * 32;
    const int pe = perm[m0 + sigma_row(r)];
    const float* ap = ea + (size_t)pe * HC + cb;
    unsigned short th[32], tl[32];
#pragma unroll
    for (int q = 0; q < 8; q++) {
      float4 v = *(const float4*)(ap + q*4);
      float vv[4] = {v.x, v.y, v.z, v.w};
#pragma unroll
      for (int e = 0; e < 4; e++) {
        unsigned short hb = f2bf(vv[e]);
        th[q*4+e] = hb; tl[q*4+e] = f2bf(vv[e] - bf2f(hb));
      }
    }
#pragma unroll
    for (int q = 0; q < 4; q++) {
      *(bf16x8*)&ldsA[0][r][cb + q*8] = *(bf16x8*)&th[q*8];
      *(bf16x8*)&ldsA[1][r][cb + q*8] = *(bf16x8*)&tl[q*8];
    }
  }
  if (tid < 64) {
    int pe = perm[m0 + sigma_row(tid)];
    sS[tid] = ei[pe];
    sD[tid] = ei[N_EDGES + pe];
  }

  const f4v zf = {0.f, 0.f, 0.f, 0.f};
  __syncthreads();

  f4v hacc[4][4];
#pragma unroll
  for (int mt = 0; mt < 4; mt++)
#pragma unroll
    for (int nt = 0; nt < 4; nt++) hacc[mt][nt] = zf;

  unsigned short* ldsF = &ldsT[0][0][0];
  for (int kk = 0; kk < 128; kk += 32) {
    {
      const int r = tid >> 2, c8 = (tid & 3) * 8;
      const float* hp_ = hfeat + (size_t)sS[r] * HC + kk + c8;
      float4 v0 = *(const float4*)hp_;
      float4 v1 = *(const float4*)(hp_ + 4);
      float vv[8] = {v0.x, v0.y, v0.z, v0.w, v1.x, v1.y, v1.z, v1.w};
      unsigned short th[8], tl[8];
#pragma unroll
      for (int e = 0; e < 8; e++) {
        unsigned short hb = f2bf(vv[e]);
        th[e] = hb; tl[e] = f2bf(vv[e] - bf2f(hb));
      }
      *(bf16x8*)&ldsF[r*40 + c8]        = *(bf16x8*)&th[0];
      *(bf16x8*)&ldsF[2560 + r*40 + c8] = *(bf16x8*)&tl[0];
    }
    __syncthreads();
#pragma unroll
    for (int nt = 0; nt < 4; nt++) {
      const size_t brow = (size_t)(wave*64 + nt*16 + l16);
      bf16x8 bh = *(const bf16x8*)&l1h[brow * HC + kk + quad*8];
      bf16x8 bl = *(const bf16x8*)&l1l[brow * HC + kk + quad*8];
#pragma unroll
      for (int mt = 0; mt < 4; mt++) {
        bf16x8 ah = *(const bf16x8*)&ldsF[(mt*16 + l16)*40 + quad*8];
        bf16x8 al = *(const bf16x8*)&ldsF[2560 + (mt*16 + l16)*40 + quad*8];
        hacc[mt][nt] = __builtin_amdgcn_mfma_f32_16x16x32_bf16(ah, bh, hacc[mt][nt], 0, 0, 0);
        hacc[mt][nt] = __builtin_amdgcn_mfma_f32_16x16x32_bf16(ah, bl, hacc[mt][nt], 0, 0, 0);
        hacc[mt][nt] = __builtin_amdgcn_mfma_f32_16x16x32_bf16(al, bh, hacc[mt][nt], 0, 0, 0);
      }
    }
    __syncthreads();
  }

  f4v wacc[4][4];
#pragma unroll
  for (int mt = 0; mt < 4; mt++)
#pragma unroll
    for (int nt = 0; nt < 4; nt++) wacc[mt][nt] = zf;

  for (int p = 0; p < 4; p++) {
    f4v tacc[4];
#pragma unroll
    for (int mt = 0; mt < 4; mt++) tacc[mt] = zf;
    const size_t b1row = (size_t)(p*64 + wave*16 + l16);
#pragma unroll
    for (int kk = 0; kk < 128; kk += 32) {
      bf16x8 bh = *(const bf16x8*)&fw1h[b1row * HC + kk + quad*8];
      bf16x8 bl = *(const bf16x8*)&fw1l[b1row * HC + kk + quad*8];
#pragma unroll
      for (int mt = 0; mt < 4; mt++) {
        bf16x8 ah = *(const bf16x8*)&ldsA[0][mt*16 + l16][kk + quad*8];
        bf16x8 al = *(const bf16x8*)&ldsA[1][mt*16 + l16][kk + quad*8];
        tacc[mt] = __builtin_amdgcn_mfma_f32_16x16x32_bf16(ah, bh, tacc[mt], 0, 0, 0);
        tacc[mt] = __builtin_amdgcn_mfma_f32_16x16x32_bf16(ah, bl, tacc[mt], 0, 0, 0);
        tacc[mt] = __builtin_amdgcn_mfma_f32_16x16x32_bf16(al, bh, tacc[mt], 0, 0, 0);
      }
    }
    {
      const int col = wave*16 + l16;
      const float bz = fb1[p*64 + col];
#pragma unroll
      for (int mt = 0; mt < 4; mt++) {
        const int rowb = mt*16 + quad*4;
#pragma unroll
        for (int rr = 0; rr < 4; rr++) {
          float v = ssp_f(tacc[mt][rr] + bz);
          unsigned short hb = f2bf(v);
          ldsT[0][rowb+rr][col] = hb;
          ldsT[1][rowb+rr][col] = f2bf(v - bf2f(hb));
        }
      }
    }
    __syncthreads();

#pragma unroll
    for (int kc = 0; kc < 2; kc++) {
      bf16x8 a_h[4], a_l[4];
#pragma unroll
      for (int mt = 0; mt < 4; mt++) {
        a_h[mt] = *(const bf16x8*)&ldsT[0][mt*16 + l16][kc*32 + quad*8];
        a_l[mt] = *(const bf16x8*)&ldsT[1][mt*16 + l16][kc*32 + quad*8];
      }
#pragma unroll
      for (int nt = 0; nt < 4; nt++) {
        const size_t brow = (size_t)(wave*64 + nt*16 + l16);
        bf16x8 bh = *(const bf16x8*)&fw2h[brow * NFC + p*64 + kc*32 + quad*8];
        bf16x8 bl = *(const bf16x8*)&fw2l[brow * NFC + p*64 + kc*32 + quad*8];
#pragma unroll
        for (int mt = 0; mt < 4; mt++) {
          wacc[mt][nt] = __builtin_amdgcn_mfma_f32_16x16x32_bf16(a_h[mt], bh, wacc[mt][nt], 0, 0, 0);
          wacc[mt][nt] = __builtin_amdgcn_mfma_f32_16x16x32_bf16(a_h[mt], bl, wacc[mt][nt], 0, 0, 0);
          wacc[mt][nt] = __builtin_amdgcn_mfma_f32_16x16x32_bf16(a_l[mt], bh, wacc[mt][nt], 0, 0, 0);
        }
      }
    }
    __syncthreads();
  }

#pragma unroll
  for (int nt = 0; nt < 4; nt++) {
    const int col = wave*64 + nt*16 + l16;
    const float bz = fb2[col];
    float accum = 0.f;
    int prev = -1;
#pragma unroll
    for (int mt = 0; mt < 4; mt++) {
#pragma unroll
      for (int rr = 0; rr < 4; rr++) {
        const int prow = mt*16 + quad*4 + rr;
        const int d = sD[prow];
        const float v = (wacc[mt][nt][rr] + bz) * hacc[mt][nt][rr];
        if (d != prev) {
          if (prev >= 0) atomicAdd(&agg[(size_t)prev * NFC + col], accum);
          accum = v; prev = d;
        } else {
          accum += v;
        }
      }
    }
    atomicAdd(&agg[(size_t)prev * NFC + col], accum);
  }
}

// ---------------------------------------------------------------------------
// Fused pool + head (batch sorted; per-graph binary search).
__global__ __launch_bounds__(256) void poolhead_kernel(
    const int* __restrict__ batch, const float* __restrict__ h,
    const float* __restrict__ w1, const float* __restrict__ b1,
    const float* __restrict__ w2, const float* __restrict__ b2,
    float* __restrict__ y)
{
  __shared__ float gs[HC];
  __shared__ float red[256];
  const int g = blockIdx.x;
  const int tid = threadIdx.x;

  int lo = 0, hi = N_NODES;
  while (lo < hi) { int m = (lo + hi) >> 1; if (batch[m] < g) lo = m + 1; else hi = m; }
  int lo2 = lo, hi2 = N_NODES;
  while (lo2 < hi2) { int m = (lo2 + hi2) >> 1; if (batch[m] < g + 1) lo2 = m + 1; else hi2 = m; }
  const int cnt = lo2 - lo;

  if (tid < HC) {
    float s = 0.f;
    for (int i = lo; i < lo2; i++) s += h[(size_t)i * HC + tid];
    gs[tid] = s / (float)max(cnt, 1);
  }
  __syncthreads();

  float partial = 0.f;
  for (int f = tid; f < NFFC; f += 256) {
    float acc = b1[f];
    const float* wr = w1 + (size_t)f * HC;
#pragma unroll 8
    for (int k = 0; k < HC; k++) acc = fmaf(gs[k], wr[k], acc);
    float t = 0.5f * acc * (1.0f + erff(acc * 0.70710678118654752440f));
    partial = fmaf(t, w2[f], partial);
  }
  red[tid] = partial;
  __syncthreads();
  for (int s = 128; s > 0; s >>= 1) {
    if (tid < s) red[tid] += red[tid + s];
    __syncthreads();
  }
  if (tid == 0) y[g] = red[0] + b2[0];
}

// ---------------------------------------------------------------------------
extern "C" void kernel_launch(void* const* d_in, const int* in_sizes, int n_in,
                              void* d_out, int out_size, void* d_ws, size_t ws_size,
                              hipStream_t stream) {
  const int*   x     = (const int*)  d_in[0];
  const int*   ei    = (const int*)  d_in[1];
  const float* eattr = (const float*)d_in[2];
  const int*   batch = (const int*)  d_in[3];
  const float* pos   = (const float*)d_in[4];
  const float* vert  = (const float*)d_in[5];
  const float* posw  = (const float*)d_in[6];
  const float* edgew = (const float*)d_in[7];
  const float* fw1   = (const float*)d_in[8];
  const float* fb1   = (const float*)d_in[9];
  const float* fw2   = (const float*)d_in[10];
  const float* fb2   = (const float*)d_in[11];
  const float* l1w   = (const float*)d_in[12];
  const float* l2w   = (const float*)d_in[13];
  const float* l2b   = (const float*)d_in[14];
  const float* l3w   = (const float*)d_in[15];
  const float* l3b   = (const float*)d_in[16];
  const float* emw   = (const float*)d_in[17];
  const float* emb   = (const float*)d_in[18];
  const float* hw1   = (const float*)d_in[19];
  const float* hb1   = (const float*)d_in[20];
  const float* hw2   = (const float*)d_in[21];
  const float* hb2   = (const float*)d_in[22];
  float* out = (float*)d_out;

  char* ws = (char*)d_ws;
  size_t off = 0;
  auto alloc = [&](size_t bytes) { char* p = ws + off; off += (bytes + 511) & ~(size_t)511; return p; };
  float* ea   = (float*)alloc((size_t)N_EDGES*HC*4);
  float* h    = (float*)alloc((size_t)N_NODES*HC*4);
  float* agg  = (float*)alloc((size_t)N_NODES*NFC*4);
  int* deg    = (int*)alloc((size_t)(N_NODES+1)*4);
  int* cursor = (int*)alloc((size_t)(N_NODES+1)*4);
  int* bsum   = (int*)alloc((size_t)256*4);
  int* perm   = (int*)alloc((size_t)N_EDGES*4);
  const int n_fw1 = NLAYER*NFC*HC, n_fw2 = NLAYER*NFC*NFC, n_l1 = NLAYER*NFC*HC;
  const int n_l2 = NLAYER*HC*NFC, n_l3 = NLAYER*HC*HC, n_em = NLAYER*HC*2*HC;
  unsigned short* fw1h = (unsigned short*)alloc((size_t)n_fw1*2);
  unsigned short* fw1l = (unsigned short*)alloc((size_t)n_fw1*2);
  unsigned short* fw2h = (unsigned short*)alloc((size_t)n_fw2*2);
  unsigned short* fw2l = (unsigned short*)alloc((size_t)n_fw2*2);
  unsigned short* l1h  = (unsigned short*)alloc((size_t)n_l1*2);
  unsigned short* l1l  = (unsigned short*)alloc((size_t)n_l1*2);
  unsigned short* l2h  = (unsigned short*)alloc((size_t)n_l2*2);
  unsigned short* l2l  = (unsigned short*)alloc((size_t)n_l2*2);
  unsigned short* l3h  = (unsigned short*)alloc((size_t)n_l3*2);
  unsigned short* l3l  = (unsigned short*)alloc((size_t)n_l3*2);
  unsigned short* emh  = (unsigned short*)alloc((size_t)n_em*2);
  unsigned short* eml  = (unsigned short*)alloc((size_t)n_em*2);

  const int NSCAN = N_NODES + 1;                 // 50001
  const int NB    = (NSCAN + 255) / 256;         // 196

  zeroi_kernel<<<(NSCAN+255)/256, 256, 0, stream>>>(deg, NSCAN);
  hist_kernel<<<(N_EDGES+255)/256, 256, 0, stream>>>(ei, deg);
  scan1_kernel<<<NB, 256, 0, stream>>>(deg, cursor, bsum, NSCAN);
  scan2_kernel<<<1, 256, 0, stream>>>(bsum, NB);
  scan3_kernel<<<NB, 256, 0, stream>>>(cursor, bsum, NSCAN);
  perm_kernel<<<(N_EDGES+255)/256, 256, 0, stream>>>(ei, cursor, perm);

  wsplit_kernel<<<(n_fw1+255)/256, 256, 0, stream>>>(fw1, fw1h, fw1l, n_fw1);
  wsplit_kernel<<<(n_fw2+255)/256, 256, 0, stream>>>(fw2, fw2h, fw2l, n_fw2);
  wsplit_kernel<<<(n_l1 +255)/256, 256, 0, stream>>>(l1w, l1h, l1l, n_l1);
  wsplit_kernel<<<(n_l2 +255)/256, 256, 0, stream>>>(l2w, l2h, l2l, n_l2);
  wsplit_kernel<<<(n_l3 +255)/256, 256, 0, stream>>>(l3w, l3h, l3l, n_l3);
  wsplit_kernel<<<(n_em +255)/256, 256, 0, stream>>>(emw, emh, eml, n_em);

  const int GN   = (N_NODES + 127) / 128;   // 391
  const int GE64 = N_EDGES / 64;            // 3125 (exact)

  embed_kernel<<<N_NODES, 128, 0, stream>>>(x, pos, vert, posw, h);
  edgeproj_kernel<<<(N_EDGES*HC + 255)/256, 256, 0, stream>>>(eattr, edgew, ea);
  zero_kernel<<<((N_NODES*NFC/4) + 255)/256, 256, 0, stream>>>(
      (float4*)agg, N_NODES*NFC/4);

  for (int i = 0; i < NLAYER; ++i) {
    ffs_kernel<<<GE64, 256, 0, stream>>>(
        ea, l1h + (size_t)i*NFC*HC, l1l + (size_t)i*NFC*HC,
        fw1h + (size_t)i*NFC*HC, fw1l + (size_t)i*NFC*HC, fb1 + (size_t)i*NFC,
        fw2h + (size_t)i*NFC*NFC, fw2l + (size_t)i*NFC*NFC, fb2 + (size_t)i*NFC,
        ei, perm, h, agg);
    nodeup_kernel<<<GN, 256, 0, stream>>>(
        agg, l2h + (size_t)i*HC*NFC, l2l + (size_t)i*HC*NFC, l2b + (size_t)i*HC,
        l3h + (size_t)i*HC*HC, l3l + (size_t)i*HC*HC, l3b + (size_t)i*HC, h);
    if (i < NLAYER - 1) {
      emlite_kernel<<<GE64, 256, 0, stream>>>(
          ea, emh + (size_t)i*HC*2*HC, eml + (size_t)i*HC*2*HC, emb + (size_t)i*HC,
          ei, h);
    }
  }

  poolhead_kernel<<<N_GRAPH, 256, 0, stream>>>(batch, h, hw1, hb1, hw2, hb2, out);
}

// Round 17
// 2092.503 us; speedup vs baseline: 1.2365x; 1.1752x over previous
//
#include <hip/hip_runtime.h>
#include <hip/hip_bf16.h>
#include <math.h>

#define N_NODES 50000
#define N_EDGES 200000
#define N_GRAPH 1024
#define HC      128
#define NFC     256
#define NLAYER  5
#define NFFC    512

typedef short bf16x8 __attribute__((ext_vector_type(8)));
typedef float f4v    __attribute__((ext_vector_type(4)));

__device__ __forceinline__ float ssp_f(float x) {
  float e = __expf(-fabsf(x));
  return fmaxf(x, 0.0f) + __logf(1.0f + e) - 0.69314718055994530942f;
}
__device__ __forceinline__ float tanh_f(float x) {
  float e = __expf(2.0f * fabsf(x));
  float t = 1.0f - 2.0f * __builtin_amdgcn_rcpf(e + 1.0f);
  return copysignf(t, x);
}
__device__ __forceinline__ unsigned short f2bf(float x) {
  union { float f; unsigned u; } v; v.f = x;
  unsigned r = v.u + 0x7fff + ((v.u >> 16) & 1);
  return (unsigned short)(r >> 16);
}
__device__ __forceinline__ float bf2f(unsigned short b) {
  union { unsigned u; float f; } v; v.u = (unsigned)b << 16; return v.f;
}

// ---------------------------------------------------------------------------
__global__ void zero_kernel(float4* __restrict__ p, int n4) {
  int i = blockIdx.x * blockDim.x + threadIdx.x;
  if (i < n4) p[i] = make_float4(0.f, 0.f, 0.f, 0.f);
}
__global__ void zeroi_kernel(int* __restrict__ p, int n) {
  int i = blockIdx.x * blockDim.x + threadIdx.x;
  if (i < n) p[i] = 0;
}

// ---- dst-sort infrastructure ----------------------------------------------
__global__ void hist_kernel(const int* __restrict__ ei, int* __restrict__ deg) {
  int e = blockIdx.x * blockDim.x + threadIdx.x;
  if (e < N_EDGES) atomicAdd(&deg[ei[N_EDGES + e]], 1);
}
__global__ void scan1_kernel(const int* __restrict__ deg, int* __restrict__ excl,
                             int* __restrict__ bsum, int n) {
  __shared__ int buf[256];
  const int tid = threadIdx.x;
  const int i = blockIdx.x * 256 + tid;
  int v = (i < n) ? deg[i] : 0;
  buf[tid] = v;
  __syncthreads();
  for (int s = 1; s < 256; s <<= 1) {
    int t = (tid >= s) ? buf[tid - s] : 0;
    __syncthreads();
    buf[tid] += t;
    __syncthreads();
  }
  if (i < n) excl[i] = buf[tid] - v;
  if (tid == 255) bsum[blockIdx.x] = buf[255];
}
__global__ void scan2_kernel(int* __restrict__ bsum, int nb) {
  __shared__ int buf[256];
  const int tid = threadIdx.x;
  int v = (tid < nb) ? bsum[tid] : 0;
  buf[tid] = v;
  __syncthreads();
  for (int s = 1; s < 256; s <<= 1) {
    int t = (tid >= s) ? buf[tid - s] : 0;
    __syncthreads();
    buf[tid] += t;
    __syncthreads();
  }
  if (tid < nb) bsum[tid] = buf[tid] - v;
}
__global__ void scan3_kernel(int* __restrict__ excl, const int* __restrict__ bsum, int n) {
  int i = blockIdx.x * 256 + threadIdx.x;
  if (i < n) excl[i] += bsum[blockIdx.x];
}
__global__ void perm_kernel(const int* __restrict__ ei, int* __restrict__ cursor,
                            int* __restrict__ perm) {
  int e = blockIdx.x * blockDim.x + threadIdx.x;
  if (e < N_EDGES) {
    int d = ei[N_EDGES + e];
    int p = atomicAdd(&cursor[d], 1);
    perm[p] = e;
  }
}

// split fp32 weights -> bf16 hi + lo
__global__ void wsplit_kernel(const float* __restrict__ w,
                              unsigned short* __restrict__ hi,
                              unsigned short* __restrict__ lo, int n) {
  int i = blockIdx.x * blockDim.x + threadIdx.x;
  if (i < n) {
    float v = w[i];
    unsigned short hb = f2bf(v);
    hi[i] = hb;
    lo[i] = f2bf(v - bf2f(hb));
  }
}

__global__ void embed_kernel(const int* __restrict__ x, const float* __restrict__ pos,
                             const float* __restrict__ vert, const float* __restrict__ posw,
                             float* __restrict__ h) {
  int n = blockIdx.x;
  int c = threadIdx.x;            // 128 threads
  float v;
  if (c < 80) {
    v = vert[(size_t)x[n] * 80 + c];
  } else {
    int j = c - 80;
    v = pos[n*3+0]*posw[j*3+0] + pos[n*3+1]*posw[j*3+1] + pos[n*3+2]*posw[j*3+2];
  }
  h[(size_t)n*HC + c] = v;
}

__global__ void edgeproj_kernel(const float* __restrict__ eattr, const float* __restrict__ ew,
                                float* __restrict__ ea) {
  int idx = blockIdx.x * blockDim.x + threadIdx.x;
  if (idx >= N_EDGES * HC) return;
  int e = idx >> 7, c = idx & 127;
  const float* a = eattr + (size_t)e*4;
  const float* w = ew + (size_t)c*4;
  ea[idx] = a[0]*w[0] + a[1]*w[1] + a[2]*w[2] + a[3]*w[3];
}

// ---------------------------------------------------------------------------
// Edge-MLP: 64-edge tile, 256 threads, ONE barrier (R16 structure, full split).
__global__ __launch_bounds__(256, 2) void emlite_kernel(
    float* ea,
    const unsigned short* __restrict__ Bh, const unsigned short* __restrict__ Bl,
    const float* __restrict__ bias, const int* __restrict__ ei,
    const float* __restrict__ hfeat)
{
  __shared__ unsigned short ldsA[2][64][136];   // ea split
  __shared__ unsigned short ldsH[2][64][136];   // hsum split

  const int tid  = threadIdx.x;
  const int m0   = blockIdx.x * 64;             // N_EDGES % 64 == 0
  const int lane = tid & 63, wave = tid >> 6;
  const int quad = lane >> 4, l16 = lane & 15;
  const int r = tid >> 2, cb = (tid & 3) * 32;

  const int e = m0 + r;
  const int s = ei[e], d = ei[N_EDGES + e];

  float va[32], v1[32], v2[32];
  {
    const float* ap = ea + (size_t)e * HC + cb;
    const float* p1 = hfeat + (size_t)s * HC + cb;
    const float* p2 = hfeat + (size_t)d * HC + cb;
#pragma unroll
    for (int q = 0; q < 8; q++) *(float4*)&va[q*4] = *(const float4*)(ap + q*4);
#pragma unroll
    for (int q = 0; q < 8; q++) *(float4*)&v1[q*4] = *(const float4*)(p1 + q*4);
#pragma unroll
    for (int q = 0; q < 8; q++) *(float4*)&v2[q*4] = *(const float4*)(p2 + q*4);
  }
  {
    unsigned short th[32], tl[32];
#pragma unroll
    for (int j = 0; j < 32; j++) {
      unsigned short hb = f2bf(va[j]);
      th[j] = hb; tl[j] = f2bf(va[j] - bf2f(hb));
    }
#pragma unroll
    for (int q = 0; q < 4; q++) {
      *(bf16x8*)&ldsA[0][r][cb + q*8] = *(bf16x8*)&th[q*8];
      *(bf16x8*)&ldsA[1][r][cb + q*8] = *(bf16x8*)&tl[q*8];
    }
#pragma unroll
    for (int j = 0; j < 32; j++) {
      float v = v1[j] + v2[j];
      unsigned short hb = f2bf(v);
      th[j] = hb; tl[j] = f2bf(v - bf2f(hb));
    }
#pragma unroll
    for (int q = 0; q < 4; q++) {
      *(bf16x8*)&ldsH[0][r][cb + q*8] = *(bf16x8*)&th[q*8];
      *(bf16x8*)&ldsH[1][r][cb + q*8] = *(bf16x8*)&tl[q*8];
    }
  }

  const f4v zf = {0.f, 0.f, 0.f, 0.f};
  f4v acc[4][2];
#pragma unroll
  for (int mt = 0; mt < 4; mt++) { acc[mt][0] = zf; acc[mt][1] = zf; }

  __syncthreads();   // the only barrier

#pragma unroll
  for (int nt = 0; nt < 2; nt++) {
    const size_t brow = (size_t)(wave*32 + nt*16 + l16);
#pragma unroll
    for (int kk = 0; kk < 128; kk += 32) {
      bf16x8 bh = *(const bf16x8*)&Bh[brow * 2*HC + kk + quad*8];
      bf16x8 bl = *(const bf16x8*)&Bl[brow * 2*HC + kk + quad*8];
#pragma unroll
      for (int mt = 0; mt < 4; mt++) {
        bf16x8 ah = *(const bf16x8*)&ldsA[0][mt*16 + l16][kk + quad*8];
        bf16x8 al = *(const bf16x8*)&ldsA[1][mt*16 + l16][kk + quad*8];
        acc[mt][nt] = __builtin_amdgcn_mfma_f32_16x16x32_bf16(ah, bh, acc[mt][nt], 0, 0, 0);
        acc[mt][nt] = __builtin_amdgcn_mfma_f32_16x16x32_bf16(ah, bl, acc[mt][nt], 0, 0, 0);
        acc[mt][nt] = __builtin_amdgcn_mfma_f32_16x16x32_bf16(al, bh, acc[mt][nt], 0, 0, 0);
      }
    }
#pragma unroll
    for (int kk = 0; kk < 128; kk += 32) {
      bf16x8 bh = *(const bf16x8*)&Bh[brow * 2*HC + HC + kk + quad*8];
      bf16x8 bl = *(const bf16x8*)&Bl[brow * 2*HC + HC + kk + quad*8];
#pragma unroll
      for (int mt = 0; mt < 4; mt++) {
        bf16x8 ah = *(const bf16x8*)&ldsH[0][mt*16 + l16][kk + quad*8];
        bf16x8 al = *(const bf16x8*)&ldsH[1][mt*16 + l16][kk + quad*8];
        acc[mt][nt] = __builtin_amdgcn_mfma_f32_16x16x32_bf16(ah, bh, acc[mt][nt], 0, 0, 0);
        acc[mt][nt] = __builtin_amdgcn_mfma_f32_16x16x32_bf16(ah, bl, acc[mt][nt], 0, 0, 0);
        acc[mt][nt] = __builtin_amdgcn_mfma_f32_16x16x32_bf16(al, bh, acc[mt][nt], 0, 0, 0);
      }
    }
  }

#pragma unroll
  for (int nt = 0; nt < 2; nt++) {
    const int col = wave*32 + nt*16 + l16;
    const float bz = bias[col];
#pragma unroll
    for (int mt = 0; mt < 4; mt++) {
      const int rowb = mt*16 + quad*4;
#pragma unroll
      for (int rr = 0; rr < 4; rr++) {
        const size_t idx = (size_t)(m0 + rowb + rr) * HC + col;
        ea[idx] = tanh_f(acc[mt][nt][rr] + bz) + ea[idx];
      }
    }
  }
}

// ---------------------------------------------------------------------------
// Fused node update (full split, R16 structure + agg self-zero).
__global__ __launch_bounds__(256, 2) void nodeup_kernel(
    float* __restrict__ agg,
    const unsigned short* __restrict__ L2h, const unsigned short* __restrict__ L2l,
    const float* __restrict__ b2,
    const unsigned short* __restrict__ L3h, const unsigned short* __restrict__ L3l,
    const float* __restrict__ b3,
    float* h)
{
  __shared__ unsigned short lds[2 * 128 * 136];
  const int AH = 0, AL = 5120;
  const int TH = 0, TL = 17408;

  const int tid  = threadIdx.x;
  const int m0   = blockIdx.x * 128;
  const int lane = tid & 63, wave = tid >> 6;
  const int quad = lane >> 4, l16 = lane & 15;
  const int wm = (wave >> 1) * 64, wn = (wave & 1) * 64;
  const int r  = tid >> 1;
  const int c0 = (tid & 1) * 16;

  const f4v zf = {0.f, 0.f, 0.f, 0.f};
  f4v acc[4][4];
#pragma unroll
  for (int i = 0; i < 4; i++)
#pragma unroll
    for (int j = 0; j < 4; j++) acc[i][j] = zf;

  const bool mok = (m0 + r) < N_NODES;
  const size_t arow = (size_t)(m0 + r);

  float av[16];
  if (mok) {
    const float* ap = agg + arow * NFC + c0;
#pragma unroll
    for (int q = 0; q < 4; q++) *(float4*)&av[q*4] = *(const float4*)(ap + q*4);
  } else {
#pragma unroll
    for (int j = 0; j < 16; j++) av[j] = 0.f;
  }

  for (int kk = 0; kk < NFC; kk += 32) {
    float avn[16];
    if (kk + 32 < NFC) {
      if (mok) {
        const float* ap = agg + arow * NFC + kk + 32 + c0;
#pragma unroll
        for (int q = 0; q < 4; q++) *(float4*)&avn[q*4] = *(const float4*)(ap + q*4);
      } else {
#pragma unroll
        for (int j = 0; j < 16; j++) avn[j] = 0.f;
      }
    }
    bf16x8 bh[4], bl[4];
#pragma unroll
    for (int nt = 0; nt < 4; nt++) {
      const size_t brow = (size_t)(wn + nt*16 + l16);
      bh[nt] = *(const bf16x8*)&L2h[brow * NFC + kk + quad*8];
      bl[nt] = *(const bf16x8*)&L2l[brow * NFC + kk + quad*8];
    }
    __syncthreads();
    unsigned short th[16], tl[16];
#pragma unroll
    for (int j = 0; j < 16; j++) {
      unsigned short hb = f2bf(av[j]);
      th[j] = hb; tl[j] = f2bf(av[j] - bf2f(hb));
    }
    *(bf16x8*)&lds[AH + r*40 + c0]     = *(bf16x8*)&th[0];
    *(bf16x8*)&lds[AH + r*40 + c0 + 8] = *(bf16x8*)&th[8];
    *(bf16x8*)&lds[AL + r*40 + c0]     = *(bf16x8*)&tl[0];
    *(bf16x8*)&lds[AL + r*40 + c0 + 8] = *(bf16x8*)&tl[8];
    __syncthreads();
    bf16x8 ah[4], al[4];
#pragma unroll
    for (int t = 0; t < 4; t++) {
      const int ra = (wm + t*16 + l16) * 40 + quad * 8;
      ah[t] = *(const bf16x8*)&lds[AH + ra];
      al[t] = *(const bf16x8*)&lds[AL + ra];
    }
#pragma unroll
    for (int mt = 0; mt < 4; mt++)
#pragma unroll
      for (int nt = 0; nt < 4; nt++) {
        acc[mt][nt] = __builtin_amdgcn_mfma_f32_16x16x32_bf16(ah[mt], bh[nt], acc[mt][nt], 0, 0, 0);
        acc[mt][nt] = __builtin_amdgcn_mfma_f32_16x16x32_bf16(ah[mt], bl[nt], acc[mt][nt], 0, 0, 0);
        acc[mt][nt] = __builtin_amdgcn_mfma_f32_16x16x32_bf16(al[mt], bh[nt], acc[mt][nt], 0, 0, 0);
      }
    if (kk + 32 < NFC) {
#pragma unroll
      for (int j = 0; j < 16; j++) av[j] = avn[j];
    }
  }
  __syncthreads();

  if (mok) {
    float4* zp = (float4*)(agg + arow * NFC + (tid & 1) * 128);
    const float4 z4 = make_float4(0.f, 0.f, 0.f, 0.f);
#pragma unroll
    for (int q = 0; q < 32; q++) zp[q] = z4;
  }

#pragma unroll
  for (int nt = 0; nt < 4; nt++) {
    const int col = wn + nt*16 + l16;
    const float bz = b2[col];
#pragma unroll
    for (int mt = 0; mt < 4; mt++) {
      const int rowb = wm + mt*16 + quad*4;
#pragma unroll
      for (int rr = 0; rr < 4; rr++) {
        float v = ssp_f(acc[mt][nt][rr] + bz);
        unsigned short hb = f2bf(v);
        lds[TH + (rowb+rr)*136 + col] = hb;
        lds[TL + (rowb+rr)*136 + col] = f2bf(v - bf2f(hb));
      }
    }
  }
  __syncthreads();

  f4v acc2[4][4];
#pragma unroll
  for (int i = 0; i < 4; i++)
#pragma unroll
    for (int j = 0; j < 4; j++) acc2[i][j] = zf;

  for (int kk = 0; kk < HC; kk += 32) {
    bf16x8 bh[4], bl[4];
#pragma unroll
    for (int nt = 0; nt < 4; nt++) {
      const size_t brow = (size_t)(wn + nt*16 + l16);
      bh[nt] = *(const bf16x8*)&L3h[brow * HC + kk + quad*8];
      bl[nt] = *(const bf16x8*)&L3l[brow * HC + kk + quad*8];
    }
    bf16x8 ah[4], al[4];
#pragma unroll
    for (int t = 0; t < 4; t++) {
      const int ra = (wm + t*16 + l16) * 136 + kk + quad * 8;
      ah[t] = *(const bf16x8*)&lds[TH + ra];
      al[t] = *(const bf16x8*)&lds[TL + ra];
    }
#pragma unroll
    for (int mt = 0; mt < 4; mt++)
#pragma unroll
      for (int nt = 0; nt < 4; nt++) {
        acc2[mt][nt] = __builtin_amdgcn_mfma_f32_16x16x32_bf16(ah[mt], bh[nt], acc2[mt][nt], 0, 0, 0);
        acc2[mt][nt] = __builtin_amdgcn_mfma_f32_16x16x32_bf16(ah[mt], bl[nt], acc2[mt][nt], 0, 0, 0);
        acc2[mt][nt] = __builtin_amdgcn_mfma_f32_16x16x32_bf16(al[mt], bh[nt], acc2[mt][nt], 0, 0, 0);
      }
  }

#pragma unroll
  for (int nt = 0; nt < 4; nt++) {
    const int ncol = wn + nt*16 + l16;
    const float bz = b3[ncol];
#pragma unroll
    for (int mt = 0; mt < 4; mt++) {
      const int mb = wm + mt*16 + quad*4;
#pragma unroll
      for (int rr = 0; rr < 4; rr++) {
        const int m = m0 + mb + rr;
        if (m < N_NODES) {
          const size_t idx = (size_t)m * HC + ncol;
          h[idx] = fmaxf(acc2[mt][nt][rr] + bz, 0.f) + h[idx];
        }
      }
    }
  }
}

// ---------------------------------------------------------------------------
// Fused lin1 + filter MLP + run-reduced scatter.
// R17 EXPERIMENT: B operands (l1/fw1/fw2) PLAIN bf16 (hi only) — 2-term split
// (ah*b + al*b). Cuts MFMAs 480->320 and B fetches 1/3. A stays split.
__device__ __forceinline__ int sigma_row(int r) {
  return ((r >> 2) & 3) * 16 + (r >> 4) * 4 + (r & 3);
}
__global__ __launch_bounds__(256, 3) void ffs_kernel(
    const float* __restrict__ ea,
    const unsigned short* __restrict__ l1h,
    const unsigned short* __restrict__ fw1h,
    const float* __restrict__ fb1,
    const unsigned short* __restrict__ fw2h,
    const float* __restrict__ fb2, const int* __restrict__ ei,
    const int* __restrict__ perm,
    const float* __restrict__ hfeat, float* agg)
{
  __shared__ unsigned short ldsA[2][64][136];
  __shared__ unsigned short ldsT[2][64][72];
  __shared__ int sS[64], sD[64];

  const int tid  = threadIdx.x;
  const int m0   = blockIdx.x * 64;
  const int lane = tid & 63, wave = tid >> 6;
  const int quad = lane >> 4, l16 = lane & 15;

  {
    const int r = tid >> 2, cb = (tid & 3) * 32;
    const int pe = perm[m0 + sigma_row(r)];
    const float* ap = ea + (size_t)pe * HC + cb;
    unsigned short th[32], tl[32];
#pragma unroll
    for (int q = 0; q < 8; q++) {
      float4 v = *(const float4*)(ap + q*4);
      float vv[4] = {v.x, v.y, v.z, v.w};
#pragma unroll
      for (int e = 0; e < 4; e++) {
        unsigned short hb = f2bf(vv[e]);
        th[q*4+e] = hb; tl[q*4+e] = f2bf(vv[e] - bf2f(hb));
      }
    }
#pragma unroll
    for (int q = 0; q < 4; q++) {
      *(bf16x8*)&ldsA[0][r][cb + q*8] = *(bf16x8*)&th[q*8];
      *(bf16x8*)&ldsA[1][r][cb + q*8] = *(bf16x8*)&tl[q*8];
    }
  }
  if (tid < 64) {
    int pe = perm[m0 + sigma_row(tid)];
    sS[tid] = ei[pe];
    sD[tid] = ei[N_EDGES + pe];
  }

  const f4v zf = {0.f, 0.f, 0.f, 0.f};
  __syncthreads();

  f4v hacc[4][4];
#pragma unroll
  for (int mt = 0; mt < 4; mt++)
#pragma unroll
    for (int nt = 0; nt < 4; nt++) hacc[mt][nt] = zf;

  unsigned short* ldsF = &ldsT[0][0][0];
  for (int kk = 0; kk < 128; kk += 32) {
    {
      const int r = tid >> 2, c8 = (tid & 3) * 8;
      const float* hp_ = hfeat + (size_t)sS[r] * HC + kk + c8;
      float4 v0 = *(const float4*)hp_;
      float4 v1 = *(const float4*)(hp_ + 4);
      float vv[8] = {v0.x, v0.y, v0.z, v0.w, v1.x, v1.y, v1.z, v1.w};
      unsigned short th[8], tl[8];
#pragma unroll
      for (int e = 0; e < 8; e++) {
        unsigned short hb = f2bf(vv[e]);
        th[e] = hb; tl[e] = f2bf(vv[e] - bf2f(hb));
      }
      *(bf16x8*)&ldsF[r*40 + c8]        = *(bf16x8*)&th[0];
      *(bf16x8*)&ldsF[2560 + r*40 + c8] = *(bf16x8*)&tl[0];
    }
    __syncthreads();
#pragma unroll
    for (int nt = 0; nt < 4; nt++) {
      const size_t brow = (size_t)(wave*64 + nt*16 + l16);
      bf16x8 b = *(const bf16x8*)&l1h[brow * HC + kk + quad*8];
#pragma unroll
      for (int mt = 0; mt < 4; mt++) {
        bf16x8 ah = *(const bf16x8*)&ldsF[(mt*16 + l16)*40 + quad*8];
        bf16x8 al = *(const bf16x8*)&ldsF[2560 + (mt*16 + l16)*40 + quad*8];
        hacc[mt][nt] = __builtin_amdgcn_mfma_f32_16x16x32_bf16(ah, b, hacc[mt][nt], 0, 0, 0);
        hacc[mt][nt] = __builtin_amdgcn_mfma_f32_16x16x32_bf16(al, b, hacc[mt][nt], 0, 0, 0);
      }
    }
    __syncthreads();
  }

  f4v wacc[4][4];
#pragma unroll
  for (int mt = 0; mt < 4; mt++)
#pragma unroll
    for (int nt = 0; nt < 4; nt++) wacc[mt][nt] = zf;

  for (int p = 0; p < 4; p++) {
    f4v tacc[4];
#pragma unroll
    for (int mt = 0; mt < 4; mt++) tacc[mt] = zf;
    const size_t b1row = (size_t)(p*64 + wave*16 + l16);
#pragma unroll
    for (int kk = 0; kk < 128; kk += 32) {
      bf16x8 b = *(const bf16x8*)&fw1h[b1row * HC + kk + quad*8];
#pragma unroll
      for (int mt = 0; mt < 4; mt++) {
        bf16x8 ah = *(const bf16x8*)&ldsA[0][mt*16 + l16][kk + quad*8];
        bf16x8 al = *(const bf16x8*)&ldsA[1][mt*16 + l16][kk + quad*8];
        tacc[mt] = __builtin_amdgcn_mfma_f32_16x16x32_bf16(ah, b, tacc[mt], 0, 0, 0);
        tacc[mt] = __builtin_amdgcn_mfma_f32_16x16x32_bf16(al, b, tacc[mt], 0, 0, 0);
      }
    }
    {
      const int col = wave*16 + l16;
      const float bz = fb1[p*64 + col];
#pragma unroll
      for (int mt = 0; mt < 4; mt++) {
        const int rowb = mt*16 + quad*4;
#pragma unroll
        for (int rr = 0; rr < 4; rr++) {
          float v = ssp_f(tacc[mt][rr] + bz);
          unsigned short hb = f2bf(v);
          ldsT[0][rowb+rr][col] = hb;
          ldsT[1][rowb+rr][col] = f2bf(v - bf2f(hb));
        }
      }
    }
    __syncthreads();

#pragma unroll
    for (int kc = 0; kc < 2; kc++) {
      bf16x8 a_h[4], a_l[4];
#pragma unroll
      for (int mt = 0; mt < 4; mt++) {
        a_h[mt] = *(const bf16x8*)&ldsT[0][mt*16 + l16][kc*32 + quad*8];
        a_l[mt] = *(const bf16x8*)&ldsT[1][mt*16 + l16][kc*32 + quad*8];
      }
#pragma unroll
      for (int nt = 0; nt < 4; nt++) {
        const size_t brow = (size_t)(wave*64 + nt*16 + l16);
        bf16x8 b = *(const bf16x8*)&fw2h[brow * NFC + p*64 + kc*32 + quad*8];
#pragma unroll
        for (int mt = 0; mt < 4; mt++) {
          wacc[mt][nt] = __builtin_amdgcn_mfma_f32_16x16x32_bf16(a_h[mt], b, wacc[mt][nt], 0, 0, 0);
          wacc[mt][nt] = __builtin_amdgcn_mfma_f32_16x16x32_bf16(a_l[mt], b, wacc[mt][nt], 0, 0, 0);
        }
      }
    }
    __syncthreads();
  }

#pragma unroll
  for (int nt = 0; nt < 4; nt++) {
    const int col = wave*64 + nt*16 + l16;
    const float bz = fb2[col];
    float accum = 0.f;
    int prev = -1;
#pragma unroll
    for (int mt = 0; mt < 4; mt++) {
#pragma unroll
      for (int rr = 0; rr < 4; rr++) {
        const int prow = mt*16 + quad*4 + rr;
        const int d = sD[prow];
        const float v = (wacc[mt][nt][rr] + bz) * hacc[mt][nt][rr];
        if (d != prev) {
          if (prev >= 0) atomicAdd(&agg[(size_t)prev * NFC + col], accum);
          accum = v; prev = d;
        } else {
          accum += v;
        }
      }
    }
    atomicAdd(&agg[(size_t)prev * NFC + col], accum);
  }
}

// ---------------------------------------------------------------------------
// Fused pool + head (batch sorted; per-graph binary search).
__global__ __launch_bounds__(256) void poolhead_kernel(
    const int* __restrict__ batch, const float* __restrict__ h,
    const float* __restrict__ w1, const float* __restrict__ b1,
    const float* __restrict__ w2, const float* __restrict__ b2,
    float* __restrict__ y)
{
  __shared__ float gs[HC];
  __shared__ float red[256];
  const int g = blockIdx.x;
  const int tid = threadIdx.x;

  int lo = 0, hi = N_NODES;
  while (lo < hi) { int m = (lo + hi) >> 1; if (batch[m] < g) lo = m + 1; else hi = m; }
  int lo2 = lo, hi2 = N_NODES;
  while (lo2 < hi2) { int m = (lo2 + hi2) >> 1; if (batch[m] < g + 1) lo2 = m + 1; else hi2 = m; }
  const int cnt = lo2 - lo;

  if (tid < HC) {
    float s = 0.f;
    for (int i = lo; i < lo2; i++) s += h[(size_t)i * HC + tid];
    gs[tid] = s / (float)max(cnt, 1);
  }
  __syncthreads();

  float partial = 0.f;
  for (int f = tid; f < NFFC; f += 256) {
    float acc = b1[f];
    const float* wr = w1 + (size_t)f * HC;
#pragma unroll 8
    for (int k = 0; k < HC; k++) acc = fmaf(gs[k], wr[k], acc);
    float t = 0.5f * acc * (1.0f + erff(acc * 0.70710678118654752440f));
    partial = fmaf(t, w2[f], partial);
  }
  red[tid] = partial;
  __syncthreads();
  for (int s = 128; s > 0; s >>= 1) {
    if (tid < s) red[tid] += red[tid + s];
    __syncthreads();
  }
  if (tid == 0) y[g] = red[0] + b2[0];
}

// ---------------------------------------------------------------------------
extern "C" void kernel_launch(void* const* d_in, const int* in_sizes, int n_in,
                              void* d_out, int out_size, void* d_ws, size_t ws_size,
                              hipStream_t stream) {
  const int*   x     = (const int*)  d_in[0];
  const int*   ei    = (const int*)  d_in[1];
  const float* eattr = (const float*)d_in[2];
  const int*   batch = (const int*)  d_in[3];
  const float* pos   = (const float*)d_in[4];
  const float* vert  = (const float*)d_in[5];
  const float* posw  = (const float*)d_in[6];
  const float* edgew = (const float*)d_in[7];
  const float* fw1   = (const float*)d_in[8];
  const float* fb1   = (const float*)d_in[9];
  const float* fw2   = (const float*)d_in[10];
  const float* fb2   = (const float*)d_in[11];
  const float* l1w   = (const float*)d_in[12];
  const float* l2w   = (const float*)d_in[13];
  const float* l2b   = (const float*)d_in[14];
  const float* l3w   = (const float*)d_in[15];
  const float* l3b   = (const float*)d_in[16];
  const float* emw   = (const float*)d_in[17];
  const float* emb   = (const float*)d_in[18];
  const float* hw1   = (const float*)d_in[19];
  const float* hb1   = (const float*)d_in[20];
  const float* hw2   = (const float*)d_in[21];
  const float* hb2   = (const float*)d_in[22];
  float* out = (float*)d_out;

  char* ws = (char*)d_ws;
  size_t off = 0;
  auto alloc = [&](size_t bytes) { char* p = ws + off; off += (bytes + 511) & ~(size_t)511; return p; };
  float* ea   = (float*)alloc((size_t)N_EDGES*HC*4);
  float* h    = (float*)alloc((size_t)N_NODES*HC*4);
  float* agg  = (float*)alloc((size_t)N_NODES*NFC*4);
  int* deg    = (int*)alloc((size_t)(N_NODES+1)*4);
  int* cursor = (int*)alloc((size_t)(N_NODES+1)*4);
  int* bsum   = (int*)alloc((size_t)256*4);
  int* perm   = (int*)alloc((size_t)N_EDGES*4);
  const int n_fw1 = NLAYER*NFC*HC, n_fw2 = NLAYER*NFC*NFC, n_l1 = NLAYER*NFC*HC;
  const int n_l2 = NLAYER*HC*NFC, n_l3 = NLAYER*HC*HC, n_em = NLAYER*HC*2*HC;
  unsigned short* fw1h = (unsigned short*)alloc((size_t)n_fw1*2);
  unsigned short* fw1l = (unsigned short*)alloc((size_t)n_fw1*2);
  unsigned short* fw2h = (unsigned short*)alloc((size_t)n_fw2*2);
  unsigned short* fw2l = (unsigned short*)alloc((size_t)n_fw2*2);
  unsigned short* l1h  = (unsigned short*)alloc((size_t)n_l1*2);
  unsigned short* l1l  = (unsigned short*)alloc((size_t)n_l1*2);
  unsigned short* l2h  = (unsigned short*)alloc((size_t)n_l2*2);
  unsigned short* l2l  = (unsigned short*)alloc((size_t)n_l2*2);
  unsigned short* l3h  = (unsigned short*)alloc((size_t)n_l3*2);
  unsigned short* l3l  = (unsigned short*)alloc((size_t)n_l3*2);
  unsigned short* emh  = (unsigned short*)alloc((size_t)n_em*2);
  unsigned short* eml  = (unsigned short*)alloc((size_t)n_em*2);

  const int NSCAN = N_NODES + 1;                 // 50001
  const int NB    = (NSCAN + 255) / 256;         // 196

  zeroi_kernel<<<(NSCAN+255)/256, 256, 0, stream>>>(deg, NSCAN);
  hist_kernel<<<(N_EDGES+255)/256, 256, 0, stream>>>(ei, deg);
  scan1_kernel<<<NB, 256, 0, stream>>>(deg, cursor, bsum, NSCAN);
  scan2_kernel<<<1, 256, 0, stream>>>(bsum, NB);
  scan3_kernel<<<NB, 256, 0, stream>>>(cursor, bsum, NSCAN);
  perm_kernel<<<(N_EDGES+255)/256, 256, 0, stream>>>(ei, cursor, perm);

  wsplit_kernel<<<(n_fw1+255)/256, 256, 0, stream>>>(fw1, fw1h, fw1l, n_fw1);
  wsplit_kernel<<<(n_fw2+255)/256, 256, 0, stream>>>(fw2, fw2h, fw2l, n_fw2);
  wsplit_kernel<<<(n_l1 +255)/256, 256, 0, stream>>>(l1w, l1h, l1l, n_l1);
  wsplit_kernel<<<(n_l2 +255)/256, 256, 0, stream>>>(l2w, l2h, l2l, n_l2);
  wsplit_kernel<<<(n_l3 +255)/256, 256, 0, stream>>>(l3w, l3h, l3l, n_l3);
  wsplit_kernel<<<(n_em +255)/256, 256, 0, stream>>>(emw, emh, eml, n_em);

  const int GN   = (N_NODES + 127) / 128;   // 391
  const int GE64 = N_EDGES / 64;            // 3125 (exact)

  embed_kernel<<<N_NODES, 128, 0, stream>>>(x, pos, vert, posw, h);
  edgeproj_kernel<<<(N_EDGES*HC + 255)/256, 256, 0, stream>>>(eattr, edgew, ea);
  zero_kernel<<<((N_NODES*NFC/4) + 255)/256, 256, 0, stream>>>(
      (float4*)agg, N_NODES*NFC/4);

  for (int i = 0; i < NLAYER; ++i) {
    ffs_kernel<<<GE64, 256, 0, stream>>>(
        ea, l1h + (size_t)i*NFC*HC,
        fw1h + (size_t)i*NFC*HC, fb1 + (size_t)i*NFC,
        fw2h + (size_t)i*NFC*NFC, fb2 + (size_t)i*NFC,
        ei, perm, h, agg);
    nodeup_kernel<<<GN, 256, 0, stream>>>(
        agg, l2h + (size_t)i*HC*NFC, l2l + (size_t)i*HC*NFC, l2b + (size_t)i*HC,
        l3h + (size_t)i*HC*HC, l3l + (size_t)i*HC*HC, l3b + (size_t)i*HC, h);
    if (i < NLAYER - 1) {
      emlite_kernel<<<GE64, 256, 0, stream>>>(
          ea, emh + (size_t)i*HC*2*HC, eml + (size_t)i*HC*2*HC, emb + (size_t)i*HC,
          ei, h);
    }
  }

  poolhead_kernel<<<N_GRAPH, 256, 0, stream>>>(batch, h, hw1, hb1, hw2, hb2, out);
}

// Round 18
// 1971.514 us; speedup vs baseline: 1.3124x; 1.0614x over previous
//
#include <hip/hip_runtime.h>
#include <hip/hip_bf16.h>
#include <math.h>

#define N_NODES 50000
#define N_EDGES 200000
#define N_GRAPH 1024
#define HC      128
#define NFC     256
#define NLAYER  5
#define NFFC    512

typedef short bf16x8 __attribute__((ext_vector_type(8)));
typedef float f4v    __attribute__((ext_vector_type(4)));

__device__ __forceinline__ float ssp_f(float x) {
  float e = __expf(-fabsf(x));
  return fmaxf(x, 0.0f) + __logf(1.0f + e) - 0.69314718055994530942f;
}
__device__ __forceinline__ float tanh_f(float x) {
  float e = __expf(2.0f * fabsf(x));
  float t = 1.0f - 2.0f * __builtin_amdgcn_rcpf(e + 1.0f);
  return copysignf(t, x);
}
__device__ __forceinline__ unsigned short f2bf(float x) {
  union { float f; unsigned u; } v; v.f = x;
  unsigned r = v.u + 0x7fff + ((v.u >> 16) & 1);
  return (unsigned short)(r >> 16);
}
__device__ __forceinline__ float bf2f(unsigned short b) {
  union { unsigned u; float f; } v; v.u = (unsigned)b << 16; return v.f;
}

// ---------------------------------------------------------------------------
__global__ void zero_kernel(float4* __restrict__ p, int n4) {
  int i = blockIdx.x * blockDim.x + threadIdx.x;
  if (i < n4) p[i] = make_float4(0.f, 0.f, 0.f, 0.f);
}
__global__ void zeroi_kernel(int* __restrict__ p, int n) {
  int i = blockIdx.x * blockDim.x + threadIdx.x;
  if (i < n) p[i] = 0;
}

// ---- dst-sort infrastructure ----------------------------------------------
__global__ void hist_kernel(const int* __restrict__ ei, int* __restrict__ deg) {
  int e = blockIdx.x * blockDim.x + threadIdx.x;
  if (e < N_EDGES) atomicAdd(&deg[ei[N_EDGES + e]], 1);
}
__global__ void scan1_kernel(const int* __restrict__ deg, int* __restrict__ excl,
                             int* __restrict__ bsum, int n) {
  __shared__ int buf[256];
  const int tid = threadIdx.x;
  const int i = blockIdx.x * 256 + tid;
  int v = (i < n) ? deg[i] : 0;
  buf[tid] = v;
  __syncthreads();
  for (int s = 1; s < 256; s <<= 1) {
    int t = (tid >= s) ? buf[tid - s] : 0;
    __syncthreads();
    buf[tid] += t;
    __syncthreads();
  }
  if (i < n) excl[i] = buf[tid] - v;
  if (tid == 255) bsum[blockIdx.x] = buf[255];
}
__global__ void scan2_kernel(int* __restrict__ bsum, int nb) {
  __shared__ int buf[256];
  const int tid = threadIdx.x;
  int v = (tid < nb) ? bsum[tid] : 0;
  buf[tid] = v;
  __syncthreads();
  for (int s = 1; s < 256; s <<= 1) {
    int t = (tid >= s) ? buf[tid - s] : 0;
    __syncthreads();
    buf[tid] += t;
    __syncthreads();
  }
  if (tid < nb) bsum[tid] = buf[tid] - v;
}
__global__ void scan3_kernel(int* __restrict__ excl, const int* __restrict__ bsum, int n) {
  int i = blockIdx.x * 256 + threadIdx.x;
  if (i < n) excl[i] += bsum[blockIdx.x];
}
__global__ void perm_kernel(const int* __restrict__ ei, int* __restrict__ cursor,
                            int* __restrict__ perm) {
  int e = blockIdx.x * blockDim.x + threadIdx.x;
  if (e < N_EDGES) {
    int d = ei[N_EDGES + e];
    int p = atomicAdd(&cursor[d], 1);
    perm[p] = e;
  }
}

// convert fp32 weights -> plain bf16 (round-to-nearest-even)
__global__ void wconv_kernel(const float* __restrict__ w,
                             unsigned short* __restrict__ hi, int n) {
  int i = blockIdx.x * blockDim.x + threadIdx.x;
  if (i < n) hi[i] = f2bf(w[i]);
}

__global__ void embed_kernel(const int* __restrict__ x, const float* __restrict__ pos,
                             const float* __restrict__ vert, const float* __restrict__ posw,
                             float* __restrict__ h) {
  int n = blockIdx.x;
  int c = threadIdx.x;            // 128 threads
  float v;
  if (c < 80) {
    v = vert[(size_t)x[n] * 80 + c];
  } else {
    int j = c - 80;
    v = pos[n*3+0]*posw[j*3+0] + pos[n*3+1]*posw[j*3+1] + pos[n*3+2]*posw[j*3+2];
  }
  h[(size_t)n*HC + c] = v;
}

__global__ void edgeproj_kernel(const float* __restrict__ eattr, const float* __restrict__ ew,
                                float* __restrict__ ea) {
  int idx = blockIdx.x * blockDim.x + threadIdx.x;
  if (idx >= N_EDGES * HC) return;
  int e = idx >> 7, c = idx & 127;
  const float* a = eattr + (size_t)e*4;
  const float* w = ew + (size_t)c*4;
  ea[idx] = a[0]*w[0] + a[1]*w[1] + a[2]*w[2] + a[3]*w[3];
}

// ---------------------------------------------------------------------------
// Edge-MLP: 64-edge tile, 256 threads, ONE barrier. Plain-bf16 B (R18),
// split A: acc += ah*b + al*b.
__global__ __launch_bounds__(256, 2) void emlite_kernel(
    float* ea,
    const unsigned short* __restrict__ Bh,
    const float* __restrict__ bias, const int* __restrict__ ei,
    const float* __restrict__ hfeat)
{
  __shared__ unsigned short ldsA[2][64][136];   // ea split
  __shared__ unsigned short ldsH[2][64][136];   // hsum split

  const int tid  = threadIdx.x;
  const int m0   = blockIdx.x * 64;             // N_EDGES % 64 == 0
  const int lane = tid & 63, wave = tid >> 6;
  const int quad = lane >> 4, l16 = lane & 15;
  const int r = tid >> 2, cb = (tid & 3) * 32;

  const int e = m0 + r;
  const int s = ei[e], d = ei[N_EDGES + e];

  float va[32], v1[32], v2[32];
  {
    const float* ap = ea + (size_t)e * HC + cb;
    const float* p1 = hfeat + (size_t)s * HC + cb;
    const float* p2 = hfeat + (size_t)d * HC + cb;
#pragma unroll
    for (int q = 0; q < 8; q++) *(float4*)&va[q*4] = *(const float4*)(ap + q*4);
#pragma unroll
    for (int q = 0; q < 8; q++) *(float4*)&v1[q*4] = *(const float4*)(p1 + q*4);
#pragma unroll
    for (int q = 0; q < 8; q++) *(float4*)&v2[q*4] = *(const float4*)(p2 + q*4);
  }
  {
    unsigned short th[32], tl[32];
#pragma unroll
    for (int j = 0; j < 32; j++) {
      unsigned short hb = f2bf(va[j]);
      th[j] = hb; tl[j] = f2bf(va[j] - bf2f(hb));
    }
#pragma unroll
    for (int q = 0; q < 4; q++) {
      *(bf16x8*)&ldsA[0][r][cb + q*8] = *(bf16x8*)&th[q*8];
      *(bf16x8*)&ldsA[1][r][cb + q*8] = *(bf16x8*)&tl[q*8];
    }
#pragma unroll
    for (int j = 0; j < 32; j++) {
      float v = v1[j] + v2[j];
      unsigned short hb = f2bf(v);
      th[j] = hb; tl[j] = f2bf(v - bf2f(hb));
    }
#pragma unroll
    for (int q = 0; q < 4; q++) {
      *(bf16x8*)&ldsH[0][r][cb + q*8] = *(bf16x8*)&th[q*8];
      *(bf16x8*)&ldsH[1][r][cb + q*8] = *(bf16x8*)&tl[q*8];
    }
  }

  const f4v zf = {0.f, 0.f, 0.f, 0.f};
  f4v acc[4][2];
#pragma unroll
  for (int mt = 0; mt < 4; mt++) { acc[mt][0] = zf; acc[mt][1] = zf; }

  __syncthreads();   // the only barrier

#pragma unroll
  for (int nt = 0; nt < 2; nt++) {
    const size_t brow = (size_t)(wave*32 + nt*16 + l16);
#pragma unroll
    for (int kk = 0; kk < 128; kk += 32) {
      bf16x8 b = *(const bf16x8*)&Bh[brow * 2*HC + kk + quad*8];
#pragma unroll
      for (int mt = 0; mt < 4; mt++) {
        bf16x8 ah = *(const bf16x8*)&ldsA[0][mt*16 + l16][kk + quad*8];
        bf16x8 al = *(const bf16x8*)&ldsA[1][mt*16 + l16][kk + quad*8];
        acc[mt][nt] = __builtin_amdgcn_mfma_f32_16x16x32_bf16(ah, b, acc[mt][nt], 0, 0, 0);
        acc[mt][nt] = __builtin_amdgcn_mfma_f32_16x16x32_bf16(al, b, acc[mt][nt], 0, 0, 0);
      }
    }
#pragma unroll
    for (int kk = 0; kk < 128; kk += 32) {
      bf16x8 b = *(const bf16x8*)&Bh[brow * 2*HC + HC + kk + quad*8];
#pragma unroll
      for (int mt = 0; mt < 4; mt++) {
        bf16x8 ah = *(const bf16x8*)&ldsH[0][mt*16 + l16][kk + quad*8];
        bf16x8 al = *(const bf16x8*)&ldsH[1][mt*16 + l16][kk + quad*8];
        acc[mt][nt] = __builtin_amdgcn_mfma_f32_16x16x32_bf16(ah, b, acc[mt][nt], 0, 0, 0);
        acc[mt][nt] = __builtin_amdgcn_mfma_f32_16x16x32_bf16(al, b, acc[mt][nt], 0, 0, 0);
      }
    }
  }

#pragma unroll
  for (int nt = 0; nt < 2; nt++) {
    const int col = wave*32 + nt*16 + l16;
    const float bz = bias[col];
#pragma unroll
    for (int mt = 0; mt < 4; mt++) {
      const int rowb = mt*16 + quad*4;
#pragma unroll
      for (int rr = 0; rr < 4; rr++) {
        const size_t idx = (size_t)(m0 + rowb + rr) * HC + col;
        ea[idx] = tanh_f(acc[mt][nt][rr] + bz) + ea[idx];
      }
    }
  }
}

// ---------------------------------------------------------------------------
// Fused node update (plain-bf16 B, split A) + agg self-zero.
__global__ __launch_bounds__(256, 2) void nodeup_kernel(
    float* __restrict__ agg,
    const unsigned short* __restrict__ L2h,
    const float* __restrict__ b2,
    const unsigned short* __restrict__ L3h,
    const float* __restrict__ b3,
    float* h)
{
  __shared__ unsigned short lds[2 * 128 * 136];
  const int AH = 0, AL = 5120;
  const int TH = 0, TL = 17408;

  const int tid  = threadIdx.x;
  const int m0   = blockIdx.x * 128;
  const int lane = tid & 63, wave = tid >> 6;
  const int quad = lane >> 4, l16 = lane & 15;
  const int wm = (wave >> 1) * 64, wn = (wave & 1) * 64;
  const int r  = tid >> 1;
  const int c0 = (tid & 1) * 16;

  const f4v zf = {0.f, 0.f, 0.f, 0.f};
  f4v acc[4][4];
#pragma unroll
  for (int i = 0; i < 4; i++)
#pragma unroll
    for (int j = 0; j < 4; j++) acc[i][j] = zf;

  const bool mok = (m0 + r) < N_NODES;
  const size_t arow = (size_t)(m0 + r);

  float av[16];
  if (mok) {
    const float* ap = agg + arow * NFC + c0;
#pragma unroll
    for (int q = 0; q < 4; q++) *(float4*)&av[q*4] = *(const float4*)(ap + q*4);
  } else {
#pragma unroll
    for (int j = 0; j < 16; j++) av[j] = 0.f;
  }

  for (int kk = 0; kk < NFC; kk += 32) {
    float avn[16];
    if (kk + 32 < NFC) {
      if (mok) {
        const float* ap = agg + arow * NFC + kk + 32 + c0;
#pragma unroll
        for (int q = 0; q < 4; q++) *(float4*)&avn[q*4] = *(const float4*)(ap + q*4);
      } else {
#pragma unroll
        for (int j = 0; j < 16; j++) avn[j] = 0.f;
      }
    }
    bf16x8 b[4];
#pragma unroll
    for (int nt = 0; nt < 4; nt++) {
      const size_t brow = (size_t)(wn + nt*16 + l16);
      b[nt] = *(const bf16x8*)&L2h[brow * NFC + kk + quad*8];
    }
    __syncthreads();
    unsigned short th[16], tl[16];
#pragma unroll
    for (int j = 0; j < 16; j++) {
      unsigned short hb = f2bf(av[j]);
      th[j] = hb; tl[j] = f2bf(av[j] - bf2f(hb));
    }
    *(bf16x8*)&lds[AH + r*40 + c0]     = *(bf16x8*)&th[0];
    *(bf16x8*)&lds[AH + r*40 + c0 + 8] = *(bf16x8*)&th[8];
    *(bf16x8*)&lds[AL + r*40 + c0]     = *(bf16x8*)&tl[0];
    *(bf16x8*)&lds[AL + r*40 + c0 + 8] = *(bf16x8*)&tl[8];
    __syncthreads();
    bf16x8 ah[4], al[4];
#pragma unroll
    for (int t = 0; t < 4; t++) {
      const int ra = (wm + t*16 + l16) * 40 + quad * 8;
      ah[t] = *(const bf16x8*)&lds[AH + ra];
      al[t] = *(const bf16x8*)&lds[AL + ra];
    }
#pragma unroll
    for (int mt = 0; mt < 4; mt++)
#pragma unroll
      for (int nt = 0; nt < 4; nt++) {
        acc[mt][nt] = __builtin_amdgcn_mfma_f32_16x16x32_bf16(ah[mt], b[nt], acc[mt][nt], 0, 0, 0);
        acc[mt][nt] = __builtin_amdgcn_mfma_f32_16x16x32_bf16(al[mt], b[nt], acc[mt][nt], 0, 0, 0);
      }
    if (kk + 32 < NFC) {
#pragma unroll
      for (int j = 0; j < 16; j++) av[j] = avn[j];
    }
  }
  __syncthreads();

  if (mok) {
    float4* zp = (float4*)(agg + arow * NFC + (tid & 1) * 128);
    const float4 z4 = make_float4(0.f, 0.f, 0.f, 0.f);
#pragma unroll
    for (int q = 0; q < 32; q++) zp[q] = z4;
  }

#pragma unroll
  for (int nt = 0; nt < 4; nt++) {
    const int col = wn + nt*16 + l16;
    const float bz = b2[col];
#pragma unroll
    for (int mt = 0; mt < 4; mt++) {
      const int rowb = wm + mt*16 + quad*4;
#pragma unroll
      for (int rr = 0; rr < 4; rr++) {
        float v = ssp_f(acc[mt][nt][rr] + bz);
        unsigned short hb = f2bf(v);
        lds[TH + (rowb+rr)*136 + col] = hb;
        lds[TL + (rowb+rr)*136 + col] = f2bf(v - bf2f(hb));
      }
    }
  }
  __syncthreads();

  f4v acc2[4][4];
#pragma unroll
  for (int i = 0; i < 4; i++)
#pragma unroll
    for (int j = 0; j < 4; j++) acc2[i][j] = zf;

  for (int kk = 0; kk < HC; kk += 32) {
    bf16x8 b[4];
#pragma unroll
    for (int nt = 0; nt < 4; nt++) {
      const size_t brow = (size_t)(wn + nt*16 + l16);
      b[nt] = *(const bf16x8*)&L3h[brow * HC + kk + quad*8];
    }
    bf16x8 ah[4], al[4];
#pragma unroll
    for (int t = 0; t < 4; t++) {
      const int ra = (wm + t*16 + l16) * 136 + kk + quad * 8;
      ah[t] = *(const bf16x8*)&lds[TH + ra];
      al[t] = *(const bf16x8*)&lds[TL + ra];
    }
#pragma unroll
    for (int mt = 0; mt < 4; mt++)
#pragma unroll
      for (int nt = 0; nt < 4; nt++) {
        acc2[mt][nt] = __builtin_amdgcn_mfma_f32_16x16x32_bf16(ah[mt], b[nt], acc2[mt][nt], 0, 0, 0);
        acc2[mt][nt] = __builtin_amdgcn_mfma_f32_16x16x32_bf16(al[mt], b[nt], acc2[mt][nt], 0, 0, 0);
      }
  }

#pragma unroll
  for (int nt = 0; nt < 4; nt++) {
    const int ncol = wn + nt*16 + l16;
    const float bz = b3[ncol];
#pragma unroll
    for (int mt = 0; mt < 4; mt++) {
      const int mb = wm + mt*16 + quad*4;
#pragma unroll
      for (int rr = 0; rr < 4; rr++) {
        const int m = m0 + mb + rr;
        if (m < N_NODES) {
          const size_t idx = (size_t)m * HC + ncol;
          h[idx] = fmaxf(acc2[mt][nt][rr] + bz, 0.f) + h[idx];
        }
      }
    }
  }
}

// ---------------------------------------------------------------------------
// Fused lin1 + filter MLP + run-reduced scatter (R17 plain-B structure).
__device__ __forceinline__ int sigma_row(int r) {
  return ((r >> 2) & 3) * 16 + (r >> 4) * 4 + (r & 3);
}
__global__ __launch_bounds__(256, 3) void ffs_kernel(
    const float* __restrict__ ea,
    const unsigned short* __restrict__ l1h,
    const unsigned short* __restrict__ fw1h,
    const float* __restrict__ fb1,
    const unsigned short* __restrict__ fw2h,
    const float* __restrict__ fb2, const int* __restrict__ ei,
    const int* __restrict__ perm,
    const float* __restrict__ hfeat, float* agg)
{
  __shared__ unsigned short ldsA[2][64][136];
  __shared__ unsigned short ldsT[2][64][72];
  __shared__ int sS[64], sD[64];

  const int tid  = threadIdx.x;
  const int m0   = blockIdx.x * 64;
  const int lane = tid & 63, wave = tid >> 6;
  const int quad = lane >> 4, l16 = lane & 15;

  {
    const int r = tid >> 2, cb = (tid & 3) * 32;
    const int pe = perm[m0 + sigma_row(r)];
    const float* ap = ea + (size_t)pe * HC + cb;
    unsigned short th[32], tl[32];
#pragma unroll
    for (int q = 0; q < 8; q++) {
      float4 v = *(const float4*)(ap + q*4);
      float vv[4] = {v.x, v.y, v.z, v.w};
#pragma unroll
      for (int e = 0; e < 4; e++) {
        unsigned short hb = f2bf(vv[e]);
        th[q*4+e] = hb; tl[q*4+e] = f2bf(vv[e] - bf2f(hb));
      }
    }
#pragma unroll
    for (int q = 0; q < 4; q++) {
      *(bf16x8*)&ldsA[0][r][cb + q*8] = *(bf16x8*)&th[q*8];
      *(bf16x8*)&ldsA[1][r][cb + q*8] = *(bf16x8*)&tl[q*8];
    }
  }
  if (tid < 64) {
    int pe = perm[m0 + sigma_row(tid)];
    sS[tid] = ei[pe];
    sD[tid] = ei[N_EDGES + pe];
  }

  const f4v zf = {0.f, 0.f, 0.f, 0.f};
  __syncthreads();

  f4v hacc[4][4];
#pragma unroll
  for (int mt = 0; mt < 4; mt++)
#pragma unroll
    for (int nt = 0; nt < 4; nt++) hacc[mt][nt] = zf;

  unsigned short* ldsF = &ldsT[0][0][0];
  for (int kk = 0; kk < 128; kk += 32) {
    {
      const int r = tid >> 2, c8 = (tid & 3) * 8;
      const float* hp_ = hfeat + (size_t)sS[r] * HC + kk + c8;
      float4 v0 = *(const float4*)hp_;
      float4 v1 = *(const float4*)(hp_ + 4);
      float vv[8] = {v0.x, v0.y, v0.z, v0.w, v1.x, v1.y, v1.z, v1.w};
      unsigned short th[8], tl[8];
#pragma unroll
      for (int e = 0; e < 8; e++) {
        unsigned short hb = f2bf(vv[e]);
        th[e] = hb; tl[e] = f2bf(vv[e] - bf2f(hb));
      }
      *(bf16x8*)&ldsF[r*40 + c8]        = *(bf16x8*)&th[0];
      *(bf16x8*)&ldsF[2560 + r*40 + c8] = *(bf16x8*)&tl[0];
    }
    __syncthreads();
#pragma unroll
    for (int nt = 0; nt < 4; nt++) {
      const size_t brow = (size_t)(wave*64 + nt*16 + l16);
      bf16x8 b = *(const bf16x8*)&l1h[brow * HC + kk + quad*8];
#pragma unroll
      for (int mt = 0; mt < 4; mt++) {
        bf16x8 ah = *(const bf16x8*)&ldsF[(mt*16 + l16)*40 + quad*8];
        bf16x8 al = *(const bf16x8*)&ldsF[2560 + (mt*16 + l16)*40 + quad*8];
        hacc[mt][nt] = __builtin_amdgcn_mfma_f32_16x16x32_bf16(ah, b, hacc[mt][nt], 0, 0, 0);
        hacc[mt][nt] = __builtin_amdgcn_mfma_f32_16x16x32_bf16(al, b, hacc[mt][nt], 0, 0, 0);
      }
    }
    __syncthreads();
  }

  f4v wacc[4][4];
#pragma unroll
  for (int mt = 0; mt < 4; mt++)
#pragma unroll
    for (int nt = 0; nt < 4; nt++) wacc[mt][nt] = zf;

  for (int p = 0; p < 4; p++) {
    f4v tacc[4];
#pragma unroll
    for (int mt = 0; mt < 4; mt++) tacc[mt] = zf;
    const size_t b1row = (size_t)(p*64 + wave*16 + l16);
#pragma unroll
    for (int kk = 0; kk < 128; kk += 32) {
      bf16x8 b = *(const bf16x8*)&fw1h[b1row * HC + kk + quad*8];
#pragma unroll
      for (int mt = 0; mt < 4; mt++) {
        bf16x8 ah = *(const bf16x8*)&ldsA[0][mt*16 + l16][kk + quad*8];
        bf16x8 al = *(const bf16x8*)&ldsA[1][mt*16 + l16][kk + quad*8];
        tacc[mt] = __builtin_amdgcn_mfma_f32_16x16x32_bf16(ah, b, tacc[mt], 0, 0, 0);
        tacc[mt] = __builtin_amdgcn_mfma_f32_16x16x32_bf16(al, b, tacc[mt], 0, 0, 0);
      }
    }
    {
      const int col = wave*16 + l16;
      const float bz = fb1[p*64 + col];
#pragma unroll
      for (int mt = 0; mt < 4; mt++) {
        const int rowb = mt*16 + quad*4;
#pragma unroll
        for (int rr = 0; rr < 4; rr++) {
          float v = ssp_f(tacc[mt][rr] + bz);
          unsigned short hb = f2bf(v);
          ldsT[0][rowb+rr][col] = hb;
          ldsT[1][rowb+rr][col] = f2bf(v - bf2f(hb));
        }
      }
    }
    __syncthreads();

#pragma unroll
    for (int kc = 0; kc < 2; kc++) {
      bf16x8 a_h[4], a_l[4];
#pragma unroll
      for (int mt = 0; mt < 4; mt++) {
        a_h[mt] = *(const bf16x8*)&ldsT[0][mt*16 + l16][kc*32 + quad*8];
        a_l[mt] = *(const bf16x8*)&ldsT[1][mt*16 + l16][kc*32 + quad*8];
      }
#pragma unroll
      for (int nt = 0; nt < 4; nt++) {
        const size_t brow = (size_t)(wave*64 + nt*16 + l16);
        bf16x8 b = *(const bf16x8*)&fw2h[brow * NFC + p*64 + kc*32 + quad*8];
#pragma unroll
        for (int mt = 0; mt < 4; mt++) {
          wacc[mt][nt] = __builtin_amdgcn_mfma_f32_16x16x32_bf16(a_h[mt], b, wacc[mt][nt], 0, 0, 0);
          wacc[mt][nt] = __builtin_amdgcn_mfma_f32_16x16x32_bf16(a_l[mt], b, wacc[mt][nt], 0, 0, 0);
        }
      }
    }
    __syncthreads();
  }

#pragma unroll
  for (int nt = 0; nt < 4; nt++) {
    const int col = wave*64 + nt*16 + l16;
    const float bz = fb2[col];
    float accum = 0.f;
    int prev = -1;
#pragma unroll
    for (int mt = 0; mt < 4; mt++) {
#pragma unroll
      for (int rr = 0; rr < 4; rr++) {
        const int prow = mt*16 + quad*4 + rr;
        const int d = sD[prow];
        const float v = (wacc[mt][nt][rr] + bz) * hacc[mt][nt][rr];
        if (d != prev) {
          if (prev >= 0) atomicAdd(&agg[(size_t)prev * NFC + col], accum);
          accum = v; prev = d;
        } else {
          accum += v;
        }
      }
    }
    atomicAdd(&agg[(size_t)prev * NFC + col], accum);
  }
}

// ---------------------------------------------------------------------------
// Fused pool + head (batch sorted; per-graph binary search).
__global__ __launch_bounds__(256) void poolhead_kernel(
    const int* __restrict__ batch, const float* __restrict__ h,
    const float* __restrict__ w1, const float* __restrict__ b1,
    const float* __restrict__ w2, const float* __restrict__ b2,
    float* __restrict__ y)
{
  __shared__ float gs[HC];
  __shared__ float red[256];
  const int g = blockIdx.x;
  const int tid = threadIdx.x;

  int lo = 0, hi = N_NODES;
  while (lo < hi) { int m = (lo + hi) >> 1; if (batch[m] < g) lo = m + 1; else hi = m; }
  int lo2 = lo, hi2 = N_NODES;
  while (lo2 < hi2) { int m = (lo2 + hi2) >> 1; if (batch[m] < g + 1) lo2 = m + 1; else hi2 = m; }
  const int cnt = lo2 - lo;

  if (tid < HC) {
    float s = 0.f;
    for (int i = lo; i < lo2; i++) s += h[(size_t)i * HC + tid];
    gs[tid] = s / (float)max(cnt, 1);
  }
  __syncthreads();

  float partial = 0.f;
  for (int f = tid; f < NFFC; f += 256) {
    float acc = b1[f];
    const float* wr = w1 + (size_t)f * HC;
#pragma unroll 8
    for (int k = 0; k < HC; k++) acc = fmaf(gs[k], wr[k], acc);
    float t = 0.5f * acc * (1.0f + erff(acc * 0.70710678118654752440f));
    partial = fmaf(t, w2[f], partial);
  }
  red[tid] = partial;
  __syncthreads();
  for (int s = 128; s > 0; s >>= 1) {
    if (tid < s) red[tid] += red[tid + s];
    __syncthreads();
  }
  if (tid == 0) y[g] = red[0] + b2[0];
}

// ---------------------------------------------------------------------------
extern "C" void kernel_launch(void* const* d_in, const int* in_sizes, int n_in,
                              void* d_out, int out_size, void* d_ws, size_t ws_size,
                              hipStream_t stream) {
  const int*   x     = (const int*)  d_in[0];
  const int*   ei    = (const int*)  d_in[1];
  const float* eattr = (const float*)d_in[2];
  const int*   batch = (const int*)  d_in[3];
  const float* pos   = (const float*)d_in[4];
  const float* vert  = (const float*)d_in[5];
  const float* posw  = (const float*)d_in[6];
  const float* edgew = (const float*)d_in[7];
  const float* fw1   = (const float*)d_in[8];
  const float* fb1   = (const float*)d_in[9];
  const float* fw2   = (const float*)d_in[10];
  const float* fb2   = (const float*)d_in[11];
  const float* l1w   = (const float*)d_in[12];
  const float* l2w   = (const float*)d_in[13];
  const float* l2b   = (const float*)d_in[14];
  const float* l3w   = (const float*)d_in[15];
  const float* l3b   = (const float*)d_in[16];
  const float* emw   = (const float*)d_in[17];
  const float* emb   = (const float*)d_in[18];
  const float* hw1   = (const float*)d_in[19];
  const float* hb1   = (const float*)d_in[20];
  const float* hw2   = (const float*)d_in[21];
  const float* hb2   = (const float*)d_in[22];
  float* out = (float*)d_out;

  char* ws = (char*)d_ws;
  size_t off = 0;
  auto alloc = [&](size_t bytes) { char* p = ws + off; off += (bytes + 511) & ~(size_t)511; return p; };
  float* ea   = (float*)alloc((size_t)N_EDGES*HC*4);
  float* h    = (float*)alloc((size_t)N_NODES*HC*4);
  float* agg  = (float*)alloc((size_t)N_NODES*NFC*4);
  int* deg    = (int*)alloc((size_t)(N_NODES+1)*4);
  int* cursor = (int*)alloc((size_t)(N_NODES+1)*4);
  int* bsum   = (int*)alloc((size_t)256*4);
  int* perm   = (int*)alloc((size_t)N_EDGES*4);
  const int n_fw1 = NLAYER*NFC*HC, n_fw2 = NLAYER*NFC*NFC, n_l1 = NLAYER*NFC*HC;
  const int n_l2 = NLAYER*HC*NFC, n_l3 = NLAYER*HC*HC, n_em = NLAYER*HC*2*HC;
  unsigned short* fw1h = (unsigned short*)alloc((size_t)n_fw1*2);
  unsigned short* fw2h = (unsigned short*)alloc((size_t)n_fw2*2);
  unsigned short* l1h  = (unsigned short*)alloc((size_t)n_l1*2);
  unsigned short* l2h  = (unsigned short*)alloc((size_t)n_l2*2);
  unsigned short* l3h  = (unsigned short*)alloc((size_t)n_l3*2);
  unsigned short* emh  = (unsigned short*)alloc((size_t)n_em*2);

  const int NSCAN = N_NODES + 1;                 // 50001
  const int NB    = (NSCAN + 255) / 256;         // 196

  zeroi_kernel<<<(NSCAN+255)/256, 256, 0, stream>>>(deg, NSCAN);
  hist_kernel<<<(N_EDGES+255)/256, 256, 0, stream>>>(ei, deg);
  scan1_kernel<<<NB, 256, 0, stream>>>(deg, cursor, bsum, NSCAN);
  scan2_kernel<<<1, 256, 0, stream>>>(bsum, NB);
  scan3_kernel<<<NB, 256, 0, stream>>>(cursor, bsum, NSCAN);
  perm_kernel<<<(N_EDGES+255)/256, 256, 0, stream>>>(ei, cursor, perm);

  wconv_kernel<<<(n_fw1+255)/256, 256, 0, stream>>>(fw1, fw1h, n_fw1);
  wconv_kernel<<<(n_fw2+255)/256, 256, 0, stream>>>(fw2, fw2h, n_fw2);
  wconv_kernel<<<(n_l1 +255)/256, 256, 0, stream>>>(l1w, l1h, n_l1);
  wconv_kernel<<<(n_l2 +255)/256, 256, 0, stream>>>(l2w, l2h, n_l2);
  wconv_kernel<<<(n_l3 +255)/256, 256, 0, stream>>>(l3w, l3h, n_l3);
  wconv_kernel<<<(n_em +255)/256, 256, 0, stream>>>(emw, emh, n_em);

  const int GN   = (N_NODES + 127) / 128;   // 391
  const int GE64 = N_EDGES / 64;            // 3125 (exact)

  embed_kernel<<<N_NODES, 128, 0, stream>>>(x, pos, vert, posw, h);
  edgeproj_kernel<<<(N_EDGES*HC + 255)/256, 256, 0, stream>>>(eattr, edgew, ea);
  zero_kernel<<<((N_NODES*NFC/4) + 255)/256, 256, 0, stream>>>(
      (float4*)agg, N_NODES*NFC/4);

  for (int i = 0; i < NLAYER; ++i) {
    ffs_kernel<<<GE64, 256, 0, stream>>>(
        ea, l1h + (size_t)i*NFC*HC,
        fw1h + (size_t)i*NFC*HC, fb1 + (size_t)i*NFC,
        fw2h + (size_t)i*NFC*NFC, fb2 + (size_t)i*NFC,
        ei, perm, h, agg);
    nodeup_kernel<<<GN, 256, 0, stream>>>(
        agg, l2h + (size_t)i*HC*NFC, l2b + (size_t)i*HC,
        l3h + (size_t)i*HC*HC, l3b + (size_t)i*HC, h);
    if (i < NLAYER - 1) {
      emlite_kernel<<<GE64, 256, 0, stream>>>(
          ea, emh + (size_t)i*HC*2*HC, emb + (size_t)i*HC,
          ei, h);
    }
  }

  poolhead_kernel<<<N_GRAPH, 256, 0, stream>>>(batch, h, hw1, hb1, hw2, hb2, out);
}

// Round 19
// 1849.254 us; speedup vs baseline: 1.3991x; 1.0661x over previous
//
#include <hip/hip_runtime.h>
#include <hip/hip_bf16.h>
#include <math.h>

#define N_NODES 50000
#define N_EDGES 200000
#define N_GRAPH 1024
#define HC      128
#define NFC     256
#define NLAYER  5
#define NFFC    512

typedef short bf16x8 __attribute__((ext_vector_type(8)));
typedef float f4v    __attribute__((ext_vector_type(4)));

__device__ __forceinline__ float ssp_f(float x) {
  float e = __expf(-fabsf(x));
  return fmaxf(x, 0.0f) + __logf(1.0f + e) - 0.69314718055994530942f;
}
__device__ __forceinline__ float tanh_f(float x) {
  float e = __expf(2.0f * fabsf(x));
  float t = 1.0f - 2.0f * __builtin_amdgcn_rcpf(e + 1.0f);
  return copysignf(t, x);
}
__device__ __forceinline__ unsigned short f2bf(float x) {
  union { float f; unsigned u; } v; v.f = x;
  unsigned r = v.u + 0x7fff + ((v.u >> 16) & 1);
  return (unsigned short)(r >> 16);
}
__device__ __forceinline__ float bf2f(unsigned short b) {
  union { unsigned u; float f; } v; v.u = (unsigned)b << 16; return v.f;
}

// ---------------------------------------------------------------------------
__global__ void zero_kernel(float4* __restrict__ p, int n4) {
  int i = blockIdx.x * blockDim.x + threadIdx.x;
  if (i < n4) p[i] = make_float4(0.f, 0.f, 0.f, 0.f);
}
__global__ void zeroi_kernel(int* __restrict__ p, int n) {
  int i = blockIdx.x * blockDim.x + threadIdx.x;
  if (i < n) p[i] = 0;
}

// ---- dst-sort infrastructure ----------------------------------------------
__global__ void hist_kernel(const int* __restrict__ ei, int* __restrict__ deg) {
  int e = blockIdx.x * blockDim.x + threadIdx.x;
  if (e < N_EDGES) atomicAdd(&deg[ei[N_EDGES + e]], 1);
}
__global__ void scan1_kernel(const int* __restrict__ deg, int* __restrict__ excl,
                             int* __restrict__ bsum, int n) {
  __shared__ int buf[256];
  const int tid = threadIdx.x;
  const int i = blockIdx.x * 256 + tid;
  int v = (i < n) ? deg[i] : 0;
  buf[tid] = v;
  __syncthreads();
  for (int s = 1; s < 256; s <<= 1) {
    int t = (tid >= s) ? buf[tid - s] : 0;
    __syncthreads();
    buf[tid] += t;
    __syncthreads();
  }
  if (i < n) excl[i] = buf[tid] - v;
  if (tid == 255) bsum[blockIdx.x] = buf[255];
}
__global__ void scan2_kernel(int* __restrict__ bsum, int nb) {
  __shared__ int buf[256];
  const int tid = threadIdx.x;
  int v = (tid < nb) ? bsum[tid] : 0;
  buf[tid] = v;
  __syncthreads();
  for (int s = 1; s < 256; s <<= 1) {
    int t = (tid >= s) ? buf[tid - s] : 0;
    __syncthreads();
    buf[tid] += t;
    __syncthreads();
  }
  if (tid < nb) bsum[tid] = buf[tid] - v;
}
__global__ void scan3_kernel(int* __restrict__ excl, const int* __restrict__ bsum, int n) {
  int i = blockIdx.x * 256 + threadIdx.x;
  if (i < n) excl[i] += bsum[blockIdx.x];
}
__global__ void perm_kernel(const int* __restrict__ ei, int* __restrict__ cursor,
                            int* __restrict__ perm) {
  int e = blockIdx.x * blockDim.x + threadIdx.x;
  if (e < N_EDGES) {
    int d = ei[N_EDGES + e];
    int p = atomicAdd(&cursor[d], 1);
    perm[p] = e;
  }
}

// convert fp32 weights -> plain bf16
__global__ void wconv_kernel(const float* __restrict__ w,
                             unsigned short* __restrict__ hi, int n) {
  int i = blockIdx.x * blockDim.x + threadIdx.x;
  if (i < n) hi[i] = f2bf(w[i]);
}

__global__ void embed_kernel(const int* __restrict__ x, const float* __restrict__ pos,
                             const float* __restrict__ vert, const float* __restrict__ posw,
                             float* __restrict__ h) {
  int n = blockIdx.x;
  int c = threadIdx.x;            // 128 threads
  float v;
  if (c < 80) {
    v = vert[(size_t)x[n] * 80 + c];
  } else {
    int j = c - 80;
    v = pos[n*3+0]*posw[j*3+0] + pos[n*3+1]*posw[j*3+1] + pos[n*3+2]*posw[j*3+2];
  }
  h[(size_t)n*HC + c] = v;
}

__global__ void edgeproj_kernel(const float* __restrict__ eattr, const float* __restrict__ ew,
                                float* __restrict__ ea) {
  int idx = blockIdx.x * blockDim.x + threadIdx.x;
  if (idx >= N_EDGES * HC) return;
  int e = idx >> 7, c = idx & 127;
  const float* a = eattr + (size_t)e*4;
  const float* w = ew + (size_t)c*4;
  ea[idx] = a[0]*w[0] + a[1]*w[1] + a[2]*w[2] + a[3]*w[3];
}

// ---------------------------------------------------------------------------
// Edge-MLP: 64-edge tile, 256 threads, ONE barrier. R19: plain bf16 A and B.
// LDS 34.8 KB -> 4 blocks/CU.
__global__ __launch_bounds__(256, 4) void emlite_kernel(
    float* ea,
    const unsigned short* __restrict__ Bh,
    const float* __restrict__ bias, const int* __restrict__ ei,
    const float* __restrict__ hfeat)
{
  __shared__ unsigned short ldsA[64][136];   // ea bf16
  __shared__ unsigned short ldsH[64][136];   // hsum bf16

  const int tid  = threadIdx.x;
  const int m0   = blockIdx.x * 64;          // N_EDGES % 64 == 0
  const int lane = tid & 63, wave = tid >> 6;
  const int quad = lane >> 4, l16 = lane & 15;
  const int r = tid >> 2, cb = (tid & 3) * 32;

  const int e = m0 + r;
  const int s = ei[e], d = ei[N_EDGES + e];

  float va[32], v1[32], v2[32];
  {
    const float* ap = ea + (size_t)e * HC + cb;
    const float* p1 = hfeat + (size_t)s * HC + cb;
    const float* p2 = hfeat + (size_t)d * HC + cb;
#pragma unroll
    for (int q = 0; q < 8; q++) *(float4*)&va[q*4] = *(const float4*)(ap + q*4);
#pragma unroll
    for (int q = 0; q < 8; q++) *(float4*)&v1[q*4] = *(const float4*)(p1 + q*4);
#pragma unroll
    for (int q = 0; q < 8; q++) *(float4*)&v2[q*4] = *(const float4*)(p2 + q*4);
  }
  {
    unsigned short th[32];
#pragma unroll
    for (int j = 0; j < 32; j++) th[j] = f2bf(va[j]);
#pragma unroll
    for (int q = 0; q < 4; q++)
      *(bf16x8*)&ldsA[r][cb + q*8] = *(bf16x8*)&th[q*8];
#pragma unroll
    for (int j = 0; j < 32; j++) th[j] = f2bf(v1[j] + v2[j]);
#pragma unroll
    for (int q = 0; q < 4; q++)
      *(bf16x8*)&ldsH[r][cb + q*8] = *(bf16x8*)&th[q*8];
  }

  const f4v zf = {0.f, 0.f, 0.f, 0.f};
  f4v acc[4][2];
#pragma unroll
  for (int mt = 0; mt < 4; mt++) { acc[mt][0] = zf; acc[mt][1] = zf; }

  __syncthreads();   // the only barrier

#pragma unroll
  for (int nt = 0; nt < 2; nt++) {
    const size_t brow = (size_t)(wave*32 + nt*16 + l16);
#pragma unroll
    for (int kk = 0; kk < 128; kk += 32) {
      bf16x8 b = *(const bf16x8*)&Bh[brow * 2*HC + kk + quad*8];
#pragma unroll
      for (int mt = 0; mt < 4; mt++) {
        bf16x8 a = *(const bf16x8*)&ldsA[mt*16 + l16][kk + quad*8];
        acc[mt][nt] = __builtin_amdgcn_mfma_f32_16x16x32_bf16(a, b, acc[mt][nt], 0, 0, 0);
      }
    }
#pragma unroll
    for (int kk = 0; kk < 128; kk += 32) {
      bf16x8 b = *(const bf16x8*)&Bh[brow * 2*HC + HC + kk + quad*8];
#pragma unroll
      for (int mt = 0; mt < 4; mt++) {
        bf16x8 a = *(const bf16x8*)&ldsH[mt*16 + l16][kk + quad*8];
        acc[mt][nt] = __builtin_amdgcn_mfma_f32_16x16x32_bf16(a, b, acc[mt][nt], 0, 0, 0);
      }
    }
  }

#pragma unroll
  for (int nt = 0; nt < 2; nt++) {
    const int col = wave*32 + nt*16 + l16;
    const float bz = bias[col];
#pragma unroll
    for (int mt = 0; mt < 4; mt++) {
      const int rowb = mt*16 + quad*4;
#pragma unroll
      for (int rr = 0; rr < 4; rr++) {
        const size_t idx = (size_t)(m0 + rowb + rr) * HC + col;
        ea[idx] = tanh_f(acc[mt][nt][rr] + bz) + ea[idx];
      }
    }
  }
}

// ---------------------------------------------------------------------------
// Fused node update (plain bf16 A and B) + agg self-zero. LDS 34.8 KB.
__global__ __launch_bounds__(256, 2) void nodeup_kernel(
    float* __restrict__ agg,
    const unsigned short* __restrict__ L2h,
    const float* __restrict__ b2,
    const unsigned short* __restrict__ L3h,
    const float* __restrict__ b3,
    float* h)
{
  __shared__ unsigned short lds[128 * 136];   // A-chunk stage (pitch 40) / T tile (pitch 136)

  const int tid  = threadIdx.x;
  const int m0   = blockIdx.x * 128;
  const int lane = tid & 63, wave = tid >> 6;
  const int quad = lane >> 4, l16 = lane & 15;
  const int wm = (wave >> 1) * 64, wn = (wave & 1) * 64;
  const int r  = tid >> 1;
  const int c0 = (tid & 1) * 16;

  const f4v zf = {0.f, 0.f, 0.f, 0.f};
  f4v acc[4][4];
#pragma unroll
  for (int i = 0; i < 4; i++)
#pragma unroll
    for (int j = 0; j < 4; j++) acc[i][j] = zf;

  const bool mok = (m0 + r) < N_NODES;
  const size_t arow = (size_t)(m0 + r);

  float av[16];
  if (mok) {
    const float* ap = agg + arow * NFC + c0;
#pragma unroll
    for (int q = 0; q < 4; q++) *(float4*)&av[q*4] = *(const float4*)(ap + q*4);
  } else {
#pragma unroll
    for (int j = 0; j < 16; j++) av[j] = 0.f;
  }

  for (int kk = 0; kk < NFC; kk += 32) {
    float avn[16];
    if (kk + 32 < NFC) {
      if (mok) {
        const float* ap = agg + arow * NFC + kk + 32 + c0;
#pragma unroll
        for (int q = 0; q < 4; q++) *(float4*)&avn[q*4] = *(const float4*)(ap + q*4);
      } else {
#pragma unroll
        for (int j = 0; j < 16; j++) avn[j] = 0.f;
      }
    }
    bf16x8 b[4];
#pragma unroll
    for (int nt = 0; nt < 4; nt++) {
      const size_t brow = (size_t)(wn + nt*16 + l16);
      b[nt] = *(const bf16x8*)&L2h[brow * NFC + kk + quad*8];
    }
    __syncthreads();
    unsigned short th[16];
#pragma unroll
    for (int j = 0; j < 16; j++) th[j] = f2bf(av[j]);
    *(bf16x8*)&lds[r*40 + c0]     = *(bf16x8*)&th[0];
    *(bf16x8*)&lds[r*40 + c0 + 8] = *(bf16x8*)&th[8];
    __syncthreads();
    bf16x8 a[4];
#pragma unroll
    for (int t = 0; t < 4; t++)
      a[t] = *(const bf16x8*)&lds[(wm + t*16 + l16) * 40 + quad * 8];
#pragma unroll
    for (int mt = 0; mt < 4; mt++)
#pragma unroll
      for (int nt = 0; nt < 4; nt++)
        acc[mt][nt] = __builtin_amdgcn_mfma_f32_16x16x32_bf16(a[mt], b[nt], acc[mt][nt], 0, 0, 0);
    if (kk + 32 < NFC) {
#pragma unroll
      for (int j = 0; j < 16; j++) av[j] = avn[j];
    }
  }
  __syncthreads();   // agg reads complete

  if (mok) {
    float4* zp = (float4*)(agg + arow * NFC + (tid & 1) * 128);
    const float4 z4 = make_float4(0.f, 0.f, 0.f, 0.f);
#pragma unroll
    for (int q = 0; q < 32; q++) zp[q] = z4;
  }

#pragma unroll
  for (int nt = 0; nt < 4; nt++) {
    const int col = wn + nt*16 + l16;
    const float bz = b2[col];
#pragma unroll
    for (int mt = 0; mt < 4; mt++) {
      const int rowb = wm + mt*16 + quad*4;
#pragma unroll
      for (int rr = 0; rr < 4; rr++)
        lds[(rowb+rr)*136 + col] = f2bf(ssp_f(acc[mt][nt][rr] + bz));
    }
  }
  __syncthreads();

  f4v acc2[4][4];
#pragma unroll
  for (int i = 0; i < 4; i++)
#pragma unroll
    for (int j = 0; j < 4; j++) acc2[i][j] = zf;

  for (int kk = 0; kk < HC; kk += 32) {
    bf16x8 b[4];
#pragma unroll
    for (int nt = 0; nt < 4; nt++) {
      const size_t brow = (size_t)(wn + nt*16 + l16);
      b[nt] = *(const bf16x8*)&L3h[brow * HC + kk + quad*8];
    }
    bf16x8 a[4];
#pragma unroll
    for (int t = 0; t < 4; t++)
      a[t] = *(const bf16x8*)&lds[(wm + t*16 + l16) * 136 + kk + quad * 8];
#pragma unroll
    for (int mt = 0; mt < 4; mt++)
#pragma unroll
      for (int nt = 0; nt < 4; nt++)
        acc2[mt][nt] = __builtin_amdgcn_mfma_f32_16x16x32_bf16(a[mt], b[nt], acc2[mt][nt], 0, 0, 0);
  }

#pragma unroll
  for (int nt = 0; nt < 4; nt++) {
    const int ncol = wn + nt*16 + l16;
    const float bz = b3[ncol];
#pragma unroll
    for (int mt = 0; mt < 4; mt++) {
      const int mb = wm + mt*16 + quad*4;
#pragma unroll
      for (int rr = 0; rr < 4; rr++) {
        const int m = m0 + mb + rr;
        if (m < N_NODES) {
          const size_t idx = (size_t)m * HC + ncol;
          h[idx] = fmaxf(acc2[mt][nt][rr] + bz, 0.f) + h[idx];
        }
      }
    }
  }
}

// ---------------------------------------------------------------------------
// Fused lin1 + filter MLP + run-reduced scatter. R19: plain bf16 A and B.
// LDS ~27 KB; MFMAs halved vs R18.
__device__ __forceinline__ int sigma_row(int r) {
  return ((r >> 2) & 3) * 16 + (r >> 4) * 4 + (r & 3);
}
__global__ __launch_bounds__(256, 3) void ffs_kernel(
    const float* __restrict__ ea,
    const unsigned short* __restrict__ l1h,
    const unsigned short* __restrict__ fw1h,
    const float* __restrict__ fb1,
    const unsigned short* __restrict__ fw2h,
    const float* __restrict__ fb2, const int* __restrict__ ei,
    const int* __restrict__ perm,
    const float* __restrict__ hfeat, float* agg)
{
  __shared__ unsigned short ldsA[64][136];   // ea bf16   17408 B
  __shared__ unsigned short ldsT[64][72];    // T / h-stage  9216 B
  __shared__ int sS[64], sD[64];

  const int tid  = threadIdx.x;
  const int m0   = blockIdx.x * 64;
  const int lane = tid & 63, wave = tid >> 6;
  const int quad = lane >> 4, l16 = lane & 15;

  {
    const int r = tid >> 2, cb = (tid & 3) * 32;
    const int pe = perm[m0 + sigma_row(r)];
    const float* ap = ea + (size_t)pe * HC + cb;
    float v[32];
#pragma unroll
    for (int q = 0; q < 8; q++) *(float4*)&v[q*4] = *(const float4*)(ap + q*4);
    unsigned short th[32];
#pragma unroll
    for (int j = 0; j < 32; j++) th[j] = f2bf(v[j]);
#pragma unroll
    for (int q = 0; q < 4; q++)
      *(bf16x8*)&ldsA[r][cb + q*8] = *(bf16x8*)&th[q*8];
  }
  if (tid < 64) {
    int pe = perm[m0 + sigma_row(tid)];
    sS[tid] = ei[pe];
    sD[tid] = ei[N_EDGES + pe];
  }

  const f4v zf = {0.f, 0.f, 0.f, 0.f};
  __syncthreads();

  f4v hacc[4][4];
#pragma unroll
  for (int mt = 0; mt < 4; mt++)
#pragma unroll
    for (int nt = 0; nt < 4; nt++) hacc[mt][nt] = zf;

  unsigned short* ldsF = &ldsT[0][0];   // h stage, pitch 40 (plain)
  for (int kk = 0; kk < 128; kk += 32) {
    {
      const int r = tid >> 2, c8 = (tid & 3) * 8;
      const float* hp_ = hfeat + (size_t)sS[r] * HC + kk + c8;
      float4 v0 = *(const float4*)hp_;
      float4 v1 = *(const float4*)(hp_ + 4);
      float vv[8] = {v0.x, v0.y, v0.z, v0.w, v1.x, v1.y, v1.z, v1.w};
      unsigned short th[8];
#pragma unroll
      for (int e = 0; e < 8; e++) th[e] = f2bf(vv[e]);
      *(bf16x8*)&ldsF[r*40 + c8] = *(bf16x8*)&th[0];
    }
    __syncthreads();
#pragma unroll
    for (int nt = 0; nt < 4; nt++) {
      const size_t brow = (size_t)(wave*64 + nt*16 + l16);
      bf16x8 b = *(const bf16x8*)&l1h[brow * HC + kk + quad*8];
#pragma unroll
      for (int mt = 0; mt < 4; mt++) {
        bf16x8 a = *(const bf16x8*)&ldsF[(mt*16 + l16)*40 + quad*8];
        hacc[mt][nt] = __builtin_amdgcn_mfma_f32_16x16x32_bf16(a, b, hacc[mt][nt], 0, 0, 0);
      }
    }
    __syncthreads();
  }

  f4v wacc[4][4];
#pragma unroll
  for (int mt = 0; mt < 4; mt++)
#pragma unroll
    for (int nt = 0; nt < 4; nt++) wacc[mt][nt] = zf;

  for (int p = 0; p < 4; p++) {
    f4v tacc[4];
#pragma unroll
    for (int mt = 0; mt < 4; mt++) tacc[mt] = zf;
    const size_t b1row = (size_t)(p*64 + wave*16 + l16);
#pragma unroll
    for (int kk = 0; kk < 128; kk += 32) {
      bf16x8 b = *(const bf16x8*)&fw1h[b1row * HC + kk + quad*8];
#pragma unroll
      for (int mt = 0; mt < 4; mt++) {
        bf16x8 a = *(const bf16x8*)&ldsA[mt*16 + l16][kk + quad*8];
        tacc[mt] = __builtin_amdgcn_mfma_f32_16x16x32_bf16(a, b, tacc[mt], 0, 0, 0);
      }
    }
    {
      const int col = wave*16 + l16;
      const float bz = fb1[p*64 + col];
#pragma unroll
      for (int mt = 0; mt < 4; mt++) {
        const int rowb = mt*16 + quad*4;
#pragma unroll
        for (int rr = 0; rr < 4; rr++)
          ldsT[rowb+rr][col] = f2bf(ssp_f(tacc[mt][rr] + bz));
      }
    }
    __syncthreads();

#pragma unroll
    for (int kc = 0; kc < 2; kc++) {
      bf16x8 a_[4];
#pragma unroll
      for (int mt = 0; mt < 4; mt++)
        a_[mt] = *(const bf16x8*)&ldsT[mt*16 + l16][kc*32 + quad*8];
#pragma unroll
      for (int nt = 0; nt < 4; nt++) {
        const size_t brow = (size_t)(wave*64 + nt*16 + l16);
        bf16x8 b = *(const bf16x8*)&fw2h[brow * NFC + p*64 + kc*32 + quad*8];
#pragma unroll
        for (int mt = 0; mt < 4; mt++)
          wacc[mt][nt] = __builtin_amdgcn_mfma_f32_16x16x32_bf16(a_[mt], b, wacc[mt][nt], 0, 0, 0);
      }
    }
    __syncthreads();
  }

#pragma unroll
  for (int nt = 0; nt < 4; nt++) {
    const int col = wave*64 + nt*16 + l16;
    const float bz = fb2[col];
    float accum = 0.f;
    int prev = -1;
#pragma unroll
    for (int mt = 0; mt < 4; mt++) {
#pragma unroll
      for (int rr = 0; rr < 4; rr++) {
        const int prow = mt*16 + quad*4 + rr;
        const int d = sD[prow];
        const float v = (wacc[mt][nt][rr] + bz) * hacc[mt][nt][rr];
        if (d != prev) {
          if (prev >= 0) atomicAdd(&agg[(size_t)prev * NFC + col], accum);
          accum = v; prev = d;
        } else {
          accum += v;
        }
      }
    }
    atomicAdd(&agg[(size_t)prev * NFC + col], accum);
  }
}

// ---------------------------------------------------------------------------
// Fused pool + head (batch sorted; per-graph binary search).
__global__ __launch_bounds__(256) void poolhead_kernel(
    const int* __restrict__ batch, const float* __restrict__ h,
    const float* __restrict__ w1, const float* __restrict__ b1,
    const float* __restrict__ w2, const float* __restrict__ b2,
    float* __restrict__ y)
{
  __shared__ float gs[HC];
  __shared__ float red[256];
  const int g = blockIdx.x;
  const int tid = threadIdx.x;

  int lo = 0, hi = N_NODES;
  while (lo < hi) { int m = (lo + hi) >> 1; if (batch[m] < g) lo = m + 1; else hi = m; }
  int lo2 = lo, hi2 = N_NODES;
  while (lo2 < hi2) { int m = (lo2 + hi2) >> 1; if (batch[m] < g + 1) lo2 = m + 1; else hi2 = m; }
  const int cnt = lo2 - lo;

  if (tid < HC) {
    float s = 0.f;
    for (int i = lo; i < lo2; i++) s += h[(size_t)i * HC + tid];
    gs[tid] = s / (float)max(cnt, 1);
  }
  __syncthreads();

  float partial = 0.f;
  for (int f = tid; f < NFFC; f += 256) {
    float acc = b1[f];
    const float* wr = w1 + (size_t)f * HC;
#pragma unroll 8
    for (int k = 0; k < HC; k++) acc = fmaf(gs[k], wr[k], acc);
    float t = 0.5f * acc * (1.0f + erff(acc * 0.70710678118654752440f));
    partial = fmaf(t, w2[f], partial);
  }
  red[tid] = partial;
  __syncthreads();
  for (int s = 128; s > 0; s >>= 1) {
    if (tid < s) red[tid] += red[tid + s];
    __syncthreads();
  }
  if (tid == 0) y[g] = red[0] + b2[0];
}

// ---------------------------------------------------------------------------
extern "C" void kernel_launch(void* const* d_in, const int* in_sizes, int n_in,
                              void* d_out, int out_size, void* d_ws, size_t ws_size,
                              hipStream_t stream) {
  const int*   x     = (const int*)  d_in[0];
  const int*   ei    = (const int*)  d_in[1];
  const float* eattr = (const float*)d_in[2];
  const int*   batch = (const int*)  d_in[3];
  const float* pos   = (const float*)d_in[4];
  const float* vert  = (const float*)d_in[5];
  const float* posw  = (const float*)d_in[6];
  const float* edgew = (const float*)d_in[7];
  const float* fw1   = (const float*)d_in[8];
  const float* fb1   = (const float*)d_in[9];
  const float* fw2   = (const float*)d_in[10];
  const float* fb2   = (const float*)d_in[11];
  const float* l1w   = (const float*)d_in[12];
  const float* l2w   = (const float*)d_in[13];
  const float* l2b   = (const float*)d_in[14];
  const float* l3w   = (const float*)d_in[15];
  const float* l3b   = (const float*)d_in[16];
  const float* emw   = (const float*)d_in[17];
  const float* emb   = (const float*)d_in[18];
  const float* hw1   = (const float*)d_in[19];
  const float* hb1   = (const float*)d_in[20];
  const float* hw2   = (const float*)d_in[21];
  const float* hb2   = (const float*)d_in[22];
  float* out = (float*)d_out;

  char* ws = (char*)d_ws;
  size_t off = 0;
  auto alloc = [&](size_t bytes) { char* p = ws + off; off += (bytes + 511) & ~(size_t)511; return p; };
  float* ea   = (float*)alloc((size_t)N_EDGES*HC*4);
  float* h    = (float*)alloc((size_t)N_NODES*HC*4);
  float* agg  = (float*)alloc((size_t)N_NODES*NFC*4);
  int* deg    = (int*)alloc((size_t)(N_NODES+1)*4);
  int* cursor = (int*)alloc((size_t)(N_NODES+1)*4);
  int* bsum   = (int*)alloc((size_t)256*4);
  int* perm   = (int*)alloc((size_t)N_EDGES*4);
  const int n_fw1 = NLAYER*NFC*HC, n_fw2 = NLAYER*NFC*NFC, n_l1 = NLAYER*NFC*HC;
  const int n_l2 = NLAYER*HC*NFC, n_l3 = NLAYER*HC*HC, n_em = NLAYER*HC*2*HC;
  unsigned short* fw1h = (unsigned short*)alloc((size_t)n_fw1*2);
  unsigned short* fw2h = (unsigned short*)alloc((size_t)n_fw2*2);
  unsigned short* l1h  = (unsigned short*)alloc((size_t)n_l1*2);
  unsigned short* l2h  = (unsigned short*)alloc((size_t)n_l2*2);
  unsigned short* l3h  = (unsigned short*)alloc((size_t)n_l3*2);
  unsigned short* emh  = (unsigned short*)alloc((size_t)n_em*2);

  const int NSCAN = N_NODES + 1;                 // 50001
  const int NB    = (NSCAN + 255) / 256;         // 196

  zeroi_kernel<<<(NSCAN+255)/256, 256, 0, stream>>>(deg, NSCAN);
  hist_kernel<<<(N_EDGES+255)/256, 256, 0, stream>>>(ei, deg);
  scan1_kernel<<<NB, 256, 0, stream>>>(deg, cursor, bsum, NSCAN);
  scan2_kernel<<<1, 256, 0, stream>>>(bsum, NB);
  scan3_kernel<<<NB, 256, 0, stream>>>(cursor, bsum, NSCAN);
  perm_kernel<<<(N_EDGES+255)/256, 256, 0, stream>>>(ei, cursor, perm);

  wconv_kernel<<<(n_fw1+255)/256, 256, 0, stream>>>(fw1, fw1h, n_fw1);
  wconv_kernel<<<(n_fw2+255)/256, 256, 0, stream>>>(fw2, fw2h, n_fw2);
  wconv_kernel<<<(n_l1 +255)/256, 256, 0, stream>>>(l1w, l1h, n_l1);
  wconv_kernel<<<(n_l2 +255)/256, 256, 0, stream>>>(l2w, l2h, n_l2);
  wconv_kernel<<<(n_l3 +255)/256, 256, 0, stream>>>(l3w, l3h, n_l3);
  wconv_kernel<<<(n_em +255)/256, 256, 0, stream>>>(emw, emh, n_em);

  const int GN   = (N_NODES + 127) / 128;   // 391
  const int GE64 = N_EDGES / 64;            // 3125 (exact)

  embed_kernel<<<N_NODES, 128, 0, stream>>>(x, pos, vert, posw, h);
  edgeproj_kernel<<<(N_EDGES*HC + 255)/256, 256, 0, stream>>>(eattr, edgew, ea);
  zero_kernel<<<((N_NODES*NFC/4) + 255)/256, 256, 0, stream>>>(
      (float4*)agg, N_NODES*NFC/4);

  for (int i = 0; i < NLAYER; ++i) {
    ffs_kernel<<<GE64, 256, 0, stream>>>(
        ea, l1h + (size_t)i*NFC*HC,
        fw1h + (size_t)i*NFC*HC, fb1 + (size_t)i*NFC,
        fw2h + (size_t)i*NFC*NFC, fb2 + (size_t)i*NFC,
        ei, perm, h, agg);
    nodeup_kernel<<<GN, 256, 0, stream>>>(
        agg, l2h + (size_t)i*HC*NFC, l2b + (size_t)i*HC,
        l3h + (size_t)i*HC*HC, l3b + (size_t)i*HC, h);
    if (i < NLAYER - 1) {
      emlite_kernel<<<GE64, 256, 0, stream>>>(
          ea, emh + (size_t)i*HC*2*HC, emb + (size_t)i*HC,
          ei, h);
    }
  }

  poolhead_kernel<<<N_GRAPH, 256, 0, stream>>>(batch, h, hw1, hb1, hw2, hb2, out);
}

// Round 20
// 1607.663 us; speedup vs baseline: 1.6094x; 1.1503x over previous
//
#include <hip/hip_runtime.h>
#include <hip/hip_bf16.h>
#include <math.h>

#define N_NODES 50000
#define N_EDGES 200000
#define N_GRAPH 1024
#define HC      128
#define NFC     256
#define NLAYER  5
#define NFFC    512

typedef short bf16x8 __attribute__((ext_vector_type(8)));
typedef float f4v    __attribute__((ext_vector_type(4)));

__device__ __forceinline__ float ssp_f(float x) {
  float e = __expf(-fabsf(x));
  return fmaxf(x, 0.0f) + __logf(1.0f + e) - 0.69314718055994530942f;
}
__device__ __forceinline__ float tanh_f(float x) {
  float e = __expf(2.0f * fabsf(x));
  float t = 1.0f - 2.0f * __builtin_amdgcn_rcpf(e + 1.0f);
  return copysignf(t, x);
}
__device__ __forceinline__ unsigned short f2bf(float x) {
  union { float f; unsigned u; } v; v.f = x;
  unsigned r = v.u + 0x7fff + ((v.u >> 16) & 1);
  return (unsigned short)(r >> 16);
}
__device__ __forceinline__ float bf2f(unsigned short b) {
  union { unsigned u; float f; } v; v.u = (unsigned)b << 16; return v.f;
}

// ---------------------------------------------------------------------------
__global__ void zero_kernel(float4* __restrict__ p, int n4) {
  int i = blockIdx.x * blockDim.x + threadIdx.x;
  if (i < n4) p[i] = make_float4(0.f, 0.f, 0.f, 0.f);
}
__global__ void zeroi_kernel(int* __restrict__ p, int n) {
  int i = blockIdx.x * blockDim.x + threadIdx.x;
  if (i < n) p[i] = 0;
}

// ---- dst-sort infrastructure ----------------------------------------------
__global__ void hist_kernel(const int* __restrict__ ei, int* __restrict__ deg) {
  int e = blockIdx.x * blockDim.x + threadIdx.x;
  if (e < N_EDGES) atomicAdd(&deg[ei[N_EDGES + e]], 1);
}
__global__ void scan1_kernel(const int* __restrict__ deg, int* __restrict__ excl,
                             int* __restrict__ bsum, int n) {
  __shared__ int buf[256];
  const int tid = threadIdx.x;
  const int i = blockIdx.x * 256 + tid;
  int v = (i < n) ? deg[i] : 0;
  buf[tid] = v;
  __syncthreads();
  for (int s = 1; s < 256; s <<= 1) {
    int t = (tid >= s) ? buf[tid - s] : 0;
    __syncthreads();
    buf[tid] += t;
    __syncthreads();
  }
  if (i < n) excl[i] = buf[tid] - v;
  if (tid == 255) bsum[blockIdx.x] = buf[255];
}
__global__ void scan2_kernel(int* __restrict__ bsum, int nb) {
  __shared__ int buf[256];
  const int tid = threadIdx.x;
  int v = (tid < nb) ? bsum[tid] : 0;
  buf[tid] = v;
  __syncthreads();
  for (int s = 1; s < 256; s <<= 1) {
    int t = (tid >= s) ? buf[tid - s] : 0;
    __syncthreads();
    buf[tid] += t;
    __syncthreads();
  }
  if (tid < nb) bsum[tid] = buf[tid] - v;
}
__global__ void scan3_kernel(int* __restrict__ excl, const int* __restrict__ bsum, int n) {
  int i = blockIdx.x * 256 + threadIdx.x;
  if (i < n) excl[i] += bsum[blockIdx.x];
}
__global__ void perm_kernel(const int* __restrict__ ei, int* __restrict__ cursor,
                            int* __restrict__ perm) {
  int e = blockIdx.x * blockDim.x + threadIdx.x;
  if (e < N_EDGES) {
    int d = ei[N_EDGES + e];
    int p = atomicAdd(&cursor[d], 1);
    perm[p] = e;
  }
}

// convert fp32 weights -> plain bf16
__global__ void wconv_kernel(const float* __restrict__ w,
                             unsigned short* __restrict__ hi, int n) {
  int i = blockIdx.x * blockDim.x + threadIdx.x;
  if (i < n) hi[i] = f2bf(w[i]);
}

// h (bf16) init
__global__ void embed_kernel(const int* __restrict__ x, const float* __restrict__ pos,
                             const float* __restrict__ vert, const float* __restrict__ posw,
                             unsigned short* __restrict__ h) {
  int n = blockIdx.x;
  int c = threadIdx.x;            // 128 threads
  float v;
  if (c < 80) {
    v = vert[(size_t)x[n] * 80 + c];
  } else {
    int j = c - 80;
    v = pos[n*3+0]*posw[j*3+0] + pos[n*3+1]*posw[j*3+1] + pos[n*3+2]*posw[j*3+2];
  }
  h[(size_t)n*HC + c] = f2bf(v);
}

// ea (bf16) init
__global__ void edgeproj_kernel(const float* __restrict__ eattr, const float* __restrict__ ew,
                                unsigned short* __restrict__ ea) {
  int idx = blockIdx.x * blockDim.x + threadIdx.x;
  if (idx >= N_EDGES * HC) return;
  int e = idx >> 7, c = idx & 127;
  const float* a = eattr + (size_t)e*4;
  const float* w = ew + (size_t)c*4;
  ea[idx] = f2bf(a[0]*w[0] + a[1]*w[1] + a[2]*w[2] + a[3]*w[3]);
}

// ---------------------------------------------------------------------------
// Edge-MLP: 64-edge tile, 256 threads, ONE barrier. bf16 activations in memory.
__global__ __launch_bounds__(256, 4) void emlite_kernel(
    unsigned short* ea,
    const unsigned short* __restrict__ Bh,
    const float* __restrict__ bias, const int* __restrict__ ei,
    const unsigned short* __restrict__ hfeat)
{
  __shared__ unsigned short ldsA[64][136];   // ea bf16
  __shared__ unsigned short ldsH[64][136];   // hsum bf16

  const int tid  = threadIdx.x;
  const int m0   = blockIdx.x * 64;          // N_EDGES % 64 == 0
  const int lane = tid & 63, wave = tid >> 6;
  const int quad = lane >> 4, l16 = lane & 15;
  const int r = tid >> 2, cb = (tid & 3) * 32;

  const int e = m0 + r;
  const int s = ei[e], d = ei[N_EDGES + e];

  // ea: pure bf16 copy; hsum: bf16+bf16 -> fp32 add -> bf16
  {
    const unsigned short* ap = ea + (size_t)e * HC + cb;
#pragma unroll
    for (int q = 0; q < 4; q++)
      *(bf16x8*)&ldsA[r][cb + q*8] = *(const bf16x8*)(ap + q*8);
    const unsigned short* p1 = hfeat + (size_t)s * HC + cb;
    const unsigned short* p2 = hfeat + (size_t)d * HC + cb;
    unsigned short x1[32], x2[32], th[32];
#pragma unroll
    for (int q = 0; q < 4; q++) {
      *(bf16x8*)&x1[q*8] = *(const bf16x8*)(p1 + q*8);
      *(bf16x8*)&x2[q*8] = *(const bf16x8*)(p2 + q*8);
    }
#pragma unroll
    for (int j = 0; j < 32; j++) th[j] = f2bf(bf2f(x1[j]) + bf2f(x2[j]));
#pragma unroll
    for (int q = 0; q < 4; q++)
      *(bf16x8*)&ldsH[r][cb + q*8] = *(bf16x8*)&th[q*8];
  }

  const f4v zf = {0.f, 0.f, 0.f, 0.f};
  f4v acc[4][2];
#pragma unroll
  for (int mt = 0; mt < 4; mt++) { acc[mt][0] = zf; acc[mt][1] = zf; }

  __syncthreads();   // the only barrier

#pragma unroll
  for (int nt = 0; nt < 2; nt++) {
    const size_t brow = (size_t)(wave*32 + nt*16 + l16);
#pragma unroll
    for (int kk = 0; kk < 128; kk += 32) {
      bf16x8 b = *(const bf16x8*)&Bh[brow * 2*HC + kk + quad*8];
#pragma unroll
      for (int mt = 0; mt < 4; mt++) {
        bf16x8 a = *(const bf16x8*)&ldsA[mt*16 + l16][kk + quad*8];
        acc[mt][nt] = __builtin_amdgcn_mfma_f32_16x16x32_bf16(a, b, acc[mt][nt], 0, 0, 0);
      }
    }
#pragma unroll
    for (int kk = 0; kk < 128; kk += 32) {
      bf16x8 b = *(const bf16x8*)&Bh[brow * 2*HC + HC + kk + quad*8];
#pragma unroll
      for (int mt = 0; mt < 4; mt++) {
        bf16x8 a = *(const bf16x8*)&ldsH[mt*16 + l16][kk + quad*8];
        acc[mt][nt] = __builtin_amdgcn_mfma_f32_16x16x32_bf16(a, b, acc[mt][nt], 0, 0, 0);
      }
    }
  }

#pragma unroll
  for (int nt = 0; nt < 2; nt++) {
    const int col = wave*32 + nt*16 + l16;
    const float bz = bias[col];
#pragma unroll
    for (int mt = 0; mt < 4; mt++) {
      const int rowb = mt*16 + quad*4;
#pragma unroll
      for (int rr = 0; rr < 4; rr++) {
        const size_t idx = (size_t)(m0 + rowb + rr) * HC + col;
        ea[idx] = f2bf(tanh_f(acc[mt][nt][rr] + bz) + bf2f(ea[idx]));
      }
    }
  }
}

// ---------------------------------------------------------------------------
// Fused node update (bf16 h in memory; agg fp32) + agg self-zero.
__global__ __launch_bounds__(256, 2) void nodeup_kernel(
    float* __restrict__ agg,
    const unsigned short* __restrict__ L2h,
    const float* __restrict__ b2,
    const unsigned short* __restrict__ L3h,
    const float* __restrict__ b3,
    unsigned short* h)
{
  __shared__ unsigned short lds[128 * 136];

  const int tid  = threadIdx.x;
  const int m0   = blockIdx.x * 128;
  const int lane = tid & 63, wave = tid >> 6;
  const int quad = lane >> 4, l16 = lane & 15;
  const int wm = (wave >> 1) * 64, wn = (wave & 1) * 64;
  const int r  = tid >> 1;
  const int c0 = (tid & 1) * 16;

  const f4v zf = {0.f, 0.f, 0.f, 0.f};
  f4v acc[4][4];
#pragma unroll
  for (int i = 0; i < 4; i++)
#pragma unroll
    for (int j = 0; j < 4; j++) acc[i][j] = zf;

  const bool mok = (m0 + r) < N_NODES;
  const size_t arow = (size_t)(m0 + r);

  float av[16];
  if (mok) {
    const float* ap = agg + arow * NFC + c0;
#pragma unroll
    for (int q = 0; q < 4; q++) *(float4*)&av[q*4] = *(const float4*)(ap + q*4);
  } else {
#pragma unroll
    for (int j = 0; j < 16; j++) av[j] = 0.f;
  }

  for (int kk = 0; kk < NFC; kk += 32) {
    float avn[16];
    if (kk + 32 < NFC) {
      if (mok) {
        const float* ap = agg + arow * NFC + kk + 32 + c0;
#pragma unroll
        for (int q = 0; q < 4; q++) *(float4*)&avn[q*4] = *(const float4*)(ap + q*4);
      } else {
#pragma unroll
        for (int j = 0; j < 16; j++) avn[j] = 0.f;
      }
    }
    bf16x8 b[4];
#pragma unroll
    for (int nt = 0; nt < 4; nt++) {
      const size_t brow = (size_t)(wn + nt*16 + l16);
      b[nt] = *(const bf16x8*)&L2h[brow * NFC + kk + quad*8];
    }
    __syncthreads();
    unsigned short th[16];
#pragma unroll
    for (int j = 0; j < 16; j++) th[j] = f2bf(av[j]);
    *(bf16x8*)&lds[r*40 + c0]     = *(bf16x8*)&th[0];
    *(bf16x8*)&lds[r*40 + c0 + 8] = *(bf16x8*)&th[8];
    __syncthreads();
    bf16x8 a[4];
#pragma unroll
    for (int t = 0; t < 4; t++)
      a[t] = *(const bf16x8*)&lds[(wm + t*16 + l16) * 40 + quad * 8];
#pragma unroll
    for (int mt = 0; mt < 4; mt++)
#pragma unroll
      for (int nt = 0; nt < 4; nt++)
        acc[mt][nt] = __builtin_amdgcn_mfma_f32_16x16x32_bf16(a[mt], b[nt], acc[mt][nt], 0, 0, 0);
    if (kk + 32 < NFC) {
#pragma unroll
      for (int j = 0; j < 16; j++) av[j] = avn[j];
    }
  }
  __syncthreads();   // agg reads complete

  if (mok) {
    float4* zp = (float4*)(agg + arow * NFC + (tid & 1) * 128);
    const float4 z4 = make_float4(0.f, 0.f, 0.f, 0.f);
#pragma unroll
    for (int q = 0; q < 32; q++) zp[q] = z4;
  }

#pragma unroll
  for (int nt = 0; nt < 4; nt++) {
    const int col = wn + nt*16 + l16;
    const float bz = b2[col];
#pragma unroll
    for (int mt = 0; mt < 4; mt++) {
      const int rowb = wm + mt*16 + quad*4;
#pragma unroll
      for (int rr = 0; rr < 4; rr++)
        lds[(rowb+rr)*136 + col] = f2bf(ssp_f(acc[mt][nt][rr] + bz));
    }
  }
  __syncthreads();

  f4v acc2[4][4];
#pragma unroll
  for (int i = 0; i < 4; i++)
#pragma unroll
    for (int j = 0; j < 4; j++) acc2[i][j] = zf;

  for (int kk = 0; kk < HC; kk += 32) {
    bf16x8 b[4];
#pragma unroll
    for (int nt = 0; nt < 4; nt++) {
      const size_t brow = (size_t)(wn + nt*16 + l16);
      b[nt] = *(const bf16x8*)&L3h[brow * HC + kk + quad*8];
    }
    bf16x8 a[4];
#pragma unroll
    for (int t = 0; t < 4; t++)
      a[t] = *(const bf16x8*)&lds[(wm + t*16 + l16) * 136 + kk + quad * 8];
#pragma unroll
    for (int mt = 0; mt < 4; mt++)
#pragma unroll
      for (int nt = 0; nt < 4; nt++)
        acc2[mt][nt] = __builtin_amdgcn_mfma_f32_16x16x32_bf16(a[mt], b[nt], acc2[mt][nt], 0, 0, 0);
  }

#pragma unroll
  for (int nt = 0; nt < 4; nt++) {
    const int ncol = wn + nt*16 + l16;
    const float bz = b3[ncol];
#pragma unroll
    for (int mt = 0; mt < 4; mt++) {
      const int mb = wm + mt*16 + quad*4;
#pragma unroll
      for (int rr = 0; rr < 4; rr++) {
        const int m = m0 + mb + rr;
        if (m < N_NODES) {
          const size_t idx = (size_t)m * HC + ncol;
          h[idx] = f2bf(fmaxf(acc2[mt][nt][rr] + bz, 0.f) + bf2f(h[idx]));
        }
      }
    }
  }
}

// ---------------------------------------------------------------------------
// Fused lin1 + filter MLP + run-reduced scatter. bf16 activations in memory:
// ea staging and h-gather are PURE 16B copies (zero conversion VALU).
__device__ __forceinline__ int sigma_row(int r) {
  return ((r >> 2) & 3) * 16 + (r >> 4) * 4 + (r & 3);
}
__global__ __launch_bounds__(256, 3) void ffs_kernel(
    const unsigned short* __restrict__ ea,
    const unsigned short* __restrict__ l1h,
    const unsigned short* __restrict__ fw1h,
    const float* __restrict__ fb1,
    const unsigned short* __restrict__ fw2h,
    const float* __restrict__ fb2, const int* __restrict__ ei,
    const int* __restrict__ perm,
    const unsigned short* __restrict__ hfeat, float* agg)
{
  __shared__ unsigned short ldsA[64][136];   // ea bf16
  __shared__ unsigned short ldsT[64][72];    // T / h-stage
  __shared__ int sS[64], sD[64];

  const int tid  = threadIdx.x;
  const int m0   = blockIdx.x * 64;
  const int lane = tid & 63, wave = tid >> 6;
  const int quad = lane >> 4, l16 = lane & 15;

  {
    const int r = tid >> 2, cb = (tid & 3) * 32;
    const int pe = perm[m0 + sigma_row(r)];
    const unsigned short* ap = ea + (size_t)pe * HC + cb;
#pragma unroll
    for (int q = 0; q < 4; q++)
      *(bf16x8*)&ldsA[r][cb + q*8] = *(const bf16x8*)(ap + q*8);
  }
  if (tid < 64) {
    int pe = perm[m0 + sigma_row(tid)];
    sS[tid] = ei[pe];
    sD[tid] = ei[N_EDGES + pe];
  }

  const f4v zf = {0.f, 0.f, 0.f, 0.f};
  __syncthreads();

  f4v hacc[4][4];
#pragma unroll
  for (int mt = 0; mt < 4; mt++)
#pragma unroll
    for (int nt = 0; nt < 4; nt++) hacc[mt][nt] = zf;

  unsigned short* ldsF = &ldsT[0][0];   // h stage, pitch 40
  for (int kk = 0; kk < 128; kk += 32) {
    {
      const int r = tid >> 2, c8 = (tid & 3) * 8;
      *(bf16x8*)&ldsF[r*40 + c8] =
          *(const bf16x8*)(hfeat + (size_t)sS[r] * HC + kk + c8);
    }
    __syncthreads();
#pragma unroll
    for (int nt = 0; nt < 4; nt++) {
      const size_t brow = (size_t)(wave*64 + nt*16 + l16);
      bf16x8 b = *(const bf16x8*)&l1h[brow * HC + kk + quad*8];
#pragma unroll
      for (int mt = 0; mt < 4; mt++) {
        bf16x8 a = *(const bf16x8*)&ldsF[(mt*16 + l16)*40 + quad*8];
        hacc[mt][nt] = __builtin_amdgcn_mfma_f32_16x16x32_bf16(a, b, hacc[mt][nt], 0, 0, 0);
      }
    }
    __syncthreads();
  }

  f4v wacc[4][4];
#pragma unroll
  for (int mt = 0; mt < 4; mt++)
#pragma unroll
    for (int nt = 0; nt < 4; nt++) wacc[mt][nt] = zf;

  for (int p = 0; p < 4; p++) {
    f4v tacc[4];
#pragma unroll
    for (int mt = 0; mt < 4; mt++) tacc[mt] = zf;
    const size_t b1row = (size_t)(p*64 + wave*16 + l16);
#pragma unroll
    for (int kk = 0; kk < 128; kk += 32) {
      bf16x8 b = *(const bf16x8*)&fw1h[b1row * HC + kk + quad*8];
#pragma unroll
      for (int mt = 0; mt < 4; mt++) {
        bf16x8 a = *(const bf16x8*)&ldsA[mt*16 + l16][kk + quad*8];
        tacc[mt] = __builtin_amdgcn_mfma_f32_16x16x32_bf16(a, b, tacc[mt], 0, 0, 0);
      }
    }
    {
      const int col = wave*16 + l16;
      const float bz = fb1[p*64 + col];
#pragma unroll
      for (int mt = 0; mt < 4; mt++) {
        const int rowb = mt*16 + quad*4;
#pragma unroll
        for (int rr = 0; rr < 4; rr++)
          ldsT[rowb+rr][col] = f2bf(ssp_f(tacc[mt][rr] + bz));
      }
    }
    __syncthreads();

#pragma unroll
    for (int kc = 0; kc < 2; kc++) {
      bf16x8 a_[4];
#pragma unroll
      for (int mt = 0; mt < 4; mt++)
        a_[mt] = *(const bf16x8*)&ldsT[mt*16 + l16][kc*32 + quad*8];
#pragma unroll
      for (int nt = 0; nt < 4; nt++) {
        const size_t brow = (size_t)(wave*64 + nt*16 + l16);
        bf16x8 b = *(const bf16x8*)&fw2h[brow * NFC + p*64 + kc*32 + quad*8];
#pragma unroll
        for (int mt = 0; mt < 4; mt++)
          wacc[mt][nt] = __builtin_amdgcn_mfma_f32_16x16x32_bf16(a_[mt], b, wacc[mt][nt], 0, 0, 0);
      }
    }
    __syncthreads();
  }

#pragma unroll
  for (int nt = 0; nt < 4; nt++) {
    const int col = wave*64 + nt*16 + l16;
    const float bz = fb2[col];
    float accum = 0.f;
    int prev = -1;
#pragma unroll
    for (int mt = 0; mt < 4; mt++) {
#pragma unroll
      for (int rr = 0; rr < 4; rr++) {
        const int prow = mt*16 + quad*4 + rr;
        const int d = sD[prow];
        const float v = (wacc[mt][nt][rr] + bz) * hacc[mt][nt][rr];
        if (d != prev) {
          if (prev >= 0) atomicAdd(&agg[(size_t)prev * NFC + col], accum);
          accum = v; prev = d;
        } else {
          accum += v;
        }
      }
    }
    atomicAdd(&agg[(size_t)prev * NFC + col], accum);
  }
}

// ---------------------------------------------------------------------------
// Fused pool + head (batch sorted; bf16 h).
__global__ __launch_bounds__(256) void poolhead_kernel(
    const int* __restrict__ batch, const unsigned short* __restrict__ h,
    const float* __restrict__ w1, const float* __restrict__ b1,
    const float* __restrict__ w2, const float* __restrict__ b2,
    float* __restrict__ y)
{
  __shared__ float gs[HC];
  __shared__ float red[256];
  const int g = blockIdx.x;
  const int tid = threadIdx.x;

  int lo = 0, hi = N_NODES;
  while (lo < hi) { int m = (lo + hi) >> 1; if (batch[m] < g) lo = m + 1; else hi = m; }
  int lo2 = lo, hi2 = N_NODES;
  while (lo2 < hi2) { int m = (lo2 + hi2) >> 1; if (batch[m] < g + 1) lo2 = m + 1; else hi2 = m; }
  const int cnt = lo2 - lo;

  if (tid < HC) {
    float s = 0.f;
    for (int i = lo; i < lo2; i++) s += bf2f(h[(size_t)i * HC + tid]);
    gs[tid] = s / (float)max(cnt, 1);
  }
  __syncthreads();

  float partial = 0.f;
  for (int f = tid; f < NFFC; f += 256) {
    float acc = b1[f];
    const float* wr = w1 + (size_t)f * HC;
#pragma unroll 8
    for (int k = 0; k < HC; k++) acc = fmaf(gs[k], wr[k], acc);
    float t = 0.5f * acc * (1.0f + erff(acc * 0.70710678118654752440f));
    partial = fmaf(t, w2[f], partial);
  }
  red[tid] = partial;
  __syncthreads();
  for (int s = 128; s > 0; s >>= 1) {
    if (tid < s) red[tid] += red[tid + s];
    __syncthreads();
  }
  if (tid == 0) y[g] = red[0] + b2[0];
}

// ---------------------------------------------------------------------------
extern "C" void kernel_launch(void* const* d_in, const int* in_sizes, int n_in,
                              void* d_out, int out_size, void* d_ws, size_t ws_size,
                              hipStream_t stream) {
  const int*   x     = (const int*)  d_in[0];
  const int*   ei    = (const int*)  d_in[1];
  const float* eattr = (const float*)d_in[2];
  const int*   batch = (const int*)  d_in[3];
  const float* pos   = (const float*)d_in[4];
  const float* vert  = (const float*)d_in[5];
  const float* posw  = (const float*)d_in[6];
  const float* edgew = (const float*)d_in[7];
  const float* fw1   = (const float*)d_in[8];
  const float* fb1   = (const float*)d_in[9];
  const float* fw2   = (const float*)d_in[10];
  const float* fb2   = (const float*)d_in[11];
  const float* l1w   = (const float*)d_in[12];
  const float* l2w   = (const float*)d_in[13];
  const float* l2b   = (const float*)d_in[14];
  const float* l3w   = (const float*)d_in[15];
  const float* l3b   = (const float*)d_in[16];
  const float* emw   = (const float*)d_in[17];
  const float* emb   = (const float*)d_in[18];
  const float* hw1   = (const float*)d_in[19];
  const float* hb1   = (const float*)d_in[20];
  const float* hw2   = (const float*)d_in[21];
  const float* hb2   = (const float*)d_in[22];
  float* out = (float*)d_out;

  char* ws = (char*)d_ws;
  size_t off = 0;
  auto alloc = [&](size_t bytes) { char* p = ws + off; off += (bytes + 511) & ~(size_t)511; return p; };
  unsigned short* ea = (unsigned short*)alloc((size_t)N_EDGES*HC*2);   // bf16
  unsigned short* h  = (unsigned short*)alloc((size_t)N_NODES*HC*2);   // bf16
  float* agg  = (float*)alloc((size_t)N_NODES*NFC*4);
  int* deg    = (int*)alloc((size_t)(N_NODES+1)*4);
  int* cursor = (int*)alloc((size_t)(N_NODES+1)*4);
  int* bsum   = (int*)alloc((size_t)256*4);
  int* perm   = (int*)alloc((size_t)N_EDGES*4);
  const int n_fw1 = NLAYER*NFC*HC, n_fw2 = NLAYER*NFC*NFC, n_l1 = NLAYER*NFC*HC;
  const int n_l2 = NLAYER*HC*NFC, n_l3 = NLAYER*HC*HC, n_em = NLAYER*HC*2*HC;
  unsigned short* fw1h = (unsigned short*)alloc((size_t)n_fw1*2);
  unsigned short* fw2h = (unsigned short*)alloc((size_t)n_fw2*2);
  unsigned short* l1h  = (unsigned short*)alloc((size_t)n_l1*2);
  unsigned short* l2h  = (unsigned short*)alloc((size_t)n_l2*2);
  unsigned short* l3h  = (unsigned short*)alloc((size_t)n_l3*2);
  unsigned short* emh  = (unsigned short*)alloc((size_t)n_em*2);

  const int NSCAN = N_NODES + 1;                 // 50001
  const int NB    = (NSCAN + 255) / 256;         // 196

  zeroi_kernel<<<(NSCAN+255)/256, 256, 0, stream>>>(deg, NSCAN);
  hist_kernel<<<(N_EDGES+255)/256, 256, 0, stream>>>(ei, deg);
  scan1_kernel<<<NB, 256, 0, stream>>>(deg, cursor, bsum, NSCAN);
  scan2_kernel<<<1, 256, 0, stream>>>(bsum, NB);
  scan3_kernel<<<NB, 256, 0, stream>>>(cursor, bsum, NSCAN);
  perm_kernel<<<(N_EDGES+255)/256, 256, 0, stream>>>(ei, cursor, perm);

  wconv_kernel<<<(n_fw1+255)/256, 256, 0, stream>>>(fw1, fw1h, n_fw1);
  wconv_kernel<<<(n_fw2+255)/256, 256, 0, stream>>>(fw2, fw2h, n_fw2);
  wconv_kernel<<<(n_l1 +255)/256, 256, 0, stream>>>(l1w, l1h, n_l1);
  wconv_kernel<<<(n_l2 +255)/256, 256, 0, stream>>>(l2w, l2h, n_l2);
  wconv_kernel<<<(n_l3 +255)/256, 256, 0, stream>>>(l3w, l3h, n_l3);
  wconv_kernel<<<(n_em +255)/256, 256, 0, stream>>>(emw, emh, n_em);

  const int GN   = (N_NODES + 127) / 128;   // 391
  const int GE64 = N_EDGES / 64;            // 3125 (exact)

  embed_kernel<<<N_NODES, 128, 0, stream>>>(x, pos, vert, posw, h);
  edgeproj_kernel<<<(N_EDGES*HC + 255)/256, 256, 0, stream>>>(eattr, edgew, ea);
  zero_kernel<<<((N_NODES*NFC/4) + 255)/256, 256, 0, stream>>>(
      (float4*)agg, N_NODES*NFC/4);

  for (int i = 0; i < NLAYER; ++i) {
    ffs_kernel<<<GE64, 256, 0, stream>>>(
        ea, l1h + (size_t)i*NFC*HC,
        fw1h + (size_t)i*NFC*HC, fb1 + (size_t)i*NFC,
        fw2h + (size_t)i*NFC*NFC, fb2 + (size_t)i*NFC,
        ei, perm, h, agg);
    nodeup_kernel<<<GN, 256, 0, stream>>>(
        agg, l2h + (size_t)i*HC*NFC, l2b + (size_t)i*HC,
        l3h + (size_t)i*HC*HC, l3b + (size_t)i*HC, h);
    if (i < NLAYER - 1) {
      emlite_kernel<<<GE64, 256, 0, stream>>>(
          ea, emh + (size_t)i*HC*2*HC, emb + (size_t)i*HC,
          ei, h);
    }
  }

  poolhead_kernel<<<N_GRAPH, 256, 0, stream>>>(batch, h, hw1, hb1, hw2, hb2, out);
}